// Round 1
// baseline (1361.078 us; speedup 1.0000x reference)
//
#include <hip/hip_runtime.h>

#define NPTS 1000000
#define NVOX 200000
#define EPSV 1e-5f

#define SB0 256     // k_stats0 blocks
#define KB1 1024    // k2b blocks (4 waves each)
#define KB2 768     // k4 blocks
#define KB6 768     // k6_gather blocks (fallback)
#define KB7 768     // k7 blocks (fallback)
#define KB6S 1024   // k6_stream blocks (fast path)
#define NMB ((NVOX + 255) / 256)   // 782 (k_mean blocks)

#define W1CH ((NPTS + KB1*4 - 1) / (KB1*4))   // 245 pts/wave (k2b)
#define W2CH ((NPTS + KB2*4 - 1) / (KB2*4))   // 326 pts/wave (k4)
#define V6CH ((NVOX + KB6*4 - 1) / (KB6*4))   // 66 vox/wave (k6_gather)
#define V7CH ((NVOX + KB7*4 - 1) / (KB7*4))   // 66 vox/wave (k7)
#define V6SCH ((NVOX + KB6S*4 - 1) / (KB6S*4)) // 49 vox/wave (k6_stream)

// ---- ws layout (4-byte words) ----
// zeroed each launch:
#define OFF_CNT    0          // 200000 ints (per-voxel counts)
#define ZERO_WORDS 200000
// fully overwritten every launch:
#define OFF_BASE   200000     // 200000 ints (after k_fill: base[v] = END offset of voxel v)
#define OFF_BSUM   400000     // 512
#define OFF_BOFF   400512     // 512
#define OFF_PIDX   401024     // 1000000 ints
#define OFF_VOX    1401024    // 800000 floats {mx,my,mz,cnt}
#define OFF_P0     2201024    // SB0*20 = 5120
#define OFF_PM     2206144    // NMB*4  = 3128
#define OFF_PH1    2209272    // KB1*64 = 65536
#define OFF_PQ1    2274808    // 65536
#define OFF_PH2    2340344    // KB2*64 = 49152
#define OFF_PQ2    2389496    // 49152
#define OFF_WF     2438648    // 832 (BN0-folded w1)
#define OFF_BF     2439480    // 64
#define OFF_WF2    2439544    // 832 (BN0+BN1-folded w1)
#define OFF_BF2    2440376    // 64
#define OFF_S2     2440440    // 64
#define OFF_T2     2440504    // 64
#define WS_WORDS   2440568
// fast-path extras (only touched when ws_size is big enough):
#define OFF_SIDX   2440568                  // 1000000 ints: point -> CSR slot
#define OFF_H      3440640                  // (aligned) NPTS*64 floats: pre-BN2 h, CSR order
#define WS_FULL_WORDS (OFF_H + (size_t)NPTS * 64)   // 67,440,640 words ~ 258 MB

#define SCAN_B 512
#define NSCAN ((NVOX + SCAN_B - 1) / SCAN_B)   // 391

__device__ __forceinline__ float bcast(float x, int k) {
    return __int_as_float(__builtin_amdgcn_readlane(__float_as_int(x), k));
}
__device__ __forceinline__ float wave_red(float x) {
#pragma unroll
    for (int o = 32; o > 0; o >>= 1) x += __shfl_down(x, o);
    return x;
}

// ---- macro-generated straight-line register code ----
#define REP13(M) M(0) M(1) M(2) M(3) M(4) M(5) M(6) M(7) M(8) M(9) M(10) M(11) M(12)
#define REP64(M) M(0) M(1) M(2) M(3) M(4) M(5) M(6) M(7) M(8) M(9) \
 M(10) M(11) M(12) M(13) M(14) M(15) M(16) M(17) M(18) M(19) \
 M(20) M(21) M(22) M(23) M(24) M(25) M(26) M(27) M(28) M(29) \
 M(30) M(31) M(32) M(33) M(34) M(35) M(36) M(37) M(38) M(39) \
 M(40) M(41) M(42) M(43) M(44) M(45) M(46) M(47) M(48) M(49) \
 M(50) M(51) M(52) M(53) M(54) M(55) M(56) M(57) M(58) M(59) \
 M(60) M(61) M(62) M(63)

// PIN: opaque the value so LLVM cannot rematerialize the (invariant) load
// inside the loop — R5 profile: without this, VGPR_Count=60 with 77+ live
// weights => all 64 w2 values re-loaded from L1 every point (3x inst bloat).
#define DECL_W1(J)  float w1c_##J = Wfp[(J)*64 + lane]; asm("" : "+v"(w1c_##J));
#define DECL_W2(K)  float w2c_##K = w2[(K)*64 + lane];  asm("" : "+v"(w2c_##K));
#define DECL_W3(K)  float w3c_##K = w3[(K)*64 + lane];  asm("" : "+v"(w3c_##K));

// features f0..f12 from point p; expects float4 vs (voxel mean) in scope
#define FEAT_BODY \
    float4 pt = pts[p]; \
    int g0 = gind[3*p], g1 = gind[3*p+1], g2 = gind[3*p+2]; \
    float f0 = pt.x, f1 = pt.y, f2 = pt.z, f3 = pt.w; \
    float f4 = pt.x - vs.x, f5 = pt.y - vs.y, f6 = pt.z - vs.z; \
    float f7 = pt.x - ((float)g0 * 0.2f - 51.2f); \
    float f8 = pt.y - ((float)g1 * 0.2f - 51.2f); \
    float f9 = pt.z - ((float)g2 * 0.2f - 4.0f); \
    float f10 = nor[3*p], f11 = nor[3*p+1], f12 = nor[3*p+2];

#define FEAT_GATHER float4 vs = vox4[cinv[p]]; FEAT_BODY

#define L1EXPR (bc + ((((f0*w1c_0 + f1*w1c_1) + (f2*w1c_2 + f3*w1c_3)) \
              + ((f4*w1c_4 + f5*w1c_5) + (f6*w1c_6 + f7*w1c_7))) \
              + (((f8*w1c_8 + f9*w1c_9) + (f10*w1c_10 + f11*w1c_11)) \
              + f12*w1c_12)))

#define L2G(A,B,C,D) ha += bcast(r,A)*w2c_##A; hb += bcast(r,B)*w2c_##B; \
                     hc += bcast(r,C)*w2c_##C; hd += bcast(r,D)*w2c_##D;
#define L2ALL L2G(0,1,2,3) L2G(4,5,6,7) L2G(8,9,10,11) L2G(12,13,14,15) \
  L2G(16,17,18,19) L2G(20,21,22,23) L2G(24,25,26,27) L2G(28,29,30,31) \
  L2G(32,33,34,35) L2G(36,37,38,39) L2G(40,41,42,43) L2G(44,45,46,47) \
  L2G(48,49,50,51) L2G(52,53,54,55) L2G(56,57,58,59) L2G(60,61,62,63)

#define L3G(A,B,C,D) ya += bcast(m,A)*w3c_##A; yb += bcast(m,B)*w3c_##B; \
                     yc += bcast(m,C)*w3c_##C; yd += bcast(m,D)*w3c_##D;
#define L3ALL L3G(0,1,2,3) L3G(4,5,6,7) L3G(8,9,10,11) L3G(12,13,14,15) \
  L3G(16,17,18,19) L3G(20,21,22,23) L3G(24,25,26,27) L3G(28,29,30,31) \
  L3G(32,33,34,35) L3G(36,37,38,39) L3G(40,41,42,43) L3G(44,45,46,47) \
  L3G(48,49,50,51) L3G(52,53,54,55) L3G(56,57,58,59) L3G(60,61,62,63)

// ---------------- counts ----------------
__global__ __launch_bounds__(256) void k_count(
    const int* __restrict__ cinv, int* __restrict__ cnt)
{
    int i = blockIdx.x * 256 + threadIdx.x;
    if (i < NPTS) atomicAdd(&cnt[cinv[i]], 1);
}

// ---------------- scan ----------------
__global__ __launch_bounds__(SCAN_B) void k_scan1(
    const int* __restrict__ cnt, int* __restrict__ base, int* __restrict__ bsum)
{
    __shared__ int sd[SCAN_B];
    int t = threadIdx.x;
    int v = blockIdx.x * SCAN_B + t;
    int x = (v < NVOX) ? cnt[v] : 0;
    sd[t] = x;
    __syncthreads();
    for (int o = 1; o < SCAN_B; o <<= 1) {
        int y = (t >= o) ? sd[t - o] : 0;
        __syncthreads();
        sd[t] += y;
        __syncthreads();
    }
    if (v < NVOX) base[v] = sd[t] - x;
    if (t == SCAN_B - 1) bsum[blockIdx.x] = sd[t];
}

__global__ __launch_bounds__(SCAN_B) void k_scan2(
    const int* __restrict__ bsum, int* __restrict__ boff)
{
    __shared__ int sd[SCAN_B];
    int t = threadIdx.x;
    int x = (t < NSCAN) ? bsum[t] : 0;
    sd[t] = x;
    __syncthreads();
    for (int o = 1; o < SCAN_B; o <<= 1) {
        int y = (t >= o) ? sd[t - o] : 0;
        __syncthreads();
        sd[t] += y;
        __syncthreads();
    }
    if (t < NSCAN) boff[t] = sd[t] - x;
}

__global__ __launch_bounds__(256) void k_base(
    const int* __restrict__ boff, int* __restrict__ base)
{
    int v = blockIdx.x * 256 + threadIdx.x;
    if (v < NVOX) base[v] += boff[v >> 9];
}

__global__ __launch_bounds__(256) void k_fill(
    const int* __restrict__ cinv, int* __restrict__ base,
    int* __restrict__ pidx, int* __restrict__ sidx)
{
    int i = blockIdx.x * 256 + threadIdx.x;
    if (i >= NPTS) return;
    int slot = atomicAdd(&base[cinv[i]], 1);
    pidx[slot] = i;
    if (sidx) sidx[i] = slot;
}

// ---------------- per-voxel means ----------------
__global__ __launch_bounds__(256, 2) void k_mean(
    const float4* __restrict__ pts, const int* __restrict__ base,
    const int* __restrict__ pidx, float4* __restrict__ vox4,
    float* __restrict__ PM)
{
    int v = blockIdx.x * 256 + threadIdx.x;
    float cm2x = 0.f, cm2y = 0.f, cm2z = 0.f;
    if (v < NVOX) {
        int st = (v == 0) ? 0 : base[v - 1];
        int en = base[v];
        int c = en - st;
        float sx = 0.f, sy = 0.f, sz = 0.f;
        for (int i = st; i < en; i++) {
            float4 p = pts[pidx[i]];
            sx += p.x; sy += p.y; sz += p.z;
        }
        float fc = (float)c;
        float ic = 1.0f / fmaxf(fc, 1.0f);
        float mx = sx * ic, my = sy * ic, mz = sz * ic;
        vox4[v] = make_float4(mx, my, mz, fc);
        cm2x = fc * mx * mx; cm2y = fc * my * my; cm2z = fc * mz * mz;
    }
    cm2x = wave_red(cm2x); cm2y = wave_red(cm2y); cm2z = wave_red(cm2z);
    __shared__ float red[4][3];
    int w = threadIdx.x >> 6, lane = threadIdx.x & 63;
    if (lane == 0) { red[w][0] = cm2x; red[w][1] = cm2y; red[w][2] = cm2z; }
    __syncthreads();
    if (threadIdx.x < 3)
        PM[blockIdx.x * 4 + threadIdx.x] =
            red[0][threadIdx.x] + red[1][threadIdx.x] + red[2][threadIdx.x] + red[3][threadIdx.x];
}

// ---------------- feature first/second moments -> per-block partials --------
__global__ __launch_bounds__(256, 2) void k_stats0(
    const float4* __restrict__ pts, const float* __restrict__ nor,
    const int* __restrict__ gind, float* __restrict__ P0)
{
    // contiguous per-thread chunks
    const int T = SB0 * 256;
    const int CH = (NPTS + T - 1) / T;
    int tid = blockIdx.x * 256 + threadIdx.x;
    int i0 = tid * CH, i1 = min(i0 + CH, NPTS);
    float s0=0,s1=0,s2=0,s3=0, q0=0,q1=0,q2=0,q3=0;
    float sc0=0,sc1=0,sc2=0, qc0=0,qc1=0,qc2=0;
    float sn0=0,sn1=0,sn2=0, qn0=0,qn1=0,qn2=0;
    for (int i = i0; i < i1; i++) {
        float4 p = pts[i];
        int g0 = gind[3*i], g1 = gind[3*i+1], g2 = gind[3*i+2];
        float n0 = nor[3*i], n1 = nor[3*i+1], n2 = nor[3*i+2];
        s0 += p.x; s1 += p.y; s2 += p.z; s3 += p.w;
        q0 += p.x*p.x; q1 += p.y*p.y; q2 += p.z*p.z; q3 += p.w*p.w;
        float c0 = p.x - ((float)g0 * 0.2f - 51.2f);
        float c1 = p.y - ((float)g1 * 0.2f - 51.2f);
        float c2 = p.z - ((float)g2 * 0.2f - 4.0f);
        sc0 += c0; sc1 += c1; sc2 += c2;
        qc0 += c0*c0; qc1 += c1*c1; qc2 += c2*c2;
        sn0 += n0; sn1 += n1; sn2 += n2;
        qn0 += n0*n0; qn1 += n1*n1; qn2 += n2*n2;
    }
    int w = threadIdx.x >> 6, lane = threadIdx.x & 63;
    __shared__ float red[4][20];
    s0 = wave_red(s0); s1 = wave_red(s1); s2 = wave_red(s2); s3 = wave_red(s3);
    q0 = wave_red(q0); q1 = wave_red(q1); q2 = wave_red(q2); q3 = wave_red(q3);
    sc0 = wave_red(sc0); sc1 = wave_red(sc1); sc2 = wave_red(sc2);
    qc0 = wave_red(qc0); qc1 = wave_red(qc1); qc2 = wave_red(qc2);
    sn0 = wave_red(sn0); sn1 = wave_red(sn1); sn2 = wave_red(sn2);
    qn0 = wave_red(qn0); qn1 = wave_red(qn1); qn2 = wave_red(qn2);
    if (lane == 0) {
        red[w][0]=s0;  red[w][1]=s1;  red[w][2]=s2;  red[w][3]=s3;
        red[w][4]=q0;  red[w][5]=q1;  red[w][6]=q2;  red[w][7]=q3;
        red[w][8]=sc0; red[w][9]=sc1; red[w][10]=sc2;
        red[w][11]=qc0; red[w][12]=qc1; red[w][13]=qc2;
        red[w][14]=sn0; red[w][15]=sn1; red[w][16]=sn2;
        red[w][17]=qn0; red[w][18]=qn1; red[w][19]=qn2;
    }
    __syncthreads();
    int t = threadIdx.x;
    if (t < 20)
        P0[blockIdx.x * 20 + t] = red[0][t] + red[1][t] + red[2][t] + red[3][t];
}

// ---------------- reduce partials + fold BN0 ----------------
__global__ void k3b_fold(
    const float* __restrict__ P0, const float* __restrict__ PM,
    const float* __restrict__ bn0g, const float* __restrict__ bn0b,
    const float* __restrict__ w1, const float* __restrict__ b1,
    float* __restrict__ Wf, float* __restrict__ bfv)
{
    __shared__ float st[23];
    int t = threadIdx.x;  // 64
    for (int j = 0; j < 20; j++) {
        float s = 0.f;
        for (int b = t; b < SB0; b += 64) s += P0[b * 20 + j];
        s = wave_red(s);
        if (t == 0) st[j] = s;
    }
    for (int j = 0; j < 3; j++) {
        float s = 0.f;
        for (int b = t; b < NMB; b += 64) s += PM[b * 4 + j];
        s = wave_red(s);
        if (t == 0) st[20 + j] = s;
    }
    __syncthreads();
    const float invN = 1.0f / (float)NPTS;
    float m[13], vr[13];
    for (int j = 0; j < 4; j++)  { m[j] = st[j] * invN;   vr[j] = st[4+j] * invN - m[j]*m[j]; }
    for (int j = 4; j < 7; j++)  { m[j] = 0.f;            vr[j] = st[j] * invN - st[16+j] * invN; }
    for (int j = 7; j < 10; j++) { m[j] = st[1+j] * invN; vr[j] = st[4+j] * invN - m[j]*m[j]; }
    for (int j = 10; j < 13; j++){ m[j] = st[4+j] * invN; vr[j] = st[7+j] * invN - m[j]*m[j]; }
    float bacc = b1[t];
    for (int j = 0; j < 13; j++) {
        float s = bn0g[j] * rsqrtf(vr[j] + EPSV);
        float tt = bn0b[j] - m[j] * s;
        Wf[j*64 + t] = s * w1[j*64 + t];
        bacc += tt * w1[j*64 + t];
    }
    bfv[t] = bacc;
}

// ---------------- BN1 stats (layer-1 only) ----------------
__global__ __launch_bounds__(256, 4) void k2b_stats1(
    const float4* __restrict__ pts, const float* __restrict__ nor,
    const int* __restrict__ gind, const int* __restrict__ cinv,
    const float4* __restrict__ vox4,
    const float* __restrict__ Wfp, const float* __restrict__ bfv,
    float* __restrict__ PH, float* __restrict__ PQ)
{
    int lane = threadIdx.x & 63;
    int w = threadIdx.x >> 6;
    int wid = blockIdx.x * 4 + w;
    int p0 = wid * W1CH, p1 = min(p0 + W1CH, NPTS);
    REP13(DECL_W1)
    float bc = bfv[lane];
    float sh = 0.f, sq = 0.f;
    for (int p = p0; p < p1; p++) {
        FEAT_GATHER
        float a = L1EXPR;
        sh += a; sq += a * a;
    }
    __shared__ float LH[4][64], LQ[4][64];
    LH[w][lane] = sh; LQ[w][lane] = sq;
    __syncthreads();
    if (w == 0) {
        PH[blockIdx.x * 64 + lane] = LH[0][lane] + LH[1][lane] + LH[2][lane] + LH[3][lane];
        PQ[blockIdx.x * 64 + lane] = LQ[0][lane] + LQ[1][lane] + LQ[2][lane] + LQ[3][lane];
    }
}

// ---------------- reduce + fold BN1 ----------------
__global__ __launch_bounds__(256) void k3c_fold(
    const float* __restrict__ PH, const float* __restrict__ PQ,
    const float* __restrict__ bn1g, const float* __restrict__ bn1b,
    const float* __restrict__ Wf, const float* __restrict__ bfv,
    float* __restrict__ Wf2, float* __restrict__ bf2)
{
    __shared__ float LH[4][64], LQ[4][64];
    int c = threadIdx.x & 63, g = threadIdx.x >> 6;
    float sH = 0.f, sQ = 0.f;
    for (int b = g; b < KB1; b += 4) { sH += PH[b*64 + c]; sQ += PQ[b*64 + c]; }
    LH[g][c] = sH; LQ[g][c] = sQ;
    __syncthreads();
    if (g == 0) {
        const float invN = 1.0f / (float)NPTS;
        float mn = (LH[0][c] + LH[1][c] + LH[2][c] + LH[3][c]) * invN;
        float vr = (LQ[0][c] + LQ[1][c] + LQ[2][c] + LQ[3][c]) * invN - mn * mn;
        float s = bn1g[c] * rsqrtf(vr + EPSV);
        float t = bn1b[c] - mn * s;
        for (int j = 0; j < 13; j++) Wf2[j*64 + c] = s * Wf[j*64 + c];
        bf2[c] = s * bfv[c] + t;
    }
}

// ---------------- BN2 stats (layer 1+2), optionally store h (CSR order) -----
__global__ __launch_bounds__(256, 3) void k4_stats2(
    const float4* __restrict__ pts, const float* __restrict__ nor,
    const int* __restrict__ gind, const int* __restrict__ cinv,
    const float4* __restrict__ vox4,
    const float* __restrict__ Wfp, const float* __restrict__ bfv,
    const float* __restrict__ w2, const float* __restrict__ b2,
    const int* __restrict__ sidx, float* __restrict__ hout,
    float* __restrict__ PH, float* __restrict__ PQ)
{
    int lane = threadIdx.x & 63;
    int w = threadIdx.x >> 6;
    int wid = blockIdx.x * 4 + w;
    int p0 = wid * W2CH, p1 = min(p0 + W2CH, NPTS);
    REP13(DECL_W1)
    float bc = bfv[lane];
    REP64(DECL_W2)
    float b2c = b2[lane];
    float sh = 0.f, sq = 0.f;
    for (int p = p0; p < p1; p++) {
        FEAT_GATHER
        float r = fmaxf(L1EXPR, 0.f);
        float ha = b2c, hb = 0.f, hc = 0.f, hd = 0.f;
        L2ALL
        float h = (ha + hb) + (hc + hd);
        if (hout) hout[(size_t)sidx[p] * 64 + lane] = h;
        sh += h; sq += h * h;
    }
    __shared__ float LH[4][64], LQ[4][64];
    LH[w][lane] = sh; LQ[w][lane] = sq;
    __syncthreads();
    if (w == 0) {
        PH[blockIdx.x * 64 + lane] = LH[0][lane] + LH[1][lane] + LH[2][lane] + LH[3][lane];
        PQ[blockIdx.x * 64 + lane] = LQ[0][lane] + LQ[1][lane] + LQ[2][lane] + LQ[3][lane];
    }
}

// ---------------- reduce + finalize BN2 ----------------
__global__ __launch_bounds__(256) void k5_bn2(
    const float* __restrict__ PH, const float* __restrict__ PQ,
    const float* __restrict__ bn2g, const float* __restrict__ bn2b,
    float* __restrict__ s2, float* __restrict__ t2)
{
    __shared__ float LH[4][64], LQ[4][64];
    int c = threadIdx.x & 63, g = threadIdx.x >> 6;
    float sH = 0.f, sQ = 0.f;
    for (int b = g; b < KB2; b += 4) { sH += PH[b*64 + c]; sQ += PQ[b*64 + c]; }
    LH[g][c] = sH; LQ[g][c] = sQ;
    __syncthreads();
    if (g == 0) {
        const float invN = 1.0f / (float)NPTS;
        float mn = (LH[0][c] + LH[1][c] + LH[2][c] + LH[3][c]) * invN;
        float vr = (LQ[0][c] + LQ[1][c] + LQ[2][c] + LQ[3][c]) * invN - mn * mn;
        float s = bn2g[c] * rsqrtf(vr + EPSV);
        s2[c] = s; t2[c] = bn2b[c] - mn * s;
    }
}

// -------- FAST PATH k6: stream stored h (CSR order), BN2+relu+segsum,
//          fuse mean + w3 matmul + bias (replaces k6_gather AND k7_final) ----
__global__ __launch_bounds__(256, 4) void k6_stream(
    const int* __restrict__ base, const float* __restrict__ h,
    const float* __restrict__ s2, const float* __restrict__ t2,
    const float* __restrict__ w3, const float* __restrict__ b3,
    float* __restrict__ out)
{
    int lane = threadIdx.x & 63;
    int wid = blockIdx.x * 4 + (threadIdx.x >> 6);
    int v0 = wid * V6SCH;
    if (v0 >= NVOX) return;
    int v1 = min(v0 + V6SCH, NVOX);
    REP64(DECL_W3)
    float b3c = b3[lane];
    float s2c = s2[lane], t2c = t2[lane];
    int st = (v0 == 0) ? 0 : base[v0 - 1];
    for (int v = v0; v < v1; v++) {
        int en = base[v];
        int c = en - st;
        const float* hp = h + (size_t)st * 64 + lane;
        float accz = 0.f;
        int ii = 0;
        // unroll-4 with independent loads for MLP
        for (; ii + 3 < c; ii += 4) {
            float h0 = hp[(size_t)(ii + 0) * 64];
            float h1 = hp[(size_t)(ii + 1) * 64];
            float h2v = hp[(size_t)(ii + 2) * 64];
            float h3v = hp[(size_t)(ii + 3) * 64];
            accz += fmaxf(s2c * h0 + t2c, 0.f);
            accz += fmaxf(s2c * h1 + t2c, 0.f);
            accz += fmaxf(s2c * h2v + t2c, 0.f);
            accz += fmaxf(s2c * h3v + t2c, 0.f);
        }
        for (; ii < c; ii++)
            accz += fmaxf(s2c * hp[(size_t)ii * 64] + t2c, 0.f);
        float* row = out + (size_t)v * 64;
        if (c > 0) {
            float m = accz / (float)c;
            float ya = b3c, yb = 0.f, yc = 0.f, yd = 0.f;
            L3ALL
            row[lane] = (ya + yb) + (yc + yd);
        } else {
            row[lane] = 0.f;
        }
        st = en;
    }
}

// ---- FALLBACK PATH: main forward + per-voxel sum (wave per voxel, CSR) -----
__global__ __launch_bounds__(256, 3) void k6_gather(
    const float4* __restrict__ pts, const float* __restrict__ nor,
    const int* __restrict__ gind,
    const int* __restrict__ base, const int* __restrict__ pidx,
    const float4* __restrict__ vox4,
    const float* __restrict__ Wfp, const float* __restrict__ bfv,
    const float* __restrict__ w2, const float* __restrict__ b2,
    const float* __restrict__ s2, const float* __restrict__ t2,
    float* __restrict__ out)
{
    int lane = threadIdx.x & 63;
    int wid = blockIdx.x * 4 + (threadIdx.x >> 6);
    int v0 = wid * V6CH, v1 = min(v0 + V6CH, NVOX);
    REP13(DECL_W1)
    float bc = bfv[lane];
    REP64(DECL_W2)
    float b2c = b2[lane];
    float s2c = s2[lane], t2c = t2[lane];

    for (int v = v0; v < v1; v++) {
        int st = (v == 0) ? 0 : base[v - 1];
        int en = base[v];
        float4 vs = vox4[v];
        float accz = 0.f;
        for (int ii = st; ii < en; ii++) {
            int p = pidx[ii];
            FEAT_BODY
            float r = fmaxf(L1EXPR, 0.f);
            float ha = b2c, hb = 0.f, hc = 0.f, hd = 0.f;
            L2ALL
            float h = (ha + hb) + (hc + hd);
            accz += fmaxf(s2c * h + t2c, 0.f);
        }
        out[(size_t)v * 64 + lane] = accz;
    }
}

// ---------- mean + w3 matmul + bias (in-place on d_out) — fallback only -----
__global__ __launch_bounds__(256, 3) void k7_final(
    const float4* __restrict__ vox4, const float* __restrict__ w3,
    const float* __restrict__ b3, float* __restrict__ out)
{
    int lane = threadIdx.x & 63;
    int wid = blockIdx.x * 4 + (threadIdx.x >> 6);
    int v0 = wid * V7CH, v1 = min(v0 + V7CH, NVOX);
    REP64(DECL_W3)
    float b3c = b3[lane];
    for (int v = v0; v < v1; v++) {
        float cnt = vox4[v].w;
        float* row = out + (size_t)v * 64;
        if (cnt > 0.5f) {
            float m = row[lane] / cnt;
            float ya = b3c, yb = 0.f, yc = 0.f, yd = 0.f;
            L3ALL
            row[lane] = (ya + yb) + (yc + yd);
        } else {
            row[lane] = 0.f;
        }
    }
}

extern "C" void kernel_launch(void* const* d_in, const int* in_sizes, int n_in,
                              void* d_out, int out_size, void* d_ws, size_t ws_size,
                              hipStream_t stream) {
    const float4* pts  = (const float4*)d_in[0];
    const float*  nor  = (const float*)d_in[1];
    const int*    gind = (const int*)d_in[2];
    const int*    cinv = (const int*)d_in[3];
    const float*  bn0g = (const float*)d_in[4];
    const float*  bn0b = (const float*)d_in[5];
    const float*  w1   = (const float*)d_in[6];
    const float*  b1   = (const float*)d_in[7];
    const float*  bn1g = (const float*)d_in[8];
    const float*  bn1b = (const float*)d_in[9];
    const float*  w2   = (const float*)d_in[10];
    const float*  b2   = (const float*)d_in[11];
    const float*  bn2g = (const float*)d_in[12];
    const float*  bn2b = (const float*)d_in[13];
    const float*  w3   = (const float*)d_in[14];
    const float*  b3   = (const float*)d_in[15];

    float* ws    = (float*)d_ws;
    float* out   = (float*)d_out;
    int*   cnt   = (int*)(ws + OFF_CNT);
    int*   base  = (int*)(ws + OFF_BASE);
    int*   bsum  = (int*)(ws + OFF_BSUM);
    int*   boff  = (int*)(ws + OFF_BOFF);
    int*   pidx  = (int*)(ws + OFF_PIDX);
    float4* vox4 = (float4*)(ws + OFF_VOX);
    float* P0    = ws + OFF_P0;
    float* PM    = ws + OFF_PM;
    float* PH1   = ws + OFF_PH1;
    float* PQ1   = ws + OFF_PQ1;
    float* PH2   = ws + OFF_PH2;
    float* PQ2   = ws + OFF_PQ2;
    float* Wf    = ws + OFF_WF;
    float* bfv   = ws + OFF_BF;
    float* Wf2   = ws + OFF_WF2;
    float* bf2   = ws + OFF_BF2;
    float* s2    = ws + OFF_S2;
    float* t2    = ws + OFF_T2;

    // fast path needs room for sidx + full h (258 MB of workspace)
    const bool fast = ws_size >= WS_FULL_WORDS * sizeof(float);
    int*   sidx = fast ? (int*)(ws + OFF_SIDX) : (int*)nullptr;
    float* hbuf = fast ? (ws + OFF_H) : (float*)nullptr;

    hipMemsetAsync(d_ws, 0, (size_t)ZERO_WORDS * 4, stream);

    k_count<<<(NPTS + 255) / 256, 256, 0, stream>>>(cinv, cnt);
    k_scan1<<<NSCAN, SCAN_B, 0, stream>>>(cnt, base, bsum);
    k_scan2<<<1, SCAN_B, 0, stream>>>(bsum, boff);
    k_base<<<(NVOX + 255) / 256, 256, 0, stream>>>(boff, base);
    k_fill<<<(NPTS + 255) / 256, 256, 0, stream>>>(cinv, base, pidx, sidx);
    k_mean<<<NMB, 256, 0, stream>>>(pts, base, pidx, vox4, PM);
    k_stats0<<<SB0, 256, 0, stream>>>(pts, nor, gind, P0);
    k3b_fold<<<1, 64, 0, stream>>>(P0, PM, bn0g, bn0b, w1, b1, Wf, bfv);
    k2b_stats1<<<KB1, 256, 0, stream>>>(pts, nor, gind, cinv, vox4, Wf, bfv, PH1, PQ1);
    k3c_fold<<<1, 256, 0, stream>>>(PH1, PQ1, bn1g, bn1b, Wf, bfv, Wf2, bf2);
    k4_stats2<<<KB2, 256, 0, stream>>>(pts, nor, gind, cinv, vox4, Wf2, bf2, w2, b2,
                                       sidx, hbuf, PH2, PQ2);
    k5_bn2<<<1, 256, 0, stream>>>(PH2, PQ2, bn2g, bn2b, s2, t2);
    if (fast) {
        k6_stream<<<KB6S, 256, 0, stream>>>(base, hbuf, s2, t2, w3, b3, out);
    } else {
        k6_gather<<<KB6, 256, 0, stream>>>(pts, nor, gind, base, pidx, vox4,
                                           Wf2, bf2, w2, b2, s2, t2, out);
        k7_final<<<KB7, 256, 0, stream>>>(vox4, w3, b3, out);
    }
}

// Round 7
// 1096.305 us; speedup vs baseline: 1.2415x; 1.2415x over previous
//
#include <hip/hip_runtime.h>

#define NPTS 1000000
#define NVOX 200000
#define EPSV 1e-5f

#define SB0 256     // k_stats0 blocks
#define KB1 1024    // k2b blocks (4 waves each)
#define KB2 768     // k4 blocks
#define KB6 768     // k6_gather blocks (fallback)
#define KB7 768     // k7 blocks (fallback)
#define KB6S 1024   // k6_stream blocks (fast path)
#define NMB ((NVOX + 255) / 256)   // 782 (k_mean blocks)

#define W1CH ((NPTS + KB1*4 - 1) / (KB1*4))   // 245 pts/wave (k2b)
#define W2CH ((NPTS + KB2*4 - 1) / (KB2*4))   // 326 pts/wave (k4)
#define V6CH ((NVOX + KB6*4 - 1) / (KB6*4))   // 66 vox/wave (k6_gather)
#define V7CH ((NVOX + KB7*4 - 1) / (KB7*4))   // 66 vox/wave (k7)
#define V6SCH ((NVOX + KB6S*4 - 1) / (KB6S*4)) // 49 vox/wave (k6_stream)

// ================= ws layouts (4-byte word offsets) =================
// --- compact layout (fallback; ws can be as small as 9.8 MB) ---
#define OFF_CNT    0
#define ZERO_WORDS 200000
#define OFF_BASE   200000
#define OFF_BSUM   400000
#define OFF_BOFF   400512
#define OFF_PIDX   401024
#define OFF_VOX    1401024
#define OFF_P0     2201024
#define OFF_PM     2206144
#define OFF_PH1    2209272
#define OFF_PQ1    2274808
#define OFF_PH2    2340344
#define OFF_PQ2    2389496
#define OFF_WF     2438648
#define OFF_BF     2439480
#define OFF_WF2    2439544
#define OFF_BF2    2440376
#define OFF_S2     2440440
#define OFF_T2     2440504
#define WS_WORDS   2440568

// --- fast layout: live-through-k6 state first, then h; everything that is
//     dead before k4 (cnt/scan/pidx/P0/PM/PH1/PQ1) OVERLAPS the h region. ---
#define F_BASE   0          // 200000   live: scan .. k6_stream
#define F_VOX    200000     // 800000   live: k_mean .. k4   (16B aligned)
#define F_PH2    1000000    // 49152    live: k4 .. k5
#define F_PQ2    1049152    // 49152
#define F_WF     1098304    // 832
#define F_BF     1099136    // 64
#define F_WF2    1099200    // 832
#define F_BF2    1100032    // 64
#define F_S2     1100096    // 64
#define F_T2     1100160    // 64
#define F_SIDX   1100224    // 1000000  live: k_fill .. k4
#define F_H      2100224    // h buffer starts here (fp32: 64e6 words, fp16: 32e6)
// early-dead blocks, placed INSIDE the h region (all dead before k4 writes h):
#define F_CNT    2100224    // 200000   k_count..k_scan1
#define F_BSUM   2300224    // 512
#define F_BOFF   2300736    // 512
#define F_PIDX   2301248    // 1000000  k_fill..k_mean
#define F_P0     3301248    // 5120     k_stats0..k3b
#define F_PM     3306368    // 3128
#define F_PH1    3309496    // 65536    k2b..k3c
#define F_PQ1    3375032    // 65536    (ends 3440568 < F_H + 32e6)

#define NEED_F32_BYTES ((size_t)(F_H + (size_t)NPTS * 64) * 4)          // 264,400,896
#define NEED_F16_BYTES ((size_t)F_H * 4 + (size_t)NPTS * 64 * 2)        // 136,400,896

#define SCAN_B 512
#define NSCAN ((NVOX + SCAN_B - 1) / SCAN_B)   // 391

__device__ __forceinline__ float bcast(float x, int k) {
    return __int_as_float(__builtin_amdgcn_readlane(__float_as_int(x), k));
}
__device__ __forceinline__ float wave_red(float x) {
#pragma unroll
    for (int o = 32; o > 0; o >>= 1) x += __shfl_down(x, o);
    return x;
}

// ---- macro-generated straight-line register code ----
#define REP13(M) M(0) M(1) M(2) M(3) M(4) M(5) M(6) M(7) M(8) M(9) M(10) M(11) M(12)
#define REP64(M) M(0) M(1) M(2) M(3) M(4) M(5) M(6) M(7) M(8) M(9) \
 M(10) M(11) M(12) M(13) M(14) M(15) M(16) M(17) M(18) M(19) \
 M(20) M(21) M(22) M(23) M(24) M(25) M(26) M(27) M(28) M(29) \
 M(30) M(31) M(32) M(33) M(34) M(35) M(36) M(37) M(38) M(39) \
 M(40) M(41) M(42) M(43) M(44) M(45) M(46) M(47) M(48) M(49) \
 M(50) M(51) M(52) M(53) M(54) M(55) M(56) M(57) M(58) M(59) \
 M(60) M(61) M(62) M(63)

// PIN: opaque the value so LLVM cannot rematerialize the (invariant) load
// inside the loop — without this, all 64 w2 values re-load from L1 per point.
#define DECL_W1(J)  float w1c_##J = Wfp[(J)*64 + lane]; asm("" : "+v"(w1c_##J));
#define DECL_W2(K)  float w2c_##K = w2[(K)*64 + lane];  asm("" : "+v"(w2c_##K));
#define DECL_W3(K)  float w3c_##K = w3[(K)*64 + lane];  asm("" : "+v"(w3c_##K));

// features f0..f12 from point p; expects float4 vs (voxel mean) in scope
#define FEAT_BODY \
    float4 pt = pts[p]; \
    int g0 = gind[3*p], g1 = gind[3*p+1], g2 = gind[3*p+2]; \
    float f0 = pt.x, f1 = pt.y, f2 = pt.z, f3 = pt.w; \
    float f4 = pt.x - vs.x, f5 = pt.y - vs.y, f6 = pt.z - vs.z; \
    float f7 = pt.x - ((float)g0 * 0.2f - 51.2f); \
    float f8 = pt.y - ((float)g1 * 0.2f - 51.2f); \
    float f9 = pt.z - ((float)g2 * 0.2f - 4.0f); \
    float f10 = nor[3*p], f11 = nor[3*p+1], f12 = nor[3*p+2];

#define FEAT_GATHER float4 vs = vox4[cinv[p]]; FEAT_BODY

#define L1EXPR (bc + ((((f0*w1c_0 + f1*w1c_1) + (f2*w1c_2 + f3*w1c_3)) \
              + ((f4*w1c_4 + f5*w1c_5) + (f6*w1c_6 + f7*w1c_7))) \
              + (((f8*w1c_8 + f9*w1c_9) + (f10*w1c_10 + f11*w1c_11)) \
              + f12*w1c_12)))

#define L2G(A,B,C,D) ha += bcast(r,A)*w2c_##A; hb += bcast(r,B)*w2c_##B; \
                     hc += bcast(r,C)*w2c_##C; hd += bcast(r,D)*w2c_##D;
#define L2ALL L2G(0,1,2,3) L2G(4,5,6,7) L2G(8,9,10,11) L2G(12,13,14,15) \
  L2G(16,17,18,19) L2G(20,21,22,23) L2G(24,25,26,27) L2G(28,29,30,31) \
  L2G(32,33,34,35) L2G(36,37,38,39) L2G(40,41,42,43) L2G(44,45,46,47) \
  L2G(48,49,50,51) L2G(52,53,54,55) L2G(56,57,58,59) L2G(60,61,62,63)

#define L3G(A,B,C,D) ya += bcast(m,A)*w3c_##A; yb += bcast(m,B)*w3c_##B; \
                     yc += bcast(m,C)*w3c_##C; yd += bcast(m,D)*w3c_##D;
#define L3ALL L3G(0,1,2,3) L3G(4,5,6,7) L3G(8,9,10,11) L3G(12,13,14,15) \
  L3G(16,17,18,19) L3G(20,21,22,23) L3G(24,25,26,27) L3G(28,29,30,31) \
  L3G(32,33,34,35) L3G(36,37,38,39) L3G(40,41,42,43) L3G(44,45,46,47) \
  L3G(48,49,50,51) L3G(52,53,54,55) L3G(56,57,58,59) L3G(60,61,62,63)

// ---------------- counts ----------------
__global__ __launch_bounds__(256) void k_count(
    const int* __restrict__ cinv, int* __restrict__ cnt)
{
    int i = blockIdx.x * 256 + threadIdx.x;
    if (i < NPTS) atomicAdd(&cnt[cinv[i]], 1);
}

// ---------------- scan ----------------
__global__ __launch_bounds__(SCAN_B) void k_scan1(
    const int* __restrict__ cnt, int* __restrict__ base, int* __restrict__ bsum)
{
    __shared__ int sd[SCAN_B];
    int t = threadIdx.x;
    int v = blockIdx.x * SCAN_B + t;
    int x = (v < NVOX) ? cnt[v] : 0;
    sd[t] = x;
    __syncthreads();
    for (int o = 1; o < SCAN_B; o <<= 1) {
        int y = (t >= o) ? sd[t - o] : 0;
        __syncthreads();
        sd[t] += y;
        __syncthreads();
    }
    if (v < NVOX) base[v] = sd[t] - x;
    if (t == SCAN_B - 1) bsum[blockIdx.x] = sd[t];
}

__global__ __launch_bounds__(SCAN_B) void k_scan2(
    const int* __restrict__ bsum, int* __restrict__ boff)
{
    __shared__ int sd[SCAN_B];
    int t = threadIdx.x;
    int x = (t < NSCAN) ? bsum[t] : 0;
    sd[t] = x;
    __syncthreads();
    for (int o = 1; o < SCAN_B; o <<= 1) {
        int y = (t >= o) ? sd[t - o] : 0;
        __syncthreads();
        sd[t] += y;
        __syncthreads();
    }
    if (t < NSCAN) boff[t] = sd[t] - x;
}

__global__ __launch_bounds__(256) void k_base(
    const int* __restrict__ boff, int* __restrict__ base)
{
    int v = blockIdx.x * 256 + threadIdx.x;
    if (v < NVOX) base[v] += boff[v >> 9];
}

__global__ __launch_bounds__(256) void k_fill(
    const int* __restrict__ cinv, int* __restrict__ base,
    int* __restrict__ pidx, int* __restrict__ sidx)
{
    int i = blockIdx.x * 256 + threadIdx.x;
    if (i >= NPTS) return;
    int slot = atomicAdd(&base[cinv[i]], 1);
    pidx[slot] = i;
    if (sidx) sidx[i] = slot;
}

// ---------------- per-voxel means ----------------
__global__ __launch_bounds__(256, 2) void k_mean(
    const float4* __restrict__ pts, const int* __restrict__ base,
    const int* __restrict__ pidx, float4* __restrict__ vox4,
    float* __restrict__ PM)
{
    int v = blockIdx.x * 256 + threadIdx.x;
    float cm2x = 0.f, cm2y = 0.f, cm2z = 0.f;
    if (v < NVOX) {
        int st = (v == 0) ? 0 : base[v - 1];
        int en = base[v];
        int c = en - st;
        float sx = 0.f, sy = 0.f, sz = 0.f;
        for (int i = st; i < en; i++) {
            float4 p = pts[pidx[i]];
            sx += p.x; sy += p.y; sz += p.z;
        }
        float fc = (float)c;
        float ic = 1.0f / fmaxf(fc, 1.0f);
        float mx = sx * ic, my = sy * ic, mz = sz * ic;
        vox4[v] = make_float4(mx, my, mz, fc);
        cm2x = fc * mx * mx; cm2y = fc * my * my; cm2z = fc * mz * mz;
    }
    cm2x = wave_red(cm2x); cm2y = wave_red(cm2y); cm2z = wave_red(cm2z);
    __shared__ float red[4][3];
    int w = threadIdx.x >> 6, lane = threadIdx.x & 63;
    if (lane == 0) { red[w][0] = cm2x; red[w][1] = cm2y; red[w][2] = cm2z; }
    __syncthreads();
    if (threadIdx.x < 3)
        PM[blockIdx.x * 4 + threadIdx.x] =
            red[0][threadIdx.x] + red[1][threadIdx.x] + red[2][threadIdx.x] + red[3][threadIdx.x];
}

// ---------------- feature first/second moments -> per-block partials --------
__global__ __launch_bounds__(256, 2) void k_stats0(
    const float4* __restrict__ pts, const float* __restrict__ nor,
    const int* __restrict__ gind, float* __restrict__ P0)
{
    const int T = SB0 * 256;
    const int CH = (NPTS + T - 1) / T;
    int tid = blockIdx.x * 256 + threadIdx.x;
    int i0 = tid * CH, i1 = min(i0 + CH, NPTS);
    float s0=0,s1=0,s2=0,s3=0, q0=0,q1=0,q2=0,q3=0;
    float sc0=0,sc1=0,sc2=0, qc0=0,qc1=0,qc2=0;
    float sn0=0,sn1=0,sn2=0, qn0=0,qn1=0,qn2=0;
    for (int i = i0; i < i1; i++) {
        float4 p = pts[i];
        int g0 = gind[3*i], g1 = gind[3*i+1], g2 = gind[3*i+2];
        float n0 = nor[3*i], n1 = nor[3*i+1], n2 = nor[3*i+2];
        s0 += p.x; s1 += p.y; s2 += p.z; s3 += p.w;
        q0 += p.x*p.x; q1 += p.y*p.y; q2 += p.z*p.z; q3 += p.w*p.w;
        float c0 = p.x - ((float)g0 * 0.2f - 51.2f);
        float c1 = p.y - ((float)g1 * 0.2f - 51.2f);
        float c2 = p.z - ((float)g2 * 0.2f - 4.0f);
        sc0 += c0; sc1 += c1; sc2 += c2;
        qc0 += c0*c0; qc1 += c1*c1; qc2 += c2*c2;
        sn0 += n0; sn1 += n1; sn2 += n2;
        qn0 += n0*n0; qn1 += n1*n1; qn2 += n2*n2;
    }
    int w = threadIdx.x >> 6, lane = threadIdx.x & 63;
    __shared__ float red[4][20];
    s0 = wave_red(s0); s1 = wave_red(s1); s2 = wave_red(s2); s3 = wave_red(s3);
    q0 = wave_red(q0); q1 = wave_red(q1); q2 = wave_red(q2); q3 = wave_red(q3);
    sc0 = wave_red(sc0); sc1 = wave_red(sc1); sc2 = wave_red(sc2);
    qc0 = wave_red(qc0); qc1 = wave_red(qc1); qc2 = wave_red(qc2);
    sn0 = wave_red(sn0); sn1 = wave_red(sn1); sn2 = wave_red(sn2);
    qn0 = wave_red(qn0); qn1 = wave_red(qn1); qn2 = wave_red(qn2);
    if (lane == 0) {
        red[w][0]=s0;  red[w][1]=s1;  red[w][2]=s2;  red[w][3]=s3;
        red[w][4]=q0;  red[w][5]=q1;  red[w][6]=q2;  red[w][7]=q3;
        red[w][8]=sc0; red[w][9]=sc1; red[w][10]=sc2;
        red[w][11]=qc0; red[w][12]=qc1; red[w][13]=qc2;
        red[w][14]=sn0; red[w][15]=sn1; red[w][16]=sn2;
        red[w][17]=qn0; red[w][18]=qn1; red[w][19]=qn2;
    }
    __syncthreads();
    int t = threadIdx.x;
    if (t < 20)
        P0[blockIdx.x * 20 + t] = red[0][t] + red[1][t] + red[2][t] + red[3][t];
}

// ---------------- reduce partials + fold BN0 ----------------
__global__ void k3b_fold(
    const float* __restrict__ P0, const float* __restrict__ PM,
    const float* __restrict__ bn0g, const float* __restrict__ bn0b,
    const float* __restrict__ w1, const float* __restrict__ b1,
    float* __restrict__ Wf, float* __restrict__ bfv)
{
    __shared__ float st[23];
    int t = threadIdx.x;  // 64
    for (int j = 0; j < 20; j++) {
        float s = 0.f;
        for (int b = t; b < SB0; b += 64) s += P0[b * 20 + j];
        s = wave_red(s);
        if (t == 0) st[j] = s;
    }
    for (int j = 0; j < 3; j++) {
        float s = 0.f;
        for (int b = t; b < NMB; b += 64) s += PM[b * 4 + j];
        s = wave_red(s);
        if (t == 0) st[20 + j] = s;
    }
    __syncthreads();
    const float invN = 1.0f / (float)NPTS;
    float m[13], vr[13];
    for (int j = 0; j < 4; j++)  { m[j] = st[j] * invN;   vr[j] = st[4+j] * invN - m[j]*m[j]; }
    for (int j = 4; j < 7; j++)  { m[j] = 0.f;            vr[j] = st[j] * invN - st[16+j] * invN; }
    for (int j = 7; j < 10; j++) { m[j] = st[1+j] * invN; vr[j] = st[4+j] * invN - m[j]*m[j]; }
    for (int j = 10; j < 13; j++){ m[j] = st[4+j] * invN; vr[j] = st[7+j] * invN - m[j]*m[j]; }
    float bacc = b1[t];
    for (int j = 0; j < 13; j++) {
        float s = bn0g[j] * rsqrtf(vr[j] + EPSV);
        float tt = bn0b[j] - m[j] * s;
        Wf[j*64 + t] = s * w1[j*64 + t];
        bacc += tt * w1[j*64 + t];
    }
    bfv[t] = bacc;
}

// ---------------- BN1 stats (layer-1 only) ----------------
__global__ __launch_bounds__(256, 4) void k2b_stats1(
    const float4* __restrict__ pts, const float* __restrict__ nor,
    const int* __restrict__ gind, const int* __restrict__ cinv,
    const float4* __restrict__ vox4,
    const float* __restrict__ Wfp, const float* __restrict__ bfv,
    float* __restrict__ PH, float* __restrict__ PQ)
{
    int lane = threadIdx.x & 63;
    int w = threadIdx.x >> 6;
    int wid = blockIdx.x * 4 + w;
    int p0 = wid * W1CH, p1 = min(p0 + W1CH, NPTS);
    REP13(DECL_W1)
    float bc = bfv[lane];
    float sh = 0.f, sq = 0.f;
    for (int p = p0; p < p1; p++) {
        FEAT_GATHER
        float a = L1EXPR;
        sh += a; sq += a * a;
    }
    __shared__ float LH[4][64], LQ[4][64];
    LH[w][lane] = sh; LQ[w][lane] = sq;
    __syncthreads();
    if (w == 0) {
        PH[blockIdx.x * 64 + lane] = LH[0][lane] + LH[1][lane] + LH[2][lane] + LH[3][lane];
        PQ[blockIdx.x * 64 + lane] = LQ[0][lane] + LQ[1][lane] + LQ[2][lane] + LQ[3][lane];
    }
}

// ---------------- reduce + fold BN1 ----------------
__global__ __launch_bounds__(256) void k3c_fold(
    const float* __restrict__ PH, const float* __restrict__ PQ,
    const float* __restrict__ bn1g, const float* __restrict__ bn1b,
    const float* __restrict__ Wf, const float* __restrict__ bfv,
    float* __restrict__ Wf2, float* __restrict__ bf2)
{
    __shared__ float LH[4][64], LQ[4][64];
    int c = threadIdx.x & 63, g = threadIdx.x >> 6;
    float sH = 0.f, sQ = 0.f;
    for (int b = g; b < KB1; b += 4) { sH += PH[b*64 + c]; sQ += PQ[b*64 + c]; }
    LH[g][c] = sH; LQ[g][c] = sQ;
    __syncthreads();
    if (g == 0) {
        const float invN = 1.0f / (float)NPTS;
        float mn = (LH[0][c] + LH[1][c] + LH[2][c] + LH[3][c]) * invN;
        float vr = (LQ[0][c] + LQ[1][c] + LQ[2][c] + LQ[3][c]) * invN - mn * mn;
        float s = bn1g[c] * rsqrtf(vr + EPSV);
        float t = bn1b[c] - mn * s;
        for (int j = 0; j < 13; j++) Wf2[j*64 + c] = s * Wf[j*64 + c];
        bf2[c] = s * bfv[c] + t;
    }
}

// ---------------- BN2 stats (layer 1+2), optionally store h (CSR order) -----
template <typename HT>
__global__ __launch_bounds__(256, 3) void k4_stats2(
    const float4* __restrict__ pts, const float* __restrict__ nor,
    const int* __restrict__ gind, const int* __restrict__ cinv,
    const float4* __restrict__ vox4,
    const float* __restrict__ Wfp, const float* __restrict__ bfv,
    const float* __restrict__ w2, const float* __restrict__ b2,
    const int* __restrict__ sidx, HT* __restrict__ hout,
    float* __restrict__ PH, float* __restrict__ PQ)
{
    int lane = threadIdx.x & 63;
    int w = threadIdx.x >> 6;
    int wid = blockIdx.x * 4 + w;
    int p0 = wid * W2CH, p1 = min(p0 + W2CH, NPTS);
    REP13(DECL_W1)
    float bc = bfv[lane];
    REP64(DECL_W2)
    float b2c = b2[lane];
    float sh = 0.f, sq = 0.f;
    for (int p = p0; p < p1; p++) {
        FEAT_GATHER
        float r = fmaxf(L1EXPR, 0.f);
        float ha = b2c, hb = 0.f, hc = 0.f, hd = 0.f;
        L2ALL
        float h = (ha + hb) + (hc + hd);
        if (hout) hout[(size_t)sidx[p] * 64 + lane] = (HT)h;
        sh += h; sq += h * h;
    }
    __shared__ float LH[4][64], LQ[4][64];
    LH[w][lane] = sh; LQ[w][lane] = sq;
    __syncthreads();
    if (w == 0) {
        PH[blockIdx.x * 64 + lane] = LH[0][lane] + LH[1][lane] + LH[2][lane] + LH[3][lane];
        PQ[blockIdx.x * 64 + lane] = LQ[0][lane] + LQ[1][lane] + LQ[2][lane] + LQ[3][lane];
    }
}

// ---------------- reduce + finalize BN2 ----------------
__global__ __launch_bounds__(256) void k5_bn2(
    const float* __restrict__ PH, const float* __restrict__ PQ,
    const float* __restrict__ bn2g, const float* __restrict__ bn2b,
    float* __restrict__ s2, float* __restrict__ t2)
{
    __shared__ float LH[4][64], LQ[4][64];
    int c = threadIdx.x & 63, g = threadIdx.x >> 6;
    float sH = 0.f, sQ = 0.f;
    for (int b = g; b < KB2; b += 4) { sH += PH[b*64 + c]; sQ += PQ[b*64 + c]; }
    LH[g][c] = sH; LQ[g][c] = sQ;
    __syncthreads();
    if (g == 0) {
        const float invN = 1.0f / (float)NPTS;
        float mn = (LH[0][c] + LH[1][c] + LH[2][c] + LH[3][c]) * invN;
        float vr = (LQ[0][c] + LQ[1][c] + LQ[2][c] + LQ[3][c]) * invN - mn * mn;
        float s = bn2g[c] * rsqrtf(vr + EPSV);
        s2[c] = s; t2[c] = bn2b[c] - mn * s;
    }
}

// -------- FAST PATH k6: stream stored h (CSR order), BN2+relu+segsum,
//          fuse mean + w3 matmul + bias (replaces k6_gather AND k7_final) ----
template <typename HT>
__global__ __launch_bounds__(256, 4) void k6_stream(
    const int* __restrict__ base, const HT* __restrict__ h,
    const float* __restrict__ s2, const float* __restrict__ t2,
    const float* __restrict__ w3, const float* __restrict__ b3,
    float* __restrict__ out)
{
    int lane = threadIdx.x & 63;
    int wid = blockIdx.x * 4 + (threadIdx.x >> 6);
    int v0 = wid * V6SCH;
    if (v0 >= NVOX) return;
    int v1 = min(v0 + V6SCH, NVOX);
    REP64(DECL_W3)
    float b3c = b3[lane];
    float s2c = s2[lane], t2c = t2[lane];
    int st = (v0 == 0) ? 0 : base[v0 - 1];
    for (int v = v0; v < v1; v++) {
        int en = base[v];
        int c = en - st;
        const HT* hp = h + (size_t)st * 64 + lane;
        float accz = 0.f;
        int ii = 0;
        // unroll-4 with independent loads
        for (; ii + 3 < c; ii += 4) {
            float h0 = (float)hp[(size_t)(ii + 0) * 64];
            float h1 = (float)hp[(size_t)(ii + 1) * 64];
            float h2v = (float)hp[(size_t)(ii + 2) * 64];
            float h3v = (float)hp[(size_t)(ii + 3) * 64];
            accz += fmaxf(s2c * h0 + t2c, 0.f);
            accz += fmaxf(s2c * h1 + t2c, 0.f);
            accz += fmaxf(s2c * h2v + t2c, 0.f);
            accz += fmaxf(s2c * h3v + t2c, 0.f);
        }
        for (; ii < c; ii++)
            accz += fmaxf(s2c * (float)hp[(size_t)ii * 64] + t2c, 0.f);
        float* row = out + (size_t)v * 64;
        if (c > 0) {
            float m = accz / (float)c;
            float ya = b3c, yb = 0.f, yc = 0.f, yd = 0.f;
            L3ALL
            row[lane] = (ya + yb) + (yc + yd);
        } else {
            row[lane] = 0.f;
        }
        st = en;
    }
}

// ---- FALLBACK PATH: main forward + per-voxel sum (wave per voxel, CSR) -----
__global__ __launch_bounds__(256, 3) void k6_gather(
    const float4* __restrict__ pts, const float* __restrict__ nor,
    const int* __restrict__ gind,
    const int* __restrict__ base, const int* __restrict__ pidx,
    const float4* __restrict__ vox4,
    const float* __restrict__ Wfp, const float* __restrict__ bfv,
    const float* __restrict__ w2, const float* __restrict__ b2,
    const float* __restrict__ s2, const float* __restrict__ t2,
    float* __restrict__ out)
{
    int lane = threadIdx.x & 63;
    int wid = blockIdx.x * 4 + (threadIdx.x >> 6);
    int v0 = wid * V6CH, v1 = min(v0 + V6CH, NVOX);
    REP13(DECL_W1)
    float bc = bfv[lane];
    REP64(DECL_W2)
    float b2c = b2[lane];
    float s2c = s2[lane], t2c = t2[lane];

    for (int v = v0; v < v1; v++) {
        int st = (v == 0) ? 0 : base[v - 1];
        int en = base[v];
        float4 vs = vox4[v];
        float accz = 0.f;
        for (int ii = st; ii < en; ii++) {
            int p = pidx[ii];
            FEAT_BODY
            float r = fmaxf(L1EXPR, 0.f);
            float ha = b2c, hb = 0.f, hc = 0.f, hd = 0.f;
            L2ALL
            float h = (ha + hb) + (hc + hd);
            accz += fmaxf(s2c * h + t2c, 0.f);
        }
        out[(size_t)v * 64 + lane] = accz;
    }
}

// ---------- mean + w3 matmul + bias (in-place on d_out) — fallback only -----
__global__ __launch_bounds__(256, 3) void k7_final(
    const float4* __restrict__ vox4, const float* __restrict__ w3,
    const float* __restrict__ b3, float* __restrict__ out)
{
    int lane = threadIdx.x & 63;
    int wid = blockIdx.x * 4 + (threadIdx.x >> 6);
    int v0 = wid * V7CH, v1 = min(v0 + V7CH, NVOX);
    REP64(DECL_W3)
    float b3c = b3[lane];
    for (int v = v0; v < v1; v++) {
        float cnt = vox4[v].w;
        float* row = out + (size_t)v * 64;
        if (cnt > 0.5f) {
            float m = row[lane] / cnt;
            float ya = b3c, yb = 0.f, yc = 0.f, yd = 0.f;
            L3ALL
            row[lane] = (ya + yb) + (yc + yd);
        } else {
            row[lane] = 0.f;
        }
    }
}

extern "C" void kernel_launch(void* const* d_in, const int* in_sizes, int n_in,
                              void* d_out, int out_size, void* d_ws, size_t ws_size,
                              hipStream_t stream) {
    const float4* pts  = (const float4*)d_in[0];
    const float*  nor  = (const float*)d_in[1];
    const int*    gind = (const int*)d_in[2];
    const int*    cinv = (const int*)d_in[3];
    const float*  bn0g = (const float*)d_in[4];
    const float*  bn0b = (const float*)d_in[5];
    const float*  w1   = (const float*)d_in[6];
    const float*  b1   = (const float*)d_in[7];
    const float*  bn1g = (const float*)d_in[8];
    const float*  bn1b = (const float*)d_in[9];
    const float*  w2   = (const float*)d_in[10];
    const float*  b2   = (const float*)d_in[11];
    const float*  bn2g = (const float*)d_in[12];
    const float*  bn2b = (const float*)d_in[13];
    const float*  w3   = (const float*)d_in[14];
    const float*  b3   = (const float*)d_in[15];

    float* ws  = (float*)d_ws;
    float* out = (float*)d_out;

    // tier select: 2 = fp32-h fast, 1 = fp16-h fast, 0 = recompute fallback
    int tier = 0;
    if (ws_size >= NEED_F32_BYTES)      tier = 2;
    else if (ws_size >= NEED_F16_BYTES) tier = 1;
    const bool fast = tier > 0;

    // per-tier layout
    int*   cnt  = (int*)(ws + (fast ? F_CNT  : OFF_CNT));
    int*   base = (int*)(ws + (fast ? F_BASE : OFF_BASE));
    int*   bsum = (int*)(ws + (fast ? F_BSUM : OFF_BSUM));
    int*   boff = (int*)(ws + (fast ? F_BOFF : OFF_BOFF));
    int*   pidx = (int*)(ws + (fast ? F_PIDX : OFF_PIDX));
    float4* vox4 = (float4*)(ws + (fast ? F_VOX : OFF_VOX));
    float* P0   = ws + (fast ? F_P0  : OFF_P0);
    float* PM   = ws + (fast ? F_PM  : OFF_PM);
    float* PH1  = ws + (fast ? F_PH1 : OFF_PH1);
    float* PQ1  = ws + (fast ? F_PQ1 : OFF_PQ1);
    float* PH2  = ws + (fast ? F_PH2 : OFF_PH2);
    float* PQ2  = ws + (fast ? F_PQ2 : OFF_PQ2);
    float* Wf   = ws + (fast ? F_WF  : OFF_WF);
    float* bfv  = ws + (fast ? F_BF  : OFF_BF);
    float* Wf2  = ws + (fast ? F_WF2 : OFF_WF2);
    float* bf2  = ws + (fast ? F_BF2 : OFF_BF2);
    float* s2   = ws + (fast ? F_S2  : OFF_S2);
    float* t2   = ws + (fast ? F_T2  : OFF_T2);
    int*   sidx = fast ? (int*)(ws + F_SIDX) : (int*)nullptr;
    void*  hbuf = fast ? (void*)(ws + F_H)   : nullptr;

    hipMemsetAsync(cnt, 0, (size_t)ZERO_WORDS * 4, stream);

    k_count<<<(NPTS + 255) / 256, 256, 0, stream>>>(cinv, cnt);
    k_scan1<<<NSCAN, SCAN_B, 0, stream>>>(cnt, base, bsum);
    k_scan2<<<1, SCAN_B, 0, stream>>>(bsum, boff);
    k_base<<<(NVOX + 255) / 256, 256, 0, stream>>>(boff, base);
    k_fill<<<(NPTS + 255) / 256, 256, 0, stream>>>(cinv, base, pidx, sidx);
    k_mean<<<NMB, 256, 0, stream>>>(pts, base, pidx, vox4, PM);
    k_stats0<<<SB0, 256, 0, stream>>>(pts, nor, gind, P0);
    k3b_fold<<<1, 64, 0, stream>>>(P0, PM, bn0g, bn0b, w1, b1, Wf, bfv);
    k2b_stats1<<<KB1, 256, 0, stream>>>(pts, nor, gind, cinv, vox4, Wf, bfv, PH1, PQ1);
    k3c_fold<<<1, 256, 0, stream>>>(PH1, PQ1, bn1g, bn1b, Wf, bfv, Wf2, bf2);

    if (tier == 2) {
        k4_stats2<float><<<KB2, 256, 0, stream>>>(pts, nor, gind, cinv, vox4, Wf2, bf2,
                                                  w2, b2, sidx, (float*)hbuf, PH2, PQ2);
    } else if (tier == 1) {
        k4_stats2<_Float16><<<KB2, 256, 0, stream>>>(pts, nor, gind, cinv, vox4, Wf2, bf2,
                                                     w2, b2, sidx, (_Float16*)hbuf, PH2, PQ2);
    } else {
        k4_stats2<float><<<KB2, 256, 0, stream>>>(pts, nor, gind, cinv, vox4, Wf2, bf2,
                                                  w2, b2, (const int*)nullptr,
                                                  (float*)nullptr, PH2, PQ2);
    }
    k5_bn2<<<1, 256, 0, stream>>>(PH2, PQ2, bn2g, bn2b, s2, t2);
    if (tier == 2) {
        k6_stream<float><<<KB6S, 256, 0, stream>>>(base, (const float*)hbuf, s2, t2, w3, b3, out);
    } else if (tier == 1) {
        k6_stream<_Float16><<<KB6S, 256, 0, stream>>>(base, (const _Float16*)hbuf, s2, t2, w3, b3, out);
    } else {
        k6_gather<<<KB6, 256, 0, stream>>>(pts, nor, gind, base, pidx, vox4,
                                           Wf2, bf2, w2, b2, s2, t2, out);
        k7_final<<<KB7, 256, 0, stream>>>(vox4, w3, b3, out);
    }
}

// Round 8
// 855.598 us; speedup vs baseline: 1.5908x; 1.2813x over previous
//
#include <hip/hip_runtime.h>

#define NPTS 1000000
#define NVOX 200000
#define EPSV 1e-5f

#define KB2 768     // k4 blocks (512 thr = 8 waves each -> 6144 waves, 75%)
#define KB6 768     // k6_gather blocks (fallback)
#define KB7 768     // k7 blocks (fallback)
#define KB6S 1024   // k6_stream blocks (512 thr = 8 waves -> 8192 waves)
#define MOMB 512    // k_mom blocks
#define NMB ((NVOX + 255) / 256)   // 782 (k_mean blocks)

#define W2CH ((NPTS + KB2*8 - 1) / (KB2*8))     // 163 pts/wave (k4)
#define V6CH ((NVOX + KB6*4 - 1) / (KB6*4))     // 66 vox/wave (k6_gather)
#define V7CH ((NVOX + KB7*4 - 1) / (KB7*4))     // 66 vox/wave (k7)
#define V6SCH ((NVOX + KB6S*8 - 1) / (KB6S*8))  // 25 vox/wave (k6_stream)

// ================= ws layouts (4-byte word offsets) =================
// --- compact layout (fallback; ~9.5 MB) ---
#define OFF_CNT    0
#define ZERO_WORDS 200000
#define OFF_BASE   200000
#define OFF_BSUM   400000
#define OFF_BOFF   400512
#define OFF_PIDX   401024
#define OFF_VOX    1401024     // 800000 (16B aligned)
#define OFF_MOM    2201024     // MOMB*104 = 53248
#define OFF_PH2    2254272     // KB2*64 = 49152
#define OFF_PQ2    2303424
#define OFF_WF2    2352576     // 832
#define OFF_BF2    2353408     // 64
#define OFF_S2     2353472
#define OFF_T2     2353536

// --- fast layout: live-through-k6 state first, then h; early-dead blocks
//     (cnt/scan/pidx/mom) overlap the h region (all dead before k4 writes h).
#define F_BASE   0             // 200000   live: scan .. k6_stream
#define F_VOX    200000        // 800000   live: k_mean .. k4 (16B aligned)
#define F_PH2    1000000       // 49152    live: k4 .. k5
#define F_PQ2    1049152       // 49152
#define F_WF2    1098304       // 832
#define F_BF2    1099136       // 64
#define F_S2     1099200       // 64
#define F_T2     1099264       // 64
#define F_SIDX   1099328       // 1000000  live: k_fill .. k4
#define F_H      2099328       // h: fp32 64e6 words / fp16 32e6 words
// early-dead overlay inside h region:
#define F_CNT    2099328       // 200000   k_count..k_scan1
#define F_BSUM   2299328       // 512
#define F_BOFF   2299840       // 512
#define F_PIDX   2300352       // 1000000  k_fill..k_mean
#define F_MOM    3300352       // 53248    k_mom..k_fold_all (ends 3353600)

#define NEED_F32_BYTES ((size_t)(F_H + (size_t)NPTS * 64) * 4)    // 264,397,312 (< proven 264,400,896)
#define NEED_F16_BYTES ((size_t)F_H * 4 + (size_t)NPTS * 64 * 2)  // 136,397,312

#define SCAN_B 512
#define NSCAN ((NVOX + SCAN_B - 1) / SCAN_B)   // 391

// upper-triangle index for 13x13 second-moment (j<=k), 91 entries
#define TRI(j,k) ((j)*13 - (j)*((j)-1)/2 + ((k)-(j)))

__device__ __forceinline__ float bcast(float x, int k) {
    return __int_as_float(__builtin_amdgcn_readlane(__float_as_int(x), k));
}
__device__ __forceinline__ float wave_red(float x) {
#pragma unroll
    for (int o = 32; o > 0; o >>= 1) x += __shfl_down(x, o);
    return x;
}

// ---- macro-generated straight-line register code ----
#define REP13(M) M(0) M(1) M(2) M(3) M(4) M(5) M(6) M(7) M(8) M(9) M(10) M(11) M(12)
#define REP64(M) M(0) M(1) M(2) M(3) M(4) M(5) M(6) M(7) M(8) M(9) \
 M(10) M(11) M(12) M(13) M(14) M(15) M(16) M(17) M(18) M(19) \
 M(20) M(21) M(22) M(23) M(24) M(25) M(26) M(27) M(28) M(29) \
 M(30) M(31) M(32) M(33) M(34) M(35) M(36) M(37) M(38) M(39) \
 M(40) M(41) M(42) M(43) M(44) M(45) M(46) M(47) M(48) M(49) \
 M(50) M(51) M(52) M(53) M(54) M(55) M(56) M(57) M(58) M(59) \
 M(60) M(61) M(62) M(63)

// PIN: opaque the value so LLVM cannot rematerialize the (invariant) load
// inside the loop — without this, all 64 w2 values re-load from L1 per point.
#define DECL_W1(J)  float w1c_##J = Wfp[(J)*64 + lane]; asm("" : "+v"(w1c_##J));
#define DECL_W2(K)  float w2c_##K = w2[(K)*64 + lane];  asm("" : "+v"(w2c_##K));
#define DECL_W3(K)  float w3c_##K = w3[(K)*64 + lane];  asm("" : "+v"(w3c_##K));

// features f0..f12 from point p; expects float4 vs (voxel mean) in scope
#define FEAT_BODY \
    float4 pt = pts[p]; \
    int g0 = gind[3*p], g1 = gind[3*p+1], g2 = gind[3*p+2]; \
    float f0 = pt.x, f1 = pt.y, f2 = pt.z, f3 = pt.w; \
    float f4 = pt.x - vs.x, f5 = pt.y - vs.y, f6 = pt.z - vs.z; \
    float f7 = pt.x - ((float)g0 * 0.2f - 51.2f); \
    float f8 = pt.y - ((float)g1 * 0.2f - 51.2f); \
    float f9 = pt.z - ((float)g2 * 0.2f - 4.0f); \
    float f10 = nor[3*p], f11 = nor[3*p+1], f12 = nor[3*p+2];

#define FEAT_GATHER float4 vs = vox4[cinv[p]]; FEAT_BODY

#define L1EXPR (bc + ((((f0*w1c_0 + f1*w1c_1) + (f2*w1c_2 + f3*w1c_3)) \
              + ((f4*w1c_4 + f5*w1c_5) + (f6*w1c_6 + f7*w1c_7))) \
              + (((f8*w1c_8 + f9*w1c_9) + (f10*w1c_10 + f11*w1c_11)) \
              + f12*w1c_12)))

#define L2G(A,B,C,D) ha += bcast(r,A)*w2c_##A; hb += bcast(r,B)*w2c_##B; \
                     hc += bcast(r,C)*w2c_##C; hd += bcast(r,D)*w2c_##D;
#define L2ALL L2G(0,1,2,3) L2G(4,5,6,7) L2G(8,9,10,11) L2G(12,13,14,15) \
  L2G(16,17,18,19) L2G(20,21,22,23) L2G(24,25,26,27) L2G(28,29,30,31) \
  L2G(32,33,34,35) L2G(36,37,38,39) L2G(40,41,42,43) L2G(44,45,46,47) \
  L2G(48,49,50,51) L2G(52,53,54,55) L2G(56,57,58,59) L2G(60,61,62,63)

#define L3G(A,B,C,D) ya += bcast(m,A)*w3c_##A; yb += bcast(m,B)*w3c_##B; \
                     yc += bcast(m,C)*w3c_##C; yd += bcast(m,D)*w3c_##D;
#define L3ALL L3G(0,1,2,3) L3G(4,5,6,7) L3G(8,9,10,11) L3G(12,13,14,15) \
  L3G(16,17,18,19) L3G(20,21,22,23) L3G(24,25,26,27) L3G(28,29,30,31) \
  L3G(32,33,34,35) L3G(36,37,38,39) L3G(40,41,42,43) L3G(44,45,46,47) \
  L3G(48,49,50,51) L3G(52,53,54,55) L3G(56,57,58,59) L3G(60,61,62,63)

// ---------------- counts ----------------
__global__ __launch_bounds__(256) void k_count(
    const int* __restrict__ cinv, int* __restrict__ cnt)
{
    int i = blockIdx.x * 256 + threadIdx.x;
    if (i < NPTS) atomicAdd(&cnt[cinv[i]], 1);
}

// ---------------- scan ----------------
__global__ __launch_bounds__(SCAN_B) void k_scan1(
    const int* __restrict__ cnt, int* __restrict__ base, int* __restrict__ bsum)
{
    __shared__ int sd[SCAN_B];
    int t = threadIdx.x;
    int v = blockIdx.x * SCAN_B + t;
    int x = (v < NVOX) ? cnt[v] : 0;
    sd[t] = x;
    __syncthreads();
    for (int o = 1; o < SCAN_B; o <<= 1) {
        int y = (t >= o) ? sd[t - o] : 0;
        __syncthreads();
        sd[t] += y;
        __syncthreads();
    }
    if (v < NVOX) base[v] = sd[t] - x;
    if (t == SCAN_B - 1) bsum[blockIdx.x] = sd[t];
}

__global__ __launch_bounds__(SCAN_B) void k_scan2(
    const int* __restrict__ bsum, int* __restrict__ boff)
{
    __shared__ int sd[SCAN_B];
    int t = threadIdx.x;
    int x = (t < NSCAN) ? bsum[t] : 0;
    sd[t] = x;
    __syncthreads();
    for (int o = 1; o < SCAN_B; o <<= 1) {
        int y = (t >= o) ? sd[t - o] : 0;
        __syncthreads();
        sd[t] += y;
        __syncthreads();
    }
    if (t < NSCAN) boff[t] = sd[t] - x;
}

__global__ __launch_bounds__(256) void k_base(
    const int* __restrict__ boff, int* __restrict__ base)
{
    int v = blockIdx.x * 256 + threadIdx.x;
    if (v < NVOX) base[v] += boff[v >> 9];
}

__global__ __launch_bounds__(256) void k_fill(
    const int* __restrict__ cinv, int* __restrict__ base,
    int* __restrict__ pidx, int* __restrict__ sidx)
{
    int i = blockIdx.x * 256 + threadIdx.x;
    if (i >= NPTS) return;
    int slot = atomicAdd(&base[cinv[i]], 1);
    pidx[slot] = i;
    if (sidx) sidx[i] = slot;
}

// ---------------- per-voxel means ----------------
__global__ __launch_bounds__(256, 2) void k_mean(
    const float4* __restrict__ pts, const int* __restrict__ base,
    const int* __restrict__ pidx, float4* __restrict__ vox4)
{
    int v = blockIdx.x * 256 + threadIdx.x;
    if (v >= NVOX) return;
    int st = (v == 0) ? 0 : base[v - 1];
    int en = base[v];
    int c = en - st;
    float sx = 0.f, sy = 0.f, sz = 0.f;
    for (int i = st; i < en; i++) {
        float4 p = pts[pidx[i]];
        sx += p.x; sy += p.y; sz += p.z;
    }
    float fc = (float)c;
    float ic = 1.0f / fmaxf(fc, 1.0f);
    vox4[v] = make_float4(sx * ic, sy * ic, sz * ic, fc);
}

// -------- feature moments: E[f] (13) + E[f f^T] upper-tri (91) -> partials --
__global__ __launch_bounds__(256) void k_mom(
    const float4* __restrict__ pts, const float* __restrict__ nor,
    const int* __restrict__ gind, const int* __restrict__ cinv,
    const float4* __restrict__ vox4, float* __restrict__ MOMP)
{
    const int T = MOMB * 256;
    int tid = blockIdx.x * 256 + threadIdx.x;
    float s[13], q[91];
#pragma unroll
    for (int j = 0; j < 13; j++) s[j] = 0.f;
#pragma unroll
    for (int j = 0; j < 91; j++) q[j] = 0.f;
    for (int i = tid; i < NPTS; i += T) {
        float4 p = pts[i];
        int g0 = gind[3*i], g1 = gind[3*i+1], g2 = gind[3*i+2];
        float n0 = nor[3*i], n1 = nor[3*i+1], n2 = nor[3*i+2];
        float4 vs = vox4[cinv[i]];
        float f[13];
        f[0] = p.x; f[1] = p.y; f[2] = p.z; f[3] = p.w;
        f[4] = p.x - vs.x; f[5] = p.y - vs.y; f[6] = p.z - vs.z;
        f[7] = p.x - ((float)g0 * 0.2f - 51.2f);
        f[8] = p.y - ((float)g1 * 0.2f - 51.2f);
        f[9] = p.z - ((float)g2 * 0.2f - 4.0f);
        f[10] = n0; f[11] = n1; f[12] = n2;
#pragma unroll
        for (int j = 0; j < 13; j++) s[j] += f[j];
#pragma unroll
        for (int j = 0; j < 13; j++)
#pragma unroll
            for (int k = j; k < 13; k++) q[TRI(j,k)] += f[j] * f[k];
    }
#pragma unroll
    for (int j = 0; j < 13; j++) s[j] = wave_red(s[j]);
#pragma unroll
    for (int j = 0; j < 91; j++) q[j] = wave_red(q[j]);
    __shared__ float red[4][104];
    int w = threadIdx.x >> 6, lane = threadIdx.x & 63;
    if (lane == 0) {
#pragma unroll
        for (int j = 0; j < 13; j++) red[w][j] = s[j];
#pragma unroll
        for (int j = 0; j < 91; j++) red[w][13 + j] = q[j];
    }
    __syncthreads();
    int t = threadIdx.x;
    if (t < 104)
        MOMP[blockIdx.x * 104 + t] = red[0][t] + red[1][t] + red[2][t] + red[3][t];
}

// ---- reduce moments; fold BN0 AND BN1 analytically (a = Wt^T f + bt is
//      linear in f => mean/var of a from mu and Cov(f)) -> Wf2, bf2 ----------
__global__ void k_fold_all(
    const float* __restrict__ MOMP,
    const float* __restrict__ bn0g, const float* __restrict__ bn0b,
    const float* __restrict__ w1, const float* __restrict__ b1,
    const float* __restrict__ bn1g, const float* __restrict__ bn1b,
    float* __restrict__ Wf2, float* __restrict__ bf2)
{
    __shared__ float mom[104];
    __shared__ float mu[13];
    __shared__ float C[13][13];
    int t = threadIdx.x;  // 128 threads
    for (int j = t; j < 104; j += 128) {
        float s = 0.f;
        for (int b = 0; b < MOMB; b++) s += MOMP[b * 104 + j];
        mom[j] = s;
    }
    __syncthreads();
    const float invN = 1.0f / (float)NPTS;
    if (t < 13) mu[t] = mom[t] * invN;
    __syncthreads();
    for (int e = t; e < 91; e += 128) {
        int j = 0, r = e;
        while (r >= 13 - j) { r -= 13 - j; j++; }
        int k = j + r;
        float v = mom[13 + e] * invN - mu[j] * mu[k];
        C[j][k] = v; C[k][j] = v;
    }
    __syncthreads();
    if (t < 64) {
        float s0[13], t0[13];
#pragma unroll
        for (int j = 0; j < 13; j++) {
            float sc = bn0g[j] * rsqrtf(C[j][j] + EPSV);
            s0[j] = sc; t0[j] = bn0b[j] - mu[j] * sc;
        }
        float wt[13];
        float bt = b1[t];
#pragma unroll
        for (int j = 0; j < 13; j++) {
            float w = w1[j*64 + t];
            wt[j] = s0[j] * w;
            bt += t0[j] * w;
        }
        float mean1 = bt;
#pragma unroll
        for (int j = 0; j < 13; j++) mean1 += wt[j] * mu[j];
        float var1 = 0.f;
#pragma unroll
        for (int j = 0; j < 13; j++) {
            float acc = 0.f;
#pragma unroll
            for (int k = 0; k < 13; k++) acc += wt[k] * C[j][k];
            var1 += wt[j] * acc;
        }
        float s1 = bn1g[t] * rsqrtf(var1 + EPSV);
        float t1 = bn1b[t] - mean1 * s1;
#pragma unroll
        for (int j = 0; j < 13; j++) Wf2[j*64 + t] = s1 * wt[j];
        bf2[t] = s1 * bt + t1;
    }
}

// ---------------- BN2 stats (layer 1+2), optionally store h (CSR order) -----
// 512 threads = 8 waves/block: KB2*8 = 6144 waves (75% grid occupancy)
template <typename HT>
__global__ __launch_bounds__(512) void k4_stats2(
    const float4* __restrict__ pts, const float* __restrict__ nor,
    const int* __restrict__ gind, const int* __restrict__ cinv,
    const float4* __restrict__ vox4,
    const float* __restrict__ Wfp, const float* __restrict__ bfv,
    const float* __restrict__ w2, const float* __restrict__ b2,
    const int* __restrict__ sidx, HT* __restrict__ hout,
    float* __restrict__ PH, float* __restrict__ PQ)
{
    int lane = threadIdx.x & 63;
    int w = threadIdx.x >> 6;      // 0..7
    int wid = blockIdx.x * 8 + w;
    int p0 = wid * W2CH, p1 = min(p0 + W2CH, NPTS);
    REP13(DECL_W1)
    float bc = bfv[lane];
    REP64(DECL_W2)
    float b2c = b2[lane];
    float sh = 0.f, sq = 0.f;
    for (int p = p0; p < p1; p++) {
        FEAT_GATHER
        float r = fmaxf(L1EXPR, 0.f);
        float ha = b2c, hb = 0.f, hc = 0.f, hd = 0.f;
        L2ALL
        float h = (ha + hb) + (hc + hd);
        if (hout) hout[(size_t)sidx[p] * 64 + lane] = (HT)h;
        sh += h; sq += h * h;
    }
    __shared__ float LH[8][64], LQ[8][64];
    LH[w][lane] = sh; LQ[w][lane] = sq;
    __syncthreads();
    if (w == 0) {
        float a = 0.f, b = 0.f;
#pragma unroll
        for (int x = 0; x < 8; x++) { a += LH[x][lane]; b += LQ[x][lane]; }
        PH[blockIdx.x * 64 + lane] = a;
        PQ[blockIdx.x * 64 + lane] = b;
    }
}

// ---------------- reduce + finalize BN2 ----------------
__global__ __launch_bounds__(256) void k5_bn2(
    const float* __restrict__ PH, const float* __restrict__ PQ,
    const float* __restrict__ bn2g, const float* __restrict__ bn2b,
    float* __restrict__ s2, float* __restrict__ t2)
{
    __shared__ float LH[4][64], LQ[4][64];
    int c = threadIdx.x & 63, g = threadIdx.x >> 6;
    float sH = 0.f, sQ = 0.f;
    for (int b = g; b < KB2; b += 4) { sH += PH[b*64 + c]; sQ += PQ[b*64 + c]; }
    LH[g][c] = sH; LQ[g][c] = sQ;
    __syncthreads();
    if (g == 0) {
        const float invN = 1.0f / (float)NPTS;
        float mn = (LH[0][c] + LH[1][c] + LH[2][c] + LH[3][c]) * invN;
        float vr = (LQ[0][c] + LQ[1][c] + LQ[2][c] + LQ[3][c]) * invN - mn * mn;
        float s = bn2g[c] * rsqrtf(vr + EPSV);
        s2[c] = s; t2[c] = bn2b[c] - mn * s;
    }
}

// -------- FAST PATH k6: stream stored h (CSR order), BN2+relu+segsum,
//          fuse mean + w3 matmul + bias. 512 thr: KB6S*8 = 8192 waves --------
template <typename HT>
__global__ __launch_bounds__(512) void k6_stream(
    const int* __restrict__ base, const HT* __restrict__ h,
    const float* __restrict__ s2, const float* __restrict__ t2,
    const float* __restrict__ w3, const float* __restrict__ b3,
    float* __restrict__ out)
{
    int lane = threadIdx.x & 63;
    int wid = blockIdx.x * 8 + (threadIdx.x >> 6);
    int v0 = wid * V6SCH;
    if (v0 >= NVOX) return;
    int v1 = min(v0 + V6SCH, NVOX);
    REP64(DECL_W3)
    float b3c = b3[lane];
    float s2c = s2[lane], t2c = t2[lane];
    int st = (v0 == 0) ? 0 : base[v0 - 1];
    for (int v = v0; v < v1; v++) {
        int en = base[v];
        int c = en - st;
        const HT* hp = h + (size_t)st * 64 + lane;
        float accz = 0.f;
        int ii = 0;
        for (; ii + 3 < c; ii += 4) {
            float h0 = (float)hp[(size_t)(ii + 0) * 64];
            float h1 = (float)hp[(size_t)(ii + 1) * 64];
            float h2v = (float)hp[(size_t)(ii + 2) * 64];
            float h3v = (float)hp[(size_t)(ii + 3) * 64];
            accz += fmaxf(s2c * h0 + t2c, 0.f);
            accz += fmaxf(s2c * h1 + t2c, 0.f);
            accz += fmaxf(s2c * h2v + t2c, 0.f);
            accz += fmaxf(s2c * h3v + t2c, 0.f);
        }
        for (; ii < c; ii++)
            accz += fmaxf(s2c * (float)hp[(size_t)ii * 64] + t2c, 0.f);
        float* row = out + (size_t)v * 64;
        if (c > 0) {
            float m = accz / (float)c;
            float ya = b3c, yb = 0.f, yc = 0.f, yd = 0.f;
            L3ALL
            row[lane] = (ya + yb) + (yc + yd);
        } else {
            row[lane] = 0.f;
        }
        st = en;
    }
}

// ---- FALLBACK PATH: main forward + per-voxel sum (wave per voxel, CSR) -----
__global__ __launch_bounds__(256, 3) void k6_gather(
    const float4* __restrict__ pts, const float* __restrict__ nor,
    const int* __restrict__ gind,
    const int* __restrict__ base, const int* __restrict__ pidx,
    const float4* __restrict__ vox4,
    const float* __restrict__ Wfp, const float* __restrict__ bfv,
    const float* __restrict__ w2, const float* __restrict__ b2,
    const float* __restrict__ s2, const float* __restrict__ t2,
    float* __restrict__ out)
{
    int lane = threadIdx.x & 63;
    int wid = blockIdx.x * 4 + (threadIdx.x >> 6);
    int v0 = wid * V6CH, v1 = min(v0 + V6CH, NVOX);
    REP13(DECL_W1)
    float bc = bfv[lane];
    REP64(DECL_W2)
    float b2c = b2[lane];
    float s2c = s2[lane], t2c = t2[lane];

    for (int v = v0; v < v1; v++) {
        int st = (v == 0) ? 0 : base[v - 1];
        int en = base[v];
        float4 vs = vox4[v];
        float accz = 0.f;
        for (int ii = st; ii < en; ii++) {
            int p = pidx[ii];
            FEAT_BODY
            float r = fmaxf(L1EXPR, 0.f);
            float ha = b2c, hb = 0.f, hc = 0.f, hd = 0.f;
            L2ALL
            float h = (ha + hb) + (hc + hd);
            accz += fmaxf(s2c * h + t2c, 0.f);
        }
        out[(size_t)v * 64 + lane] = accz;
    }
}

// ---------- mean + w3 matmul + bias (in-place on d_out) — fallback only -----
__global__ __launch_bounds__(256, 3) void k7_final(
    const float4* __restrict__ vox4, const float* __restrict__ w3,
    const float* __restrict__ b3, float* __restrict__ out)
{
    int lane = threadIdx.x & 63;
    int wid = blockIdx.x * 4 + (threadIdx.x >> 6);
    int v0 = wid * V7CH, v1 = min(v0 + V7CH, NVOX);
    REP64(DECL_W3)
    float b3c = b3[lane];
    for (int v = v0; v < v1; v++) {
        float cnt = vox4[v].w;
        float* row = out + (size_t)v * 64;
        if (cnt > 0.5f) {
            float m = row[lane] / cnt;
            float ya = b3c, yb = 0.f, yc = 0.f, yd = 0.f;
            L3ALL
            row[lane] = (ya + yb) + (yc + yd);
        } else {
            row[lane] = 0.f;
        }
    }
}

extern "C" void kernel_launch(void* const* d_in, const int* in_sizes, int n_in,
                              void* d_out, int out_size, void* d_ws, size_t ws_size,
                              hipStream_t stream) {
    const float4* pts  = (const float4*)d_in[0];
    const float*  nor  = (const float*)d_in[1];
    const int*    gind = (const int*)d_in[2];
    const int*    cinv = (const int*)d_in[3];
    const float*  bn0g = (const float*)d_in[4];
    const float*  bn0b = (const float*)d_in[5];
    const float*  w1   = (const float*)d_in[6];
    const float*  b1   = (const float*)d_in[7];
    const float*  bn1g = (const float*)d_in[8];
    const float*  bn1b = (const float*)d_in[9];
    const float*  w2   = (const float*)d_in[10];
    const float*  b2   = (const float*)d_in[11];
    const float*  bn2g = (const float*)d_in[12];
    const float*  bn2b = (const float*)d_in[13];
    const float*  w3   = (const float*)d_in[14];
    const float*  b3   = (const float*)d_in[15];

    float* ws  = (float*)d_ws;
    float* out = (float*)d_out;

    // tier select: 2 = fp32-h fast, 1 = fp16-h fast, 0 = recompute fallback
    int tier = 0;
    if (ws_size >= NEED_F32_BYTES)      tier = 2;
    else if (ws_size >= NEED_F16_BYTES) tier = 1;
    const bool fast = tier > 0;

    int*   cnt  = (int*)(ws + (fast ? F_CNT  : OFF_CNT));
    int*   base = (int*)(ws + (fast ? F_BASE : OFF_BASE));
    int*   bsum = (int*)(ws + (fast ? F_BSUM : OFF_BSUM));
    int*   boff = (int*)(ws + (fast ? F_BOFF : OFF_BOFF));
    int*   pidx = (int*)(ws + (fast ? F_PIDX : OFF_PIDX));
    float4* vox4 = (float4*)(ws + (fast ? F_VOX : OFF_VOX));
    float* MOMP = ws + (fast ? F_MOM : OFF_MOM);
    float* PH2  = ws + (fast ? F_PH2 : OFF_PH2);
    float* PQ2  = ws + (fast ? F_PQ2 : OFF_PQ2);
    float* Wf2  = ws + (fast ? F_WF2 : OFF_WF2);
    float* bf2  = ws + (fast ? F_BF2 : OFF_BF2);
    float* s2   = ws + (fast ? F_S2  : OFF_S2);
    float* t2   = ws + (fast ? F_T2  : OFF_T2);
    int*   sidx = fast ? (int*)(ws + F_SIDX) : (int*)nullptr;
    void*  hbuf = fast ? (void*)(ws + F_H)   : nullptr;

    hipMemsetAsync(cnt, 0, (size_t)ZERO_WORDS * 4, stream);

    k_count<<<(NPTS + 255) / 256, 256, 0, stream>>>(cinv, cnt);
    k_scan1<<<NSCAN, SCAN_B, 0, stream>>>(cnt, base, bsum);
    k_scan2<<<1, SCAN_B, 0, stream>>>(bsum, boff);
    k_base<<<(NVOX + 255) / 256, 256, 0, stream>>>(boff, base);
    k_fill<<<(NPTS + 255) / 256, 256, 0, stream>>>(cinv, base, pidx, sidx);
    k_mean<<<NMB, 256, 0, stream>>>(pts, base, pidx, vox4);
    k_mom<<<MOMB, 256, 0, stream>>>(pts, nor, gind, cinv, vox4, MOMP);
    k_fold_all<<<1, 128, 0, stream>>>(MOMP, bn0g, bn0b, w1, b1, bn1g, bn1b, Wf2, bf2);

    if (tier == 2) {
        k4_stats2<float><<<KB2, 512, 0, stream>>>(pts, nor, gind, cinv, vox4, Wf2, bf2,
                                                  w2, b2, sidx, (float*)hbuf, PH2, PQ2);
    } else if (tier == 1) {
        k4_stats2<_Float16><<<KB2, 512, 0, stream>>>(pts, nor, gind, cinv, vox4, Wf2, bf2,
                                                     w2, b2, sidx, (_Float16*)hbuf, PH2, PQ2);
    } else {
        k4_stats2<float><<<KB2, 512, 0, stream>>>(pts, nor, gind, cinv, vox4, Wf2, bf2,
                                                  w2, b2, (const int*)nullptr,
                                                  (float*)nullptr, PH2, PQ2);
    }
    k5_bn2<<<1, 256, 0, stream>>>(PH2, PQ2, bn2g, bn2b, s2, t2);
    if (tier == 2) {
        k6_stream<float><<<KB6S, 512, 0, stream>>>(base, (const float*)hbuf, s2, t2, w3, b3, out);
    } else if (tier == 1) {
        k6_stream<_Float16><<<KB6S, 512, 0, stream>>>(base, (const _Float16*)hbuf, s2, t2, w3, b3, out);
    } else {
        k6_gather<<<KB6, 256, 0, stream>>>(pts, nor, gind, base, pidx, vox4,
                                           Wf2, bf2, w2, b2, s2, t2, out);
        k7_final<<<KB7, 256, 0, stream>>>(vox4, w3, b3, out);
    }
}

// Round 12
// 823.206 us; speedup vs baseline: 1.6534x; 1.0393x over previous
//
#include <hip/hip_runtime.h>

#define NPTS 1000000
#define NVOX 200000
#define EPSV 1e-5f

#define KB2 712     // k4 blocks (512 thr = 8 waves). W2CH=176 (16-divisible!)
#define KB6 768     // k6_gather blocks (fallback)
#define KB7 768     // k7 blocks (fallback)
#define KB6S 1024   // k6_stream blocks (512 thr = 8 waves)
#define MOMB 512    // k_mom blocks
#define NMB ((NVOX + 255) / 256)   // 782 (k_mean blocks)

#define W2CH ((NPTS + KB2*8 - 1) / (KB2*8))     // 176 pts/wave (k4); 176%16==0
#define V6CH ((NVOX + KB6*4 - 1) / (KB6*4))     // 66 vox/wave (k6_gather)
#define V7CH ((NVOX + KB7*4 - 1) / (KB7*4))     // 66 vox/wave (k7)
#define V6SCH ((NVOX + KB6S*8 - 1) / (KB6S*8))  // 25 vox/wave (k6_stream)

// NOTE: NPTS%16==0 and W2CH%16==0 => every wave's [p0,p1) chunk is a
// multiple of 16 -> all MFMA batches are full, no mask path needed.

// ================= ws layouts (4-byte word offsets) =================
// --- compact layout (fallback; ~9.5 MB) ---
#define OFF_CNT    0
#define ZERO_WORDS 200000
#define OFF_BASE   200000
#define OFF_BSUM   400000
#define OFF_BOFF   400512
#define OFF_PIDX   401024
#define OFF_VOX    1401024     // 800000 (16B aligned)
#define OFF_MOM    2201024     // MOMB*104 = 53248
#define OFF_PH2    2254272     // KB2*64 <= 49152
#define OFF_PQ2    2303424
#define OFF_WF2    2352576     // 832
#define OFF_BF2    2353408     // 64
#define OFF_S2     2353472
#define OFF_T2     2353536

// --- fast layout: live-through-k6 state first, then h; early-dead blocks
//     (cnt/scan/pidx/mom) overlap the h region (dead before k4 writes h). ---
#define F_BASE   0             // 200000   live: scan .. k6_stream
#define F_VOX    200000        // 800000   live: k_mean .. k4 (16B aligned)
#define F_PH2    1000000       // 49152    live: k4 .. k5
#define F_PQ2    1049152       // 49152
#define F_WF2    1098304       // 832
#define F_BF2    1099136       // 64
#define F_S2     1099200       // 64
#define F_T2     1099264       // 64
#define F_SIDX   1099328       // 1000000  live: k_fill .. k4
#define F_H      2099328       // h: fp32 64e6 words / fp16 32e6 words
// early-dead overlay inside h region:
#define F_CNT    2099328       // 200000   k_count..k_scan1
#define F_BSUM   2299328       // 512
#define F_BOFF   2299840       // 512
#define F_PIDX   2300352       // 1000000  k_fill..k_mean
#define F_MOM    3300352       // 53248    k_mom..k_fold_all

#define NEED_F32_BYTES ((size_t)(F_H + (size_t)NPTS * 64) * 4)    // 264,397,312
#define NEED_F16_BYTES ((size_t)F_H * 4 + (size_t)NPTS * 64 * 2)  // 136,397,312

#define SCAN_B 512
#define NSCAN ((NVOX + SCAN_B - 1) / SCAN_B)   // 391

#define TRI(j,k) ((j)*13 - (j)*((j)-1)/2 + ((k)-(j)))

typedef _Float16 f16x8 __attribute__((ext_vector_type(8)));
typedef float f32x4 __attribute__((ext_vector_type(4)));

__device__ __forceinline__ float bcast(float x, int k) {
    return __int_as_float(__builtin_amdgcn_readlane(__float_as_int(x), k));
}
__device__ __forceinline__ float wave_red(float x) {
#pragma unroll
    for (int o = 32; o > 0; o >>= 1) x += __shfl_down(x, o);
    return x;
}

// ---- macro-generated straight-line register code ----
#define REP13(M) M(0) M(1) M(2) M(3) M(4) M(5) M(6) M(7) M(8) M(9) M(10) M(11) M(12)
#define REP64(M) M(0) M(1) M(2) M(3) M(4) M(5) M(6) M(7) M(8) M(9) \
 M(10) M(11) M(12) M(13) M(14) M(15) M(16) M(17) M(18) M(19) \
 M(20) M(21) M(22) M(23) M(24) M(25) M(26) M(27) M(28) M(29) \
 M(30) M(31) M(32) M(33) M(34) M(35) M(36) M(37) M(38) M(39) \
 M(40) M(41) M(42) M(43) M(44) M(45) M(46) M(47) M(48) M(49) \
 M(50) M(51) M(52) M(53) M(54) M(55) M(56) M(57) M(58) M(59) \
 M(60) M(61) M(62) M(63)

#define DECL_W1(J)  float w1c_##J = Wfp[(J)*64 + lane]; asm("" : "+v"(w1c_##J));
#define DECL_W2(K)  float w2c_##K = w2[(K)*64 + lane];  asm("" : "+v"(w2c_##K));
#define DECL_W3(K)  float w3c_##K = w3[(K)*64 + lane];  asm("" : "+v"(w3c_##K));

#define FEAT_BODY \
    float4 pt = pts[p]; \
    int g0 = gind[3*p], g1 = gind[3*p+1], g2 = gind[3*p+2]; \
    float f0 = pt.x, f1 = pt.y, f2 = pt.z, f3 = pt.w; \
    float f4 = pt.x - vs.x, f5 = pt.y - vs.y, f6 = pt.z - vs.z; \
    float f7 = pt.x - ((float)g0 * 0.2f - 51.2f); \
    float f8 = pt.y - ((float)g1 * 0.2f - 51.2f); \
    float f9 = pt.z - ((float)g2 * 0.2f - 4.0f); \
    float f10 = nor[3*p], f11 = nor[3*p+1], f12 = nor[3*p+2];

#define FEAT_GATHER float4 vs = vox4[cinv[p]]; FEAT_BODY

#define L1EXPR (bc + ((((f0*w1c_0 + f1*w1c_1) + (f2*w1c_2 + f3*w1c_3)) \
              + ((f4*w1c_4 + f5*w1c_5) + (f6*w1c_6 + f7*w1c_7))) \
              + (((f8*w1c_8 + f9*w1c_9) + (f10*w1c_10 + f11*w1c_11)) \
              + f12*w1c_12)))

#define L2G(A,B,C,D) ha += bcast(r,A)*w2c_##A; hb += bcast(r,B)*w2c_##B; \
                     hc += bcast(r,C)*w2c_##C; hd += bcast(r,D)*w2c_##D;
#define L2ALL L2G(0,1,2,3) L2G(4,5,6,7) L2G(8,9,10,11) L2G(12,13,14,15) \
  L2G(16,17,18,19) L2G(20,21,22,23) L2G(24,25,26,27) L2G(28,29,30,31) \
  L2G(32,33,34,35) L2G(36,37,38,39) L2G(40,41,42,43) L2G(44,45,46,47) \
  L2G(48,49,50,51) L2G(52,53,54,55) L2G(56,57,58,59) L2G(60,61,62,63)

#define L3G(A,B,C,D) ya += bcast(m,A)*w3c_##A; yb += bcast(m,B)*w3c_##B; \
                     yc += bcast(m,C)*w3c_##C; yd += bcast(m,D)*w3c_##D;
#define L3ALL L3G(0,1,2,3) L3G(4,5,6,7) L3G(8,9,10,11) L3G(12,13,14,15) \
  L3G(16,17,18,19) L3G(20,21,22,23) L3G(24,25,26,27) L3G(28,29,30,31) \
  L3G(32,33,34,35) L3G(36,37,38,39) L3G(40,41,42,43) L3G(44,45,46,47) \
  L3G(48,49,50,51) L3G(52,53,54,55) L3G(56,57,58,59) L3G(60,61,62,63)

// ---------------- counts ----------------
__global__ __launch_bounds__(256) void k_count(
    const int* __restrict__ cinv, int* __restrict__ cnt)
{
    int i = blockIdx.x * 256 + threadIdx.x;
    if (i < NPTS) atomicAdd(&cnt[cinv[i]], 1);
}

// ---------------- scan ----------------
__global__ __launch_bounds__(SCAN_B) void k_scan1(
    const int* __restrict__ cnt, int* __restrict__ base, int* __restrict__ bsum)
{
    __shared__ int sd[SCAN_B];
    int t = threadIdx.x;
    int v = blockIdx.x * SCAN_B + t;
    int x = (v < NVOX) ? cnt[v] : 0;
    sd[t] = x;
    __syncthreads();
    for (int o = 1; o < SCAN_B; o <<= 1) {
        int y = (t >= o) ? sd[t - o] : 0;
        __syncthreads();
        sd[t] += y;
        __syncthreads();
    }
    if (v < NVOX) base[v] = sd[t] - x;
    if (t == SCAN_B - 1) bsum[blockIdx.x] = sd[t];
}

__global__ __launch_bounds__(SCAN_B) void k_scan2(
    const int* __restrict__ bsum, int* __restrict__ boff)
{
    __shared__ int sd[SCAN_B];
    int t = threadIdx.x;
    int x = (t < NSCAN) ? bsum[t] : 0;
    sd[t] = x;
    __syncthreads();
    for (int o = 1; o < SCAN_B; o <<= 1) {
        int y = (t >= o) ? sd[t - o] : 0;
        __syncthreads();
        sd[t] += y;
        __syncthreads();
    }
    if (t < NSCAN) boff[t] = sd[t] - x;
}

__global__ __launch_bounds__(256) void k_base(
    const int* __restrict__ boff, int* __restrict__ base)
{
    int v = blockIdx.x * 256 + threadIdx.x;
    if (v < NVOX) base[v] += boff[v >> 9];
}

__global__ __launch_bounds__(256) void k_fill(
    const int* __restrict__ cinv, int* __restrict__ base,
    int* __restrict__ pidx, int* __restrict__ sidx)
{
    int i = blockIdx.x * 256 + threadIdx.x;
    if (i >= NPTS) return;
    int slot = atomicAdd(&base[cinv[i]], 1);
    pidx[slot] = i;
    if (sidx) sidx[i] = slot;
}

// ---------------- per-voxel means ----------------
__global__ __launch_bounds__(256, 2) void k_mean(
    const float4* __restrict__ pts, const int* __restrict__ base,
    const int* __restrict__ pidx, float4* __restrict__ vox4)
{
    int v = blockIdx.x * 256 + threadIdx.x;
    if (v >= NVOX) return;
    int st = (v == 0) ? 0 : base[v - 1];
    int en = base[v];
    int c = en - st;
    float sx = 0.f, sy = 0.f, sz = 0.f;
    for (int i = st; i < en; i++) {
        float4 p = pts[pidx[i]];
        sx += p.x; sy += p.y; sz += p.z;
    }
    float fc = (float)c;
    float ic = 1.0f / fmaxf(fc, 1.0f);
    vox4[v] = make_float4(sx * ic, sy * ic, sz * ic, fc);
}

// -------- feature moments: E[f] (13) + E[f f^T] upper-tri (91) -> partials --
__global__ __launch_bounds__(256) void k_mom(
    const float4* __restrict__ pts, const float* __restrict__ nor,
    const int* __restrict__ gind, const int* __restrict__ cinv,
    const float4* __restrict__ vox4, float* __restrict__ MOMP)
{
    const int T = MOMB * 256;
    int tid = blockIdx.x * 256 + threadIdx.x;
    float s[13], q[91];
#pragma unroll
    for (int j = 0; j < 13; j++) s[j] = 0.f;
#pragma unroll
    for (int j = 0; j < 91; j++) q[j] = 0.f;
    for (int i = tid; i < NPTS; i += T) {
        float4 p = pts[i];
        int g0 = gind[3*i], g1 = gind[3*i+1], g2 = gind[3*i+2];
        float n0 = nor[3*i], n1 = nor[3*i+1], n2 = nor[3*i+2];
        float4 vs = vox4[cinv[i]];
        float f[13];
        f[0] = p.x; f[1] = p.y; f[2] = p.z; f[3] = p.w;
        f[4] = p.x - vs.x; f[5] = p.y - vs.y; f[6] = p.z - vs.z;
        f[7] = p.x - ((float)g0 * 0.2f - 51.2f);
        f[8] = p.y - ((float)g1 * 0.2f - 51.2f);
        f[9] = p.z - ((float)g2 * 0.2f - 4.0f);
        f[10] = n0; f[11] = n1; f[12] = n2;
#pragma unroll
        for (int j = 0; j < 13; j++) s[j] += f[j];
#pragma unroll
        for (int j = 0; j < 13; j++)
#pragma unroll
            for (int k = j; k < 13; k++) q[TRI(j,k)] += f[j] * f[k];
    }
#pragma unroll
    for (int j = 0; j < 13; j++) s[j] = wave_red(s[j]);
#pragma unroll
    for (int j = 0; j < 91; j++) q[j] = wave_red(q[j]);
    __shared__ float red[4][104];
    int w = threadIdx.x >> 6, lane = threadIdx.x & 63;
    if (lane == 0) {
#pragma unroll
        for (int j = 0; j < 13; j++) red[w][j] = s[j];
#pragma unroll
        for (int j = 0; j < 91; j++) red[w][13 + j] = q[j];
    }
    __syncthreads();
    int t = threadIdx.x;
    if (t < 104)
        MOMP[blockIdx.x * 104 + t] = red[0][t] + red[1][t] + red[2][t] + red[3][t];
}

// ---- reduce moments; fold BN0 AND BN1 analytically -> Wf2, bf2 -------------
__global__ void k_fold_all(
    const float* __restrict__ MOMP,
    const float* __restrict__ bn0g, const float* __restrict__ bn0b,
    const float* __restrict__ w1, const float* __restrict__ b1,
    const float* __restrict__ bn1g, const float* __restrict__ bn1b,
    float* __restrict__ Wf2, float* __restrict__ bf2)
{
    __shared__ float mom[104];
    __shared__ float mu[13];
    __shared__ float C[13][13];
    int t = threadIdx.x;  // 128 threads
    for (int j = t; j < 104; j += 128) {
        float s = 0.f;
        for (int b = 0; b < MOMB; b++) s += MOMP[b * 104 + j];
        mom[j] = s;
    }
    __syncthreads();
    const float invN = 1.0f / (float)NPTS;
    if (t < 13) mu[t] = mom[t] * invN;
    __syncthreads();
    for (int e = t; e < 91; e += 128) {
        int j = 0, r = e;
        while (r >= 13 - j) { r -= 13 - j; j++; }
        int k = j + r;
        float v = mom[13 + e] * invN - mu[j] * mu[k];
        C[j][k] = v; C[k][j] = v;
    }
    __syncthreads();
    if (t < 64) {
        float s0[13], t0[13];
#pragma unroll
        for (int j = 0; j < 13; j++) {
            float sc = bn0g[j] * rsqrtf(C[j][j] + EPSV);
            s0[j] = sc; t0[j] = bn0b[j] - mu[j] * sc;
        }
        float wt[13];
        float bt = b1[t];
#pragma unroll
        for (int j = 0; j < 13; j++) {
            float w = w1[j*64 + t];
            wt[j] = s0[j] * w;
            bt += t0[j] * w;
        }
        float mean1 = bt;
#pragma unroll
        for (int j = 0; j < 13; j++) mean1 += wt[j] * mu[j];
        float var1 = 0.f;
#pragma unroll
        for (int j = 0; j < 13; j++) {
            float acc = 0.f;
#pragma unroll
            for (int k = 0; k < 13; k++) acc += wt[k] * C[j][k];
            var1 += wt[j] * acc;
        }
        float s1 = bn1g[t] * rsqrtf(var1 + EPSV);
        float t1 = bn1b[t] - mean1 * s1;
#pragma unroll
        for (int j = 0; j < 13; j++) Wf2[j*64 + t] = s1 * wt[j];
        bf2[t] = s1 * bt + t1;
    }
}

// ---------------- k4: L1 in fp32 (exact) + L2 via MFMA fp16 -----------------
// Per wave: 16-point batches. r staged in per-wave LDS [16][80] fp16;
// A-frag: lane l holds A[l&15][(l>>4)*8+j] (m92 contiguous-k layout).
// B-frag (w2 fp16): lane l holds w2[h*32+(l>>4)*8+j][t*16+(l&15)].
// D (m89): lane l, reg r -> row m=(l>>4)*4+r, col c=t*16+(l&15).
template <typename HT>
__global__ __launch_bounds__(512) void k4_stats2(
    const float4* __restrict__ pts, const float* __restrict__ nor,
    const int* __restrict__ gind, const int* __restrict__ cinv,
    const float4* __restrict__ vox4,
    const float* __restrict__ Wfp, const float* __restrict__ bfv,
    const float* __restrict__ w2, const float* __restrict__ b2,
    const int* __restrict__ sidx, HT* __restrict__ hout,
    float* __restrict__ PH, float* __restrict__ PQ)
{
    int lane = threadIdx.x & 63;
    int w = threadIdx.x >> 6;      // 0..7
    int wid = blockIdx.x * 8 + w;
    int p0 = wid * W2CH, p1 = min(p0 + W2CH, NPTS);
    int cl = lane & 15;            // col within 16
    int kg = lane >> 4;            // k-group / row-group

    __shared__ __align__(16) _Float16 RS[8][16 * 80];  // r staging, 2560B/wave
    __shared__ int SLT[8][16];
    __shared__ float LH[8][64], LQ[8][64];

    REP13(DECL_W1)
    float bc = bfv[lane];

    // w2 fragments in fp16: wf[t*2+h]
    f16x8 wf[8];
#pragma unroll
    for (int t = 0; t < 4; t++)
#pragma unroll
        for (int h = 0; h < 2; h++) {
            f16x8 v;
#pragma unroll
            for (int j = 0; j < 8; j++) {
                int k = h * 32 + kg * 8 + j;
                v[j] = (_Float16)w2[k * 64 + t * 16 + cl];
            }
            wf[t * 2 + h] = v;
        }
    float b20 = b2[cl], b21 = b2[16 + cl], b22 = b2[32 + cl], b23 = b2[48 + cl];

    float sh0 = 0.f, sh1 = 0.f, sh2 = 0.f, sh3 = 0.f;
    float sq0 = 0.f, sq1 = 0.f, sq2 = 0.f, sq3 = 0.f;

    _Float16* rs = RS[w];
    int* slt = SLT[w];

    for (int pb = p0; pb < p1; pb += 16) {
        if (sidx) slt[cl] = sidx[pb + cl];
        // r for 16 points (fp32 exact), staged as fp16
        for (int m = 0; m < 16; m++) {
            int p = pb + m;
            FEAT_GATHER
            float r = fmaxf(L1EXPR, 0.f);
            rs[m * 80 + lane] = (_Float16)r;
        }
        const _Float16* arow = rs + cl * 80 + kg * 8;
        f16x8 a0 = *(const f16x8*)(arow);        // k 0..31 slice
        f16x8 a1 = *(const f16x8*)(arow + 32);   // k 32..63 slice
        f32x4 acc0 = {b20, b20, b20, b20};
        f32x4 acc1 = {b21, b21, b21, b21};
        f32x4 acc2 = {b22, b22, b22, b22};
        f32x4 acc3 = {b23, b23, b23, b23};
        acc0 = __builtin_amdgcn_mfma_f32_16x16x32_f16(a0, wf[0], acc0, 0, 0, 0);
        acc0 = __builtin_amdgcn_mfma_f32_16x16x32_f16(a1, wf[1], acc0, 0, 0, 0);
        acc1 = __builtin_amdgcn_mfma_f32_16x16x32_f16(a0, wf[2], acc1, 0, 0, 0);
        acc1 = __builtin_amdgcn_mfma_f32_16x16x32_f16(a1, wf[3], acc1, 0, 0, 0);
        acc2 = __builtin_amdgcn_mfma_f32_16x16x32_f16(a0, wf[4], acc2, 0, 0, 0);
        acc2 = __builtin_amdgcn_mfma_f32_16x16x32_f16(a1, wf[5], acc2, 0, 0, 0);
        acc3 = __builtin_amdgcn_mfma_f32_16x16x32_f16(a0, wf[6], acc3, 0, 0, 0);
        acc3 = __builtin_amdgcn_mfma_f32_16x16x32_f16(a1, wf[7], acc3, 0, 0, 0);
        int s0v = 0, s1v = 0, s2v = 0, s3v = 0;
        if (sidx) {
            s0v = slt[kg * 4 + 0]; s1v = slt[kg * 4 + 1];
            s2v = slt[kg * 4 + 2]; s3v = slt[kg * 4 + 3];
        }
#define TILE_OUT(T, ACC) { \
        float d0 = ACC[0], d1 = ACC[1], d2 = ACC[2], d3 = ACC[3]; \
        sh##T += (d0 + d1) + (d2 + d3); \
        sq##T += (d0*d0 + d1*d1) + (d2*d2 + d3*d3); \
        if (hout) { \
            hout[(size_t)s0v * 64 + (T)*16 + cl] = (HT)d0; \
            hout[(size_t)s1v * 64 + (T)*16 + cl] = (HT)d1; \
            hout[(size_t)s2v * 64 + (T)*16 + cl] = (HT)d2; \
            hout[(size_t)s3v * 64 + (T)*16 + cl] = (HT)d3; \
        } }
        TILE_OUT(0, acc0)
        TILE_OUT(1, acc1)
        TILE_OUT(2, acc2)
        TILE_OUT(3, acc3)
#undef TILE_OUT
    }
    // column totals: combine lanes {l, l^16, l^32, l^48}
#define COLRED(V) { V += __shfl_xor(V, 16); V += __shfl_xor(V, 32); }
    COLRED(sh0) COLRED(sh1) COLRED(sh2) COLRED(sh3)
    COLRED(sq0) COLRED(sq1) COLRED(sq2) COLRED(sq3)
#undef COLRED
    if (lane < 16) {
        LH[w][cl]      = sh0; LH[w][16 + cl] = sh1;
        LH[w][32 + cl] = sh2; LH[w][48 + cl] = sh3;
        LQ[w][cl]      = sq0; LQ[w][16 + cl] = sq1;
        LQ[w][32 + cl] = sq2; LQ[w][48 + cl] = sq3;
    }
    __syncthreads();
    if (w == 0) {
        float a = 0.f, b = 0.f;
#pragma unroll
        for (int x = 0; x < 8; x++) { a += LH[x][lane]; b += LQ[x][lane]; }
        PH[blockIdx.x * 64 + lane] = a;
        PQ[blockIdx.x * 64 + lane] = b;
    }
}

// ---------------- reduce + finalize BN2 ----------------
__global__ __launch_bounds__(256) void k5_bn2(
    const float* __restrict__ PH, const float* __restrict__ PQ,
    const float* __restrict__ bn2g, const float* __restrict__ bn2b,
    float* __restrict__ s2, float* __restrict__ t2)
{
    __shared__ float LH[4][64], LQ[4][64];
    int c = threadIdx.x & 63, g = threadIdx.x >> 6;
    float sH = 0.f, sQ = 0.f;
    for (int b = g; b < KB2; b += 4) { sH += PH[b*64 + c]; sQ += PQ[b*64 + c]; }
    LH[g][c] = sH; LQ[g][c] = sQ;
    __syncthreads();
    if (g == 0) {
        const float invN = 1.0f / (float)NPTS;
        float mn = (LH[0][c] + LH[1][c] + LH[2][c] + LH[3][c]) * invN;
        float vr = (LQ[0][c] + LQ[1][c] + LQ[2][c] + LQ[3][c]) * invN - mn * mn;
        float s = bn2g[c] * rsqrtf(vr + EPSV);
        s2[c] = s; t2[c] = bn2b[c] - mn * s;
    }
}

// -------- FAST PATH k6: stream stored h (CSR order), BN2+relu+segsum,
//          fuse mean + w3 matmul + bias ------------------------------------
template <typename HT>
__global__ __launch_bounds__(512) void k6_stream(
    const int* __restrict__ base, const HT* __restrict__ h,
    const float* __restrict__ s2, const float* __restrict__ t2,
    const float* __restrict__ w3, const float* __restrict__ b3,
    float* __restrict__ out)
{
    int lane = threadIdx.x & 63;
    int wid = blockIdx.x * 8 + (threadIdx.x >> 6);
    int v0 = wid * V6SCH;
    if (v0 >= NVOX) return;
    int v1 = min(v0 + V6SCH, NVOX);
    REP64(DECL_W3)
    float b3c = b3[lane];
    float s2c = s2[lane], t2c = t2[lane];
    int st = (v0 == 0) ? 0 : base[v0 - 1];
    for (int v = v0; v < v1; v++) {
        int en = base[v];
        int c = en - st;
        const HT* hp = h + (size_t)st * 64 + lane;
        float accz = 0.f;
        int ii = 0;
        for (; ii + 3 < c; ii += 4) {
            float h0 = (float)hp[(size_t)(ii + 0) * 64];
            float h1 = (float)hp[(size_t)(ii + 1) * 64];
            float h2v = (float)hp[(size_t)(ii + 2) * 64];
            float h3v = (float)hp[(size_t)(ii + 3) * 64];
            accz += fmaxf(s2c * h0 + t2c, 0.f);
            accz += fmaxf(s2c * h1 + t2c, 0.f);
            accz += fmaxf(s2c * h2v + t2c, 0.f);
            accz += fmaxf(s2c * h3v + t2c, 0.f);
        }
        for (; ii < c; ii++)
            accz += fmaxf(s2c * (float)hp[(size_t)ii * 64] + t2c, 0.f);
        float* row = out + (size_t)v * 64;
        if (c > 0) {
            float m = accz / (float)c;
            float ya = b3c, yb = 0.f, yc = 0.f, yd = 0.f;
            L3ALL
            row[lane] = (ya + yb) + (yc + yd);
        } else {
            row[lane] = 0.f;
        }
        st = en;
    }
}

// ---- FALLBACK PATH: main forward + per-voxel sum (wave per voxel, CSR) -----
__global__ __launch_bounds__(256, 3) void k6_gather(
    const float4* __restrict__ pts, const float* __restrict__ nor,
    const int* __restrict__ gind,
    const int* __restrict__ base, const int* __restrict__ pidx,
    const float4* __restrict__ vox4,
    const float* __restrict__ Wfp, const float* __restrict__ bfv,
    const float* __restrict__ w2, const float* __restrict__ b2,
    const float* __restrict__ s2, const float* __restrict__ t2,
    float* __restrict__ out)
{
    int lane = threadIdx.x & 63;
    int wid = blockIdx.x * 4 + (threadIdx.x >> 6);
    int v0 = wid * V6CH, v1 = min(v0 + V6CH, NVOX);
    REP13(DECL_W1)
    float bc = bfv[lane];
    REP64(DECL_W2)
    float b2c = b2[lane];
    float s2c = s2[lane], t2c = t2[lane];

    for (int v = v0; v < v1; v++) {
        int st = (v == 0) ? 0 : base[v - 1];
        int en = base[v];
        float4 vs = vox4[v];
        float accz = 0.f;
        for (int ii = st; ii < en; ii++) {
            int p = pidx[ii];
            FEAT_BODY
            float r = fmaxf(L1EXPR, 0.f);
            float ha = b2c, hb = 0.f, hc = 0.f, hd = 0.f;
            L2ALL
            float h = (ha + hb) + (hc + hd);
            accz += fmaxf(s2c * h + t2c, 0.f);
        }
        out[(size_t)v * 64 + lane] = accz;
    }
}

// ---------- mean + w3 matmul + bias (in-place on d_out) — fallback only -----
__global__ __launch_bounds__(256, 3) void k7_final(
    const float4* __restrict__ vox4, const float* __restrict__ w3,
    const float* __restrict__ b3, float* __restrict__ out)
{
    int lane = threadIdx.x & 63;
    int wid = blockIdx.x * 4 + (threadIdx.x >> 6);
    int v0 = wid * V7CH, v1 = min(v0 + V7CH, NVOX);
    REP64(DECL_W3)
    float b3c = b3[lane];
    for (int v = v0; v < v1; v++) {
        float cnt = vox4[v].w;
        float* row = out + (size_t)v * 64;
        if (cnt > 0.5f) {
            float m = row[lane] / cnt;
            float ya = b3c, yb = 0.f, yc = 0.f, yd = 0.f;
            L3ALL
            row[lane] = (ya + yb) + (yc + yd);
        } else {
            row[lane] = 0.f;
        }
    }
}

extern "C" void kernel_launch(void* const* d_in, const int* in_sizes, int n_in,
                              void* d_out, int out_size, void* d_ws, size_t ws_size,
                              hipStream_t stream) {
    const float4* pts  = (const float4*)d_in[0];
    const float*  nor  = (const float*)d_in[1];
    const int*    gind = (const int*)d_in[2];
    const int*    cinv = (const int*)d_in[3];
    const float*  bn0g = (const float*)d_in[4];
    const float*  bn0b = (const float*)d_in[5];
    const float*  w1   = (const float*)d_in[6];
    const float*  b1   = (const float*)d_in[7];
    const float*  bn1g = (const float*)d_in[8];
    const float*  bn1b = (const float*)d_in[9];
    const float*  w2   = (const float*)d_in[10];
    const float*  b2   = (const float*)d_in[11];
    const float*  bn2g = (const float*)d_in[12];
    const float*  bn2b = (const float*)d_in[13];
    const float*  w3   = (const float*)d_in[14];
    const float*  b3   = (const float*)d_in[15];

    float* ws  = (float*)d_ws;
    float* out = (float*)d_out;

    // tier select: 2 = fp32-h fast, 1 = fp16-h fast, 0 = recompute fallback
    int tier = 0;
    if (ws_size >= NEED_F32_BYTES)      tier = 2;
    else if (ws_size >= NEED_F16_BYTES) tier = 1;
    const bool fast = tier > 0;

    int*   cnt  = (int*)(ws + (fast ? F_CNT  : OFF_CNT));
    int*   base = (int*)(ws + (fast ? F_BASE : OFF_BASE));
    int*   bsum = (int*)(ws + (fast ? F_BSUM : OFF_BSUM));
    int*   boff = (int*)(ws + (fast ? F_BOFF : OFF_BOFF));
    int*   pidx = (int*)(ws + (fast ? F_PIDX : OFF_PIDX));
    float4* vox4 = (float4*)(ws + (fast ? F_VOX : OFF_VOX));
    float* MOMP = ws + (fast ? F_MOM : OFF_MOM);
    float* PH2  = ws + (fast ? F_PH2 : OFF_PH2);
    float* PQ2  = ws + (fast ? F_PQ2 : OFF_PQ2);
    float* Wf2  = ws + (fast ? F_WF2 : OFF_WF2);
    float* bf2  = ws + (fast ? F_BF2 : OFF_BF2);
    float* s2   = ws + (fast ? F_S2  : OFF_S2);
    float* t2   = ws + (fast ? F_T2  : OFF_T2);
    int*   sidx = fast ? (int*)(ws + F_SIDX) : (int*)nullptr;
    void*  hbuf = fast ? (void*)(ws + F_H)   : nullptr;

    hipMemsetAsync(cnt, 0, (size_t)ZERO_WORDS * 4, stream);

    k_count<<<(NPTS + 255) / 256, 256, 0, stream>>>(cinv, cnt);
    k_scan1<<<NSCAN, SCAN_B, 0, stream>>>(cnt, base, bsum);
    k_scan2<<<1, SCAN_B, 0, stream>>>(bsum, boff);
    k_base<<<(NVOX + 255) / 256, 256, 0, stream>>>(boff, base);
    k_fill<<<(NPTS + 255) / 256, 256, 0, stream>>>(cinv, base, pidx, sidx);
    k_mean<<<NMB, 256, 0, stream>>>(pts, base, pidx, vox4);
    k_mom<<<MOMB, 256, 0, stream>>>(pts, nor, gind, cinv, vox4, MOMP);
    k_fold_all<<<1, 128, 0, stream>>>(MOMP, bn0g, bn0b, w1, b1, bn1g, bn1b, Wf2, bf2);

    if (tier == 2) {
        k4_stats2<float><<<KB2, 512, 0, stream>>>(pts, nor, gind, cinv, vox4, Wf2, bf2,
                                                  w2, b2, sidx, (float*)hbuf, PH2, PQ2);
    } else if (tier == 1) {
        k4_stats2<_Float16><<<KB2, 512, 0, stream>>>(pts, nor, gind, cinv, vox4, Wf2, bf2,
                                                     w2, b2, sidx, (_Float16*)hbuf, PH2, PQ2);
    } else {
        k4_stats2<float><<<KB2, 512, 0, stream>>>(pts, nor, gind, cinv, vox4, Wf2, bf2,
                                                  w2, b2, (const int*)nullptr,
                                                  (float*)nullptr, PH2, PQ2);
    }
    k5_bn2<<<1, 256, 0, stream>>>(PH2, PQ2, bn2g, bn2b, s2, t2);
    if (tier == 2) {
        k6_stream<float><<<KB6S, 512, 0, stream>>>(base, (const float*)hbuf, s2, t2, w3, b3, out);
    } else if (tier == 1) {
        k6_stream<_Float16><<<KB6S, 512, 0, stream>>>(base, (const _Float16*)hbuf, s2, t2, w3, b3, out);
    } else {
        k6_gather<<<KB6, 256, 0, stream>>>(pts, nor, gind, base, pidx, vox4,
                                           Wf2, bf2, w2, b2, s2, t2, out);
        k7_final<<<KB7, 256, 0, stream>>>(vox4, w3, b3, out);
    }
}

// Round 13
// 577.338 us; speedup vs baseline: 2.3575x; 1.4259x over previous
//
#include <hip/hip_runtime.h>

#define NPTS 1000000
#define NVOX 200000
#define EPSV 1e-5f

#define KB2 768     // k4 blocks (512 thr = 8 waves) -> 6144 waves, exactly 3 blocks/CU
#define KB6 768     // k6_gather blocks (fallback)
#define KB7 768     // k7 blocks (fallback)
#define KB6S 1024   // k6_stream blocks (512 thr = 8 waves)
#define MOMB 512    // k_mom blocks
#define NMB ((NVOX + 255) / 256)   // 782 (k_mean blocks)

#define W2CH 176    // pts/wave (k4): 176%16==0; 6144 waves * 176 >= NPTS (trailing waves idle-safe)
#define V6CH ((NVOX + KB6*4 - 1) / (KB6*4))     // 66 vox/wave (k6_gather)
#define V7CH ((NVOX + KB7*4 - 1) / (KB7*4))     // 66 vox/wave (k7)
#define V6SCH ((NVOX + KB6S*8 - 1) / (KB6S*8))  // 25 vox/wave (k6_stream)

// NOTE: NPTS%16==0 and W2CH%16==0 => every wave's [p0,p1) chunk is a
// multiple of 16 -> all MFMA batches are full, no mask path needed.

// ================= ws layouts (4-byte word offsets) =================
// --- compact layout (fallback; ~9.5 MB) ---
#define OFF_CNT    0
#define ZERO_WORDS 200000
#define OFF_BASE   200000
#define OFF_BSUM   400000
#define OFF_BOFF   400512
#define OFF_PIDX   401024
#define OFF_VOX    1401024     // 800000 (16B aligned)
#define OFF_MOM    2201024     // MOMB*104 = 53248
#define OFF_PH2    2254272     // KB2*64 = 49152
#define OFF_PQ2    2303424
#define OFF_WF2    2352576     // 832
#define OFF_BF2    2353408     // 64
#define OFF_S2     2353472
#define OFF_T2     2353536

// --- fast layout: live-through-k6 state first, then h; early-dead blocks
//     (cnt/scan/pidx/mom) overlap the h region (dead before k4 writes h). ---
#define F_BASE   0             // 200000   live: scan .. k6_stream
#define F_VOX    200000        // 800000   live: k_mean .. k4 (16B aligned)
#define F_PH2    1000000       // 49152    live: k4 .. k5
#define F_PQ2    1049152       // 49152
#define F_WF2    1098304       // 832
#define F_BF2    1099136       // 64
#define F_S2     1099200       // 64
#define F_T2     1099264       // 64
#define F_SIDX   1099328       // 1000000  live: k_fill .. k4
#define F_H      2099328       // h: fp32 64e6 words / fp16 32e6 words
// early-dead overlay inside h region:
#define F_CNT    2099328       // 200000   k_count..k_scan1
#define F_BSUM   2299328       // 512
#define F_BOFF   2299840       // 512
#define F_PIDX   2300352       // 1000000  k_fill..k_mean
#define F_MOM    3300352       // 53248    k_mom..k_fold_all

#define NEED_F32_BYTES ((size_t)(F_H + (size_t)NPTS * 64) * 4)    // 264,397,312
#define NEED_F16_BYTES ((size_t)F_H * 4 + (size_t)NPTS * 64 * 2)  // 136,397,312

#define SCAN_B 512
#define NSCAN ((NVOX + SCAN_B - 1) / SCAN_B)   // 391

#define TRI(j,k) ((j)*13 - (j)*((j)-1)/2 + ((k)-(j)))

typedef _Float16 f16x8 __attribute__((ext_vector_type(8)));
typedef float f32x4 __attribute__((ext_vector_type(4)));

__device__ __forceinline__ float bcast(float x, int k) {
    return __int_as_float(__builtin_amdgcn_readlane(__float_as_int(x), k));
}
__device__ __forceinline__ float wave_red(float x) {
#pragma unroll
    for (int o = 32; o > 0; o >>= 1) x += __shfl_down(x, o);
    return x;
}

// ---- macro-generated straight-line register code ----
#define REP13(M) M(0) M(1) M(2) M(3) M(4) M(5) M(6) M(7) M(8) M(9) M(10) M(11) M(12)
#define REP64(M) M(0) M(1) M(2) M(3) M(4) M(5) M(6) M(7) M(8) M(9) \
 M(10) M(11) M(12) M(13) M(14) M(15) M(16) M(17) M(18) M(19) \
 M(20) M(21) M(22) M(23) M(24) M(25) M(26) M(27) M(28) M(29) \
 M(30) M(31) M(32) M(33) M(34) M(35) M(36) M(37) M(38) M(39) \
 M(40) M(41) M(42) M(43) M(44) M(45) M(46) M(47) M(48) M(49) \
 M(50) M(51) M(52) M(53) M(54) M(55) M(56) M(57) M(58) M(59) \
 M(60) M(61) M(62) M(63)

#define DECL_W1(J)  float w1c_##J = Wfp[(J)*64 + lane]; asm("" : "+v"(w1c_##J));
#define DECL_W2(K)  float w2c_##K = w2[(K)*64 + lane];  asm("" : "+v"(w2c_##K));
#define DECL_W3(K)  float w3c_##K = w3[(K)*64 + lane];  asm("" : "+v"(w3c_##K));

#define FEAT_BODY \
    float4 pt = pts[p]; \
    int g0 = gind[3*p], g1 = gind[3*p+1], g2 = gind[3*p+2]; \
    float f0 = pt.x, f1 = pt.y, f2 = pt.z, f3 = pt.w; \
    float f4 = pt.x - vs.x, f5 = pt.y - vs.y, f6 = pt.z - vs.z; \
    float f7 = pt.x - ((float)g0 * 0.2f - 51.2f); \
    float f8 = pt.y - ((float)g1 * 0.2f - 51.2f); \
    float f9 = pt.z - ((float)g2 * 0.2f - 4.0f); \
    float f10 = nor[3*p], f11 = nor[3*p+1], f12 = nor[3*p+2];

#define FEAT_GATHER float4 vs = vox4[cinv[p]]; FEAT_BODY

#define L1EXPR (bc + ((((f0*w1c_0 + f1*w1c_1) + (f2*w1c_2 + f3*w1c_3)) \
              + ((f4*w1c_4 + f5*w1c_5) + (f6*w1c_6 + f7*w1c_7))) \
              + (((f8*w1c_8 + f9*w1c_9) + (f10*w1c_10 + f11*w1c_11)) \
              + f12*w1c_12)))

#define L2G(A,B,C,D) ha += bcast(r,A)*w2c_##A; hb += bcast(r,B)*w2c_##B; \
                     hc += bcast(r,C)*w2c_##C; hd += bcast(r,D)*w2c_##D;
#define L2ALL L2G(0,1,2,3) L2G(4,5,6,7) L2G(8,9,10,11) L2G(12,13,14,15) \
  L2G(16,17,18,19) L2G(20,21,22,23) L2G(24,25,26,27) L2G(28,29,30,31) \
  L2G(32,33,34,35) L2G(36,37,38,39) L2G(40,41,42,43) L2G(44,45,46,47) \
  L2G(48,49,50,51) L2G(52,53,54,55) L2G(56,57,58,59) L2G(60,61,62,63)

#define L3G(A,B,C,D) ya += bcast(m,A)*w3c_##A; yb += bcast(m,B)*w3c_##B; \
                     yc += bcast(m,C)*w3c_##C; yd += bcast(m,D)*w3c_##D;
#define L3ALL L3G(0,1,2,3) L3G(4,5,6,7) L3G(8,9,10,11) L3G(12,13,14,15) \
  L3G(16,17,18,19) L3G(20,21,22,23) L3G(24,25,26,27) L3G(28,29,30,31) \
  L3G(32,33,34,35) L3G(36,37,38,39) L3G(40,41,42,43) L3G(44,45,46,47) \
  L3G(48,49,50,51) L3G(52,53,54,55) L3G(56,57,58,59) L3G(60,61,62,63)

// ---------------- counts ----------------
__global__ __launch_bounds__(256) void k_count(
    const int* __restrict__ cinv, int* __restrict__ cnt)
{
    int i = blockIdx.x * 256 + threadIdx.x;
    if (i < NPTS) atomicAdd(&cnt[cinv[i]], 1);
}

// ---------------- scan ----------------
__global__ __launch_bounds__(SCAN_B) void k_scan1(
    const int* __restrict__ cnt, int* __restrict__ base, int* __restrict__ bsum)
{
    __shared__ int sd[SCAN_B];
    int t = threadIdx.x;
    int v = blockIdx.x * SCAN_B + t;
    int x = (v < NVOX) ? cnt[v] : 0;
    sd[t] = x;
    __syncthreads();
    for (int o = 1; o < SCAN_B; o <<= 1) {
        int y = (t >= o) ? sd[t - o] : 0;
        __syncthreads();
        sd[t] += y;
        __syncthreads();
    }
    if (v < NVOX) base[v] = sd[t] - x;
    if (t == SCAN_B - 1) bsum[blockIdx.x] = sd[t];
}

__global__ __launch_bounds__(SCAN_B) void k_scan2(
    const int* __restrict__ bsum, int* __restrict__ boff)
{
    __shared__ int sd[SCAN_B];
    int t = threadIdx.x;
    int x = (t < NSCAN) ? bsum[t] : 0;
    sd[t] = x;
    __syncthreads();
    for (int o = 1; o < SCAN_B; o <<= 1) {
        int y = (t >= o) ? sd[t - o] : 0;
        __syncthreads();
        sd[t] += y;
        __syncthreads();
    }
    if (t < NSCAN) boff[t] = sd[t] - x;
}

__global__ __launch_bounds__(256) void k_base(
    const int* __restrict__ boff, int* __restrict__ base)
{
    int v = blockIdx.x * 256 + threadIdx.x;
    if (v < NVOX) base[v] += boff[v >> 9];
}

__global__ __launch_bounds__(256) void k_fill(
    const int* __restrict__ cinv, int* __restrict__ base,
    int* __restrict__ pidx, int* __restrict__ sidx)
{
    int i = blockIdx.x * 256 + threadIdx.x;
    if (i >= NPTS) return;
    int slot = atomicAdd(&base[cinv[i]], 1);
    pidx[slot] = i;
    if (sidx) sidx[i] = slot;
}

// ---------------- per-voxel means ----------------
__global__ __launch_bounds__(256, 2) void k_mean(
    const float4* __restrict__ pts, const int* __restrict__ base,
    const int* __restrict__ pidx, float4* __restrict__ vox4)
{
    int v = blockIdx.x * 256 + threadIdx.x;
    if (v >= NVOX) return;
    int st = (v == 0) ? 0 : base[v - 1];
    int en = base[v];
    int c = en - st;
    float sx = 0.f, sy = 0.f, sz = 0.f;
    for (int i = st; i < en; i++) {
        float4 p = pts[pidx[i]];
        sx += p.x; sy += p.y; sz += p.z;
    }
    float fc = (float)c;
    float ic = 1.0f / fmaxf(fc, 1.0f);
    vox4[v] = make_float4(sx * ic, sy * ic, sz * ic, fc);
}

// -------- feature moments: E[f] (13) + E[f f^T] upper-tri (91) -> partials --
__global__ __launch_bounds__(256) void k_mom(
    const float4* __restrict__ pts, const float* __restrict__ nor,
    const int* __restrict__ gind, const int* __restrict__ cinv,
    const float4* __restrict__ vox4, float* __restrict__ MOMP)
{
    const int T = MOMB * 256;
    int tid = blockIdx.x * 256 + threadIdx.x;
    float s[13], q[91];
#pragma unroll
    for (int j = 0; j < 13; j++) s[j] = 0.f;
#pragma unroll
    for (int j = 0; j < 91; j++) q[j] = 0.f;
    for (int i = tid; i < NPTS; i += T) {
        float4 p = pts[i];
        int g0 = gind[3*i], g1 = gind[3*i+1], g2 = gind[3*i+2];
        float n0 = nor[3*i], n1 = nor[3*i+1], n2 = nor[3*i+2];
        float4 vs = vox4[cinv[i]];
        float f[13];
        f[0] = p.x; f[1] = p.y; f[2] = p.z; f[3] = p.w;
        f[4] = p.x - vs.x; f[5] = p.y - vs.y; f[6] = p.z - vs.z;
        f[7] = p.x - ((float)g0 * 0.2f - 51.2f);
        f[8] = p.y - ((float)g1 * 0.2f - 51.2f);
        f[9] = p.z - ((float)g2 * 0.2f - 4.0f);
        f[10] = n0; f[11] = n1; f[12] = n2;
#pragma unroll
        for (int j = 0; j < 13; j++) s[j] += f[j];
#pragma unroll
        for (int j = 0; j < 13; j++)
#pragma unroll
            for (int k = j; k < 13; k++) q[TRI(j,k)] += f[j] * f[k];
    }
#pragma unroll
    for (int j = 0; j < 13; j++) s[j] = wave_red(s[j]);
#pragma unroll
    for (int j = 0; j < 91; j++) q[j] = wave_red(q[j]);
    __shared__ float red[4][104];
    int w = threadIdx.x >> 6, lane = threadIdx.x & 63;
    if (lane == 0) {
#pragma unroll
        for (int j = 0; j < 13; j++) red[w][j] = s[j];
#pragma unroll
        for (int j = 0; j < 91; j++) red[w][13 + j] = q[j];
    }
    __syncthreads();
    int t = threadIdx.x;
    if (t < 104)
        MOMP[blockIdx.x * 104 + t] = red[0][t] + red[1][t] + red[2][t] + red[3][t];
}

// ---- reduce moments; fold BN0 AND BN1 analytically -> Wf2, bf2 -------------
__global__ void k_fold_all(
    const float* __restrict__ MOMP,
    const float* __restrict__ bn0g, const float* __restrict__ bn0b,
    const float* __restrict__ w1, const float* __restrict__ b1,
    const float* __restrict__ bn1g, const float* __restrict__ bn1b,
    float* __restrict__ Wf2, float* __restrict__ bf2)
{
    __shared__ float mom[104];
    __shared__ float mu[13];
    __shared__ float C[13][13];
    int t = threadIdx.x;  // 128 threads
    for (int j = t; j < 104; j += 128) {
        float s = 0.f;
        for (int b = 0; b < MOMB; b++) s += MOMP[b * 104 + j];
        mom[j] = s;
    }
    __syncthreads();
    const float invN = 1.0f / (float)NPTS;
    if (t < 13) mu[t] = mom[t] * invN;
    __syncthreads();
    for (int e = t; e < 91; e += 128) {
        int j = 0, r = e;
        while (r >= 13 - j) { r -= 13 - j; j++; }
        int k = j + r;
        float v = mom[13 + e] * invN - mu[j] * mu[k];
        C[j][k] = v; C[k][j] = v;
    }
    __syncthreads();
    if (t < 64) {
        float s0[13], t0[13];
#pragma unroll
        for (int j = 0; j < 13; j++) {
            float sc = bn0g[j] * rsqrtf(C[j][j] + EPSV);
            s0[j] = sc; t0[j] = bn0b[j] - mu[j] * sc;
        }
        float wt[13];
        float bt = b1[t];
#pragma unroll
        for (int j = 0; j < 13; j++) {
            float w = w1[j*64 + t];
            wt[j] = s0[j] * w;
            bt += t0[j] * w;
        }
        float mean1 = bt;
#pragma unroll
        for (int j = 0; j < 13; j++) mean1 += wt[j] * mu[j];
        float var1 = 0.f;
#pragma unroll
        for (int j = 0; j < 13; j++) {
            float acc = 0.f;
#pragma unroll
            for (int k = 0; k < 13; k++) acc += wt[k] * C[j][k];
            var1 += wt[j] * acc;
        }
        float s1 = bn1g[t] * rsqrtf(var1 + EPSV);
        float t1 = bn1b[t] - mean1 * s1;
#pragma unroll
        for (int j = 0; j < 13; j++) Wf2[j*64 + t] = s1 * wt[j];
        bf2[t] = s1 * bt + t1;
    }
}

// ---------------- k4: L1 fp32 (exact, LDS-fed) + L2 via MFMA fp16 -----------
// Per batch of 16 points: lanes 0..47 stage ALL batch inputs into LDS with
// ~7 coalesced/parallel VMEM ops (incl. the 16 parallel vox4 gathers); the
// 16-iteration L1 loop then reads only LDS (uniform broadcast). b2 is NOT
// added (h' = h - b2): BN2 stats+apply on h' are algebraically identical.
// A-frag m92 layout; D readout m89: row=(l>>4)*4+r, col=t*16+(l&15).
template <typename HT>
__global__ __launch_bounds__(512) void k4_stats2(
    const float4* __restrict__ pts, const float* __restrict__ nor,
    const int* __restrict__ gind, const int* __restrict__ cinv,
    const float4* __restrict__ vox4,
    const float* __restrict__ Wfp, const float* __restrict__ bfv,
    const float* __restrict__ w2, const float* __restrict__ b2,
    const int* __restrict__ sidx, HT* __restrict__ hout,
    float* __restrict__ PH, float* __restrict__ PQ)
{
    int lane = threadIdx.x & 63;
    int w = threadIdx.x >> 6;      // 0..7
    int wid = blockIdx.x * 8 + w;
    int p0 = wid * W2CH;
    int p1 = min(p0 + W2CH, NPTS);
    int cl = lane & 15;            // col within 16
    int kg = lane >> 4;            // k-group / row-group

    __shared__ __align__(16) _Float16 RS[8][16 * 80];  // r staging, 2560B/wave
    __shared__ int SLT[8][16];
    __shared__ __align__(16) float4 PTSL[8][16];
    __shared__ __align__(16) float4 VOXL[8][16];
    __shared__ float CENL[8][48];
    __shared__ float NORL[8][48];
    __shared__ float LH[8][64], LQ[8][64];

    REP13(DECL_W1)
    float bc = bfv[lane];

    // w2 fragments in fp16: wf[t*2+h]
    f16x8 wf[8];
#pragma unroll
    for (int t = 0; t < 4; t++)
#pragma unroll
        for (int h = 0; h < 2; h++) {
            f16x8 v;
#pragma unroll
            for (int j = 0; j < 8; j++) {
                int k = h * 32 + kg * 8 + j;
                v[j] = (_Float16)w2[k * 64 + t * 16 + cl];
            }
            wf[t * 2 + h] = v;
        }

    float sh0 = 0.f, sh1 = 0.f, sh2 = 0.f, sh3 = 0.f;
    float sq0 = 0.f, sq1 = 0.f, sq2 = 0.f, sq3 = 0.f;

    _Float16* rs = RS[w];
    int* slt = SLT[w];
    float4* ptl = PTSL[w];
    float4* vxl = VOXL[w];
    float* cel = CENL[w];
    float* nol = NORL[w];

    for (int pb = p0; pb < p1; pb += 16) {
        // ---- batch input staging: coalesced / 16-parallel loads ----
        if (lane < 16) {
            int p = pb + lane;
            ptl[lane] = pts[p];
            int cv = cinv[p];
            vxl[lane] = vox4[cv];        // 16 parallel gathers
            if (sidx) slt[lane] = sidx[p];
        }
        if (lane < 48) {
            int gv = gind[3 * pb + lane];        // coalesced 48 dwords
            int comp = lane % 3;
            cel[lane] = (float)gv * 0.2f - ((comp == 2) ? 4.0f : 51.2f);
            nol[lane] = nor[3 * pb + lane];      // coalesced
        }
        // ---- L1 for 16 points (fp32 exact), all inputs from LDS ----
        for (int m = 0; m < 16; m++) {
            float4 pt = ptl[m];
            float4 vs = vxl[m];
            float c0 = cel[3*m], c1 = cel[3*m+1], c2 = cel[3*m+2];
            float f0 = pt.x, f1 = pt.y, f2 = pt.z, f3 = pt.w;
            float f4 = pt.x - vs.x, f5 = pt.y - vs.y, f6 = pt.z - vs.z;
            float f7 = pt.x - c0, f8 = pt.y - c1, f9 = pt.z - c2;
            float f10 = nol[3*m], f11 = nol[3*m+1], f12 = nol[3*m+2];
            float r = fmaxf(L1EXPR, 0.f);
            rs[m * 80 + lane] = (_Float16)r;
        }
        const _Float16* arow = rs + cl * 80 + kg * 8;
        f16x8 a0 = *(const f16x8*)(arow);        // k 0..31 slice
        f16x8 a1 = *(const f16x8*)(arow + 32);   // k 32..63 slice
        f32x4 acc0 = {0.f, 0.f, 0.f, 0.f};
        f32x4 acc1 = {0.f, 0.f, 0.f, 0.f};
        f32x4 acc2 = {0.f, 0.f, 0.f, 0.f};
        f32x4 acc3 = {0.f, 0.f, 0.f, 0.f};
        acc0 = __builtin_amdgcn_mfma_f32_16x16x32_f16(a0, wf[0], acc0, 0, 0, 0);
        acc0 = __builtin_amdgcn_mfma_f32_16x16x32_f16(a1, wf[1], acc0, 0, 0, 0);
        acc1 = __builtin_amdgcn_mfma_f32_16x16x32_f16(a0, wf[2], acc1, 0, 0, 0);
        acc1 = __builtin_amdgcn_mfma_f32_16x16x32_f16(a1, wf[3], acc1, 0, 0, 0);
        acc2 = __builtin_amdgcn_mfma_f32_16x16x32_f16(a0, wf[4], acc2, 0, 0, 0);
        acc2 = __builtin_amdgcn_mfma_f32_16x16x32_f16(a1, wf[5], acc2, 0, 0, 0);
        acc3 = __builtin_amdgcn_mfma_f32_16x16x32_f16(a0, wf[6], acc3, 0, 0, 0);
        acc3 = __builtin_amdgcn_mfma_f32_16x16x32_f16(a1, wf[7], acc3, 0, 0, 0);
        int s0v = 0, s1v = 0, s2v = 0, s3v = 0;
        if (sidx) {
            s0v = slt[kg * 4 + 0]; s1v = slt[kg * 4 + 1];
            s2v = slt[kg * 4 + 2]; s3v = slt[kg * 4 + 3];
        }
#define TILE_OUT(T, ACC) { \
        float d0 = ACC[0], d1 = ACC[1], d2 = ACC[2], d3 = ACC[3]; \
        sh##T += (d0 + d1) + (d2 + d3); \
        sq##T += (d0*d0 + d1*d1) + (d2*d2 + d3*d3); \
        if (hout) { \
            hout[(size_t)s0v * 64 + (T)*16 + cl] = (HT)d0; \
            hout[(size_t)s1v * 64 + (T)*16 + cl] = (HT)d1; \
            hout[(size_t)s2v * 64 + (T)*16 + cl] = (HT)d2; \
            hout[(size_t)s3v * 64 + (T)*16 + cl] = (HT)d3; \
        } }
        TILE_OUT(0, acc0)
        TILE_OUT(1, acc1)
        TILE_OUT(2, acc2)
        TILE_OUT(3, acc3)
#undef TILE_OUT
    }
    // column totals: combine lanes {l, l^16, l^32, l^48}
#define COLRED(V) { V += __shfl_xor(V, 16); V += __shfl_xor(V, 32); }
    COLRED(sh0) COLRED(sh1) COLRED(sh2) COLRED(sh3)
    COLRED(sq0) COLRED(sq1) COLRED(sq2) COLRED(sq3)
#undef COLRED
    if (lane < 16) {
        LH[w][cl]      = sh0; LH[w][16 + cl] = sh1;
        LH[w][32 + cl] = sh2; LH[w][48 + cl] = sh3;
        LQ[w][cl]      = sq0; LQ[w][16 + cl] = sq1;
        LQ[w][32 + cl] = sq2; LQ[w][48 + cl] = sq3;
    }
    __syncthreads();
    if (w == 0) {
        float a = 0.f, b = 0.f;
#pragma unroll
        for (int x = 0; x < 8; x++) { a += LH[x][lane]; b += LQ[x][lane]; }
        PH[blockIdx.x * 64 + lane] = a;
        PQ[blockIdx.x * 64 + lane] = b;
    }
}

// ---------------- reduce + finalize BN2 (stats are of h' = h - b2) ----------
__global__ __launch_bounds__(256) void k5_bn2(
    const float* __restrict__ PH, const float* __restrict__ PQ,
    const float* __restrict__ bn2g, const float* __restrict__ bn2b,
    float* __restrict__ s2, float* __restrict__ t2)
{
    __shared__ float LH[4][64], LQ[4][64];
    int c = threadIdx.x & 63, g = threadIdx.x >> 6;
    float sH = 0.f, sQ = 0.f;
    for (int b = g; b < KB2; b += 4) { sH += PH[b*64 + c]; sQ += PQ[b*64 + c]; }
    LH[g][c] = sH; LQ[g][c] = sQ;
    __syncthreads();
    if (g == 0) {
        const float invN = 1.0f / (float)NPTS;
        float mn = (LH[0][c] + LH[1][c] + LH[2][c] + LH[3][c]) * invN;
        float vr = (LQ[0][c] + LQ[1][c] + LQ[2][c] + LQ[3][c]) * invN - mn * mn;
        float s = bn2g[c] * rsqrtf(vr + EPSV);
        s2[c] = s; t2[c] = bn2b[c] - mn * s;
    }
}

// -------- FAST PATH k6: stream stored h' (CSR order), BN2+relu+segsum,
//          fuse mean + w3 matmul + bias ------------------------------------
template <typename HT>
__global__ __launch_bounds__(512) void k6_stream(
    const int* __restrict__ base, const HT* __restrict__ h,
    const float* __restrict__ s2, const float* __restrict__ t2,
    const float* __restrict__ w3, const float* __restrict__ b3,
    float* __restrict__ out)
{
    int lane = threadIdx.x & 63;
    int wid = blockIdx.x * 8 + (threadIdx.x >> 6);
    int v0 = wid * V6SCH;
    if (v0 >= NVOX) return;
    int v1 = min(v0 + V6SCH, NVOX);
    REP64(DECL_W3)
    float b3c = b3[lane];
    float s2c = s2[lane], t2c = t2[lane];
    int st = (v0 == 0) ? 0 : base[v0 - 1];
    for (int v = v0; v < v1; v++) {
        int en = base[v];
        int c = en - st;
        const HT* hp = h + (size_t)st * 64 + lane;
        float accz = 0.f;
        int ii = 0;
        for (; ii + 3 < c; ii += 4) {
            float h0 = (float)hp[(size_t)(ii + 0) * 64];
            float h1 = (float)hp[(size_t)(ii + 1) * 64];
            float h2v = (float)hp[(size_t)(ii + 2) * 64];
            float h3v = (float)hp[(size_t)(ii + 3) * 64];
            accz += fmaxf(s2c * h0 + t2c, 0.f);
            accz += fmaxf(s2c * h1 + t2c, 0.f);
            accz += fmaxf(s2c * h2v + t2c, 0.f);
            accz += fmaxf(s2c * h3v + t2c, 0.f);
        }
        for (; ii < c; ii++)
            accz += fmaxf(s2c * (float)hp[(size_t)ii * 64] + t2c, 0.f);
        float* row = out + (size_t)v * 64;
        if (c > 0) {
            float m = accz / (float)c;
            float ya = b3c, yb = 0.f, yc = 0.f, yd = 0.f;
            L3ALL
            row[lane] = (ya + yb) + (yc + yd);
        } else {
            row[lane] = 0.f;
        }
        st = en;
    }
}

// ---- FALLBACK PATH: recompute h' (no b2; consistent with k5 stats) ---------
__global__ __launch_bounds__(256, 3) void k6_gather(
    const float4* __restrict__ pts, const float* __restrict__ nor,
    const int* __restrict__ gind,
    const int* __restrict__ base, const int* __restrict__ pidx,
    const float4* __restrict__ vox4,
    const float* __restrict__ Wfp, const float* __restrict__ bfv,
    const float* __restrict__ w2, const float* __restrict__ b2,
    const float* __restrict__ s2, const float* __restrict__ t2,
    float* __restrict__ out)
{
    int lane = threadIdx.x & 63;
    int wid = blockIdx.x * 4 + (threadIdx.x >> 6);
    int v0 = wid * V6CH, v1 = min(v0 + V6CH, NVOX);
    REP13(DECL_W1)
    float bc = bfv[lane];
    REP64(DECL_W2)
    float s2c = s2[lane], t2c = t2[lane];

    for (int v = v0; v < v1; v++) {
        int st = (v == 0) ? 0 : base[v - 1];
        int en = base[v];
        float4 vs = vox4[v];
        float accz = 0.f;
        for (int ii = st; ii < en; ii++) {
            int p = pidx[ii];
            FEAT_BODY
            float r = fmaxf(L1EXPR, 0.f);
            float ha = 0.f, hb = 0.f, hc = 0.f, hd = 0.f;
            L2ALL
            float h = (ha + hb) + (hc + hd);
            accz += fmaxf(s2c * h + t2c, 0.f);
        }
        out[(size_t)v * 64 + lane] = accz;
    }
}

// ---------- mean + w3 matmul + bias (in-place on d_out) — fallback only -----
__global__ __launch_bounds__(256, 3) void k7_final(
    const float4* __restrict__ vox4, const float* __restrict__ w3,
    const float* __restrict__ b3, float* __restrict__ out)
{
    int lane = threadIdx.x & 63;
    int wid = blockIdx.x * 4 + (threadIdx.x >> 6);
    int v0 = wid * V7CH, v1 = min(v0 + V7CH, NVOX);
    REP64(DECL_W3)
    float b3c = b3[lane];
    for (int v = v0; v < v1; v++) {
        float cnt = vox4[v].w;
        float* row = out + (size_t)v * 64;
        if (cnt > 0.5f) {
            float m = row[lane] / cnt;
            float ya = b3c, yb = 0.f, yc = 0.f, yd = 0.f;
            L3ALL
            row[lane] = (ya + yb) + (yc + yd);
        } else {
            row[lane] = 0.f;
        }
    }
}

extern "C" void kernel_launch(void* const* d_in, const int* in_sizes, int n_in,
                              void* d_out, int out_size, void* d_ws, size_t ws_size,
                              hipStream_t stream) {
    const float4* pts  = (const float4*)d_in[0];
    const float*  nor  = (const float*)d_in[1];
    const int*    gind = (const int*)d_in[2];
    const int*    cinv = (const int*)d_in[3];
    const float*  bn0g = (const float*)d_in[4];
    const float*  bn0b = (const float*)d_in[5];
    const float*  w1   = (const float*)d_in[6];
    const float*  b1   = (const float*)d_in[7];
    const float*  bn1g = (const float*)d_in[8];
    const float*  bn1b = (const float*)d_in[9];
    const float*  w2   = (const float*)d_in[10];
    const float*  b2   = (const float*)d_in[11];
    const float*  bn2g = (const float*)d_in[12];
    const float*  bn2b = (const float*)d_in[13];
    const float*  w3   = (const float*)d_in[14];
    const float*  b3   = (const float*)d_in[15];

    float* ws  = (float*)d_ws;
    float* out = (float*)d_out;

    // tier select: 2 = fp32-h fast, 1 = fp16-h fast, 0 = recompute fallback
    int tier = 0;
    if (ws_size >= NEED_F32_BYTES)      tier = 2;
    else if (ws_size >= NEED_F16_BYTES) tier = 1;
    const bool fast = tier > 0;

    int*   cnt  = (int*)(ws + (fast ? F_CNT  : OFF_CNT));
    int*   base = (int*)(ws + (fast ? F_BASE : OFF_BASE));
    int*   bsum = (int*)(ws + (fast ? F_BSUM : OFF_BSUM));
    int*   boff = (int*)(ws + (fast ? F_BOFF : OFF_BOFF));
    int*   pidx = (int*)(ws + (fast ? F_PIDX : OFF_PIDX));
    float4* vox4 = (float4*)(ws + (fast ? F_VOX : OFF_VOX));
    float* MOMP = ws + (fast ? F_MOM : OFF_MOM);
    float* PH2  = ws + (fast ? F_PH2 : OFF_PH2);
    float* PQ2  = ws + (fast ? F_PQ2 : OFF_PQ2);
    float* Wf2  = ws + (fast ? F_WF2 : OFF_WF2);
    float* bf2  = ws + (fast ? F_BF2 : OFF_BF2);
    float* s2   = ws + (fast ? F_S2  : OFF_S2);
    float* t2   = ws + (fast ? F_T2  : OFF_T2);
    int*   sidx = fast ? (int*)(ws + F_SIDX) : (int*)nullptr;
    void*  hbuf = fast ? (void*)(ws + F_H)   : nullptr;

    hipMemsetAsync(cnt, 0, (size_t)ZERO_WORDS * 4, stream);

    k_count<<<(NPTS + 255) / 256, 256, 0, stream>>>(cinv, cnt);
    k_scan1<<<NSCAN, SCAN_B, 0, stream>>>(cnt, base, bsum);
    k_scan2<<<1, SCAN_B, 0, stream>>>(bsum, boff);
    k_base<<<(NVOX + 255) / 256, 256, 0, stream>>>(boff, base);
    k_fill<<<(NPTS + 255) / 256, 256, 0, stream>>>(cinv, base, pidx, sidx);
    k_mean<<<NMB, 256, 0, stream>>>(pts, base, pidx, vox4);
    k_mom<<<MOMB, 256, 0, stream>>>(pts, nor, gind, cinv, vox4, MOMP);
    k_fold_all<<<1, 128, 0, stream>>>(MOMP, bn0g, bn0b, w1, b1, bn1g, bn1b, Wf2, bf2);

    if (tier == 2) {
        k4_stats2<float><<<KB2, 512, 0, stream>>>(pts, nor, gind, cinv, vox4, Wf2, bf2,
                                                  w2, b2, sidx, (float*)hbuf, PH2, PQ2);
    } else if (tier == 1) {
        k4_stats2<_Float16><<<KB2, 512, 0, stream>>>(pts, nor, gind, cinv, vox4, Wf2, bf2,
                                                     w2, b2, sidx, (_Float16*)hbuf, PH2, PQ2);
    } else {
        k4_stats2<float><<<KB2, 512, 0, stream>>>(pts, nor, gind, cinv, vox4, Wf2, bf2,
                                                  w2, b2, (const int*)nullptr,
                                                  (float*)nullptr, PH2, PQ2);
    }
    k5_bn2<<<1, 256, 0, stream>>>(PH2, PQ2, bn2g, bn2b, s2, t2);
    if (tier == 2) {
        k6_stream<float><<<KB6S, 512, 0, stream>>>(base, (const float*)hbuf, s2, t2, w3, b3, out);
    } else if (tier == 1) {
        k6_stream<_Float16><<<KB6S, 512, 0, stream>>>(base, (const _Float16*)hbuf, s2, t2, w3, b3, out);
    } else {
        k6_gather<<<KB6, 256, 0, stream>>>(pts, nor, gind, base, pidx, vox4,
                                           Wf2, bf2, w2, b2, s2, t2, out);
        k7_final<<<KB7, 256, 0, stream>>>(vox4, w3, b3, out);
    }
}

// Round 15
// 539.479 us; speedup vs baseline: 2.5229x; 1.0702x over previous
//
#include <hip/hip_runtime.h>

#define NPTS 1000000
#define NVOX 200000
#define EPSV 1e-5f

#define KB2 768     // k4 blocks (512 thr = 8 waves) -> 6144 waves, exactly 3 blocks/CU
#define KB6 768     // k6_gather blocks (fallback)
#define KB7 768     // k7 blocks (fallback)
#define KB6S 1024   // k6_stream blocks (512 thr = 8 waves)
#define MOMB 512    // k_mom blocks
#define NMB ((NVOX + 255) / 256)   // 782 (k_mean blocks)

#define W2CH 176    // pts/wave (k4): 176%16==0; 6144 waves * 176 >= NPTS (trailing waves idle-safe)
#define V6CH ((NVOX + KB6*4 - 1) / (KB6*4))     // 66 vox/wave (k6_gather)
#define V7CH ((NVOX + KB7*4 - 1) / (KB7*4))     // 66 vox/wave (k7)
#define V6SCH ((NVOX + KB6S*8 - 1) / (KB6S*8))  // 25 vox/wave (k6_stream)

// ================= ws layouts (4-byte word offsets) =================
// --- compact layout (fallback; ~9.5 MB) ---
#define OFF_CNT    0
#define ZERO_WORDS 200000
#define OFF_BASE   200000
#define OFF_BSUM   400000
#define OFF_BOFF   400512
#define OFF_PIDX   401024
#define OFF_VOX    1401024     // 800000 (16B aligned)
#define OFF_MOM    2201024     // MOMB*104 = 53248
#define OFF_PH2    2254272     // KB2*64 = 49152
#define OFF_PQ2    2303424
#define OFF_WF2    2352576     // 832
#define OFF_BF2    2353408     // 64
#define OFF_S2     2353472
#define OFF_T2     2353536

// --- fast layout: live-through-k6 state first, then h; early-dead blocks
//     (cnt/scan/pidx/mom) overlap the h region (dead before k4 writes h). ---
#define F_BASE   0             // 200000   live: scan .. k6_stream
#define F_VOX    200000        // 800000   live: k_mean .. k4 (16B aligned)
#define F_PH2    1000000       // 49152    live: k4 .. k5
#define F_PQ2    1049152       // 49152
#define F_WF2    1098304       // 832
#define F_BF2    1099136       // 64
#define F_S2     1099200       // 64
#define F_T2     1099264       // 64
#define F_SIDX   1099328       // 1000000  live: k_fill .. k4
#define F_H      2099328       // h: fp32 64e6 words / fp16 32e6 words
// early-dead overlay inside h region:
#define F_CNT    2099328       // 200000   k_count..k_scan1
#define F_BSUM   2299328       // 512
#define F_BOFF   2299840       // 512
#define F_PIDX   2300352       // 1000000  k_fill..k_mean
#define F_MOM    3300352       // 53248    k_mom..k_fold_all

#define NEED_F32_BYTES ((size_t)(F_H + (size_t)NPTS * 64) * 4)    // 264,397,312
#define NEED_F16_BYTES ((size_t)F_H * 4 + (size_t)NPTS * 64 * 2)  // 136,397,312

#define SCAN_B 512
#define NSCAN ((NVOX + SCAN_B - 1) / SCAN_B)   // 391

#define TRI(j,k) ((j)*13 - (j)*((j)-1)/2 + ((k)-(j)))

typedef _Float16 f16x8 __attribute__((ext_vector_type(8)));
typedef float f32x4 __attribute__((ext_vector_type(4)));

__device__ __forceinline__ float bcast(float x, int k) {
    return __int_as_float(__builtin_amdgcn_readlane(__float_as_int(x), k));
}
__device__ __forceinline__ float wave_red(float x) {
#pragma unroll
    for (int o = 32; o > 0; o >>= 1) x += __shfl_down(x, o);
    return x;
}

// ---- macro-generated straight-line register code ----
#define REP13(M) M(0) M(1) M(2) M(3) M(4) M(5) M(6) M(7) M(8) M(9) M(10) M(11) M(12)
#define REP64(M) M(0) M(1) M(2) M(3) M(4) M(5) M(6) M(7) M(8) M(9) \
 M(10) M(11) M(12) M(13) M(14) M(15) M(16) M(17) M(18) M(19) \
 M(20) M(21) M(22) M(23) M(24) M(25) M(26) M(27) M(28) M(29) \
 M(30) M(31) M(32) M(33) M(34) M(35) M(36) M(37) M(38) M(39) \
 M(40) M(41) M(42) M(43) M(44) M(45) M(46) M(47) M(48) M(49) \
 M(50) M(51) M(52) M(53) M(54) M(55) M(56) M(57) M(58) M(59) \
 M(60) M(61) M(62) M(63)

#define DECL_W1(J)  float w1c_##J = Wfp[(J)*64 + lane]; asm("" : "+v"(w1c_##J));
#define DECL_W2(K)  float w2c_##K = w2[(K)*64 + lane];  asm("" : "+v"(w2c_##K));
#define DECL_W3(K)  float w3c_##K = w3[(K)*64 + lane];  asm("" : "+v"(w3c_##K));

#define FEAT_BODY \
    float4 pt = pts[p]; \
    int g0 = gind[3*p], g1 = gind[3*p+1], g2 = gind[3*p+2]; \
    float f0 = pt.x, f1 = pt.y, f2 = pt.z, f3 = pt.w; \
    float f4 = pt.x - vs.x, f5 = pt.y - vs.y, f6 = pt.z - vs.z; \
    float f7 = pt.x - ((float)g0 * 0.2f - 51.2f); \
    float f8 = pt.y - ((float)g1 * 0.2f - 51.2f); \
    float f9 = pt.z - ((float)g2 * 0.2f - 4.0f); \
    float f10 = nor[3*p], f11 = nor[3*p+1], f12 = nor[3*p+2];

#define FEAT_GATHER float4 vs = vox4[cinv[p]]; FEAT_BODY

#define L1EXPR (bc + ((((f0*w1c_0 + f1*w1c_1) + (f2*w1c_2 + f3*w1c_3)) \
              + ((f4*w1c_4 + f5*w1c_5) + (f6*w1c_6 + f7*w1c_7))) \
              + (((f8*w1c_8 + f9*w1c_9) + (f10*w1c_10 + f11*w1c_11)) \
              + f12*w1c_12)))

#define L2G(A,B,C,D) ha += bcast(r,A)*w2c_##A; hb += bcast(r,B)*w2c_##B; \
                     hc += bcast(r,C)*w2c_##C; hd += bcast(r,D)*w2c_##D;
#define L2ALL L2G(0,1,2,3) L2G(4,5,6,7) L2G(8,9,10,11) L2G(12,13,14,15) \
  L2G(16,17,18,19) L2G(20,21,22,23) L2G(24,25,26,27) L2G(28,29,30,31) \
  L2G(32,33,34,35) L2G(36,37,38,39) L2G(40,41,42,43) L2G(44,45,46,47) \
  L2G(48,49,50,51) L2G(52,53,54,55) L2G(56,57,58,59) L2G(60,61,62,63)

#define L3G(A,B,C,D) ya += bcast(m,A)*w3c_##A; yb += bcast(m,B)*w3c_##B; \
                     yc += bcast(m,C)*w3c_##C; yd += bcast(m,D)*w3c_##D;
#define L3ALL L3G(0,1,2,3) L3G(4,5,6,7) L3G(8,9,10,11) L3G(12,13,14,15) \
  L3G(16,17,18,19) L3G(20,21,22,23) L3G(24,25,26,27) L3G(28,29,30,31) \
  L3G(32,33,34,35) L3G(36,37,38,39) L3G(40,41,42,43) L3G(44,45,46,47) \
  L3G(48,49,50,51) L3G(52,53,54,55) L3G(56,57,58,59) L3G(60,61,62,63)

// ---------------- counts ----------------
__global__ __launch_bounds__(256) void k_count(
    const int* __restrict__ cinv, int* __restrict__ cnt)
{
    int i = blockIdx.x * 256 + threadIdx.x;
    if (i < NPTS) atomicAdd(&cnt[cinv[i]], 1);
}

// ---------------- scan ----------------
__global__ __launch_bounds__(SCAN_B) void k_scan1(
    const int* __restrict__ cnt, int* __restrict__ base, int* __restrict__ bsum)
{
    __shared__ int sd[SCAN_B];
    int t = threadIdx.x;
    int v = blockIdx.x * SCAN_B + t;
    int x = (v < NVOX) ? cnt[v] : 0;
    sd[t] = x;
    __syncthreads();
    for (int o = 1; o < SCAN_B; o <<= 1) {
        int y = (t >= o) ? sd[t - o] : 0;
        __syncthreads();
        sd[t] += y;
        __syncthreads();
    }
    if (v < NVOX) base[v] = sd[t] - x;
    if (t == SCAN_B - 1) bsum[blockIdx.x] = sd[t];
}

__global__ __launch_bounds__(SCAN_B) void k_scan2(
    const int* __restrict__ bsum, int* __restrict__ boff)
{
    __shared__ int sd[SCAN_B];
    int t = threadIdx.x;
    int x = (t < NSCAN) ? bsum[t] : 0;
    sd[t] = x;
    __syncthreads();
    for (int o = 1; o < SCAN_B; o <<= 1) {
        int y = (t >= o) ? sd[t - o] : 0;
        __syncthreads();
        sd[t] += y;
        __syncthreads();
    }
    if (t < NSCAN) boff[t] = sd[t] - x;
}

__global__ __launch_bounds__(256) void k_base(
    const int* __restrict__ boff, int* __restrict__ base)
{
    int v = blockIdx.x * 256 + threadIdx.x;
    if (v < NVOX) base[v] += boff[v >> 9];
}

__global__ __launch_bounds__(256) void k_fill(
    const int* __restrict__ cinv, int* __restrict__ base,
    int* __restrict__ pidx, int* __restrict__ sidx)
{
    int i = blockIdx.x * 256 + threadIdx.x;
    if (i >= NPTS) return;
    int slot = atomicAdd(&base[cinv[i]], 1);
    pidx[slot] = i;
    if (sidx) sidx[i] = slot;
}

// ---------------- per-voxel means ----------------
__global__ __launch_bounds__(256, 2) void k_mean(
    const float4* __restrict__ pts, const int* __restrict__ base,
    const int* __restrict__ pidx, float4* __restrict__ vox4)
{
    int v = blockIdx.x * 256 + threadIdx.x;
    if (v >= NVOX) return;
    int st = (v == 0) ? 0 : base[v - 1];
    int en = base[v];
    int c = en - st;
    float sx = 0.f, sy = 0.f, sz = 0.f;
    for (int i = st; i < en; i++) {
        float4 p = pts[pidx[i]];
        sx += p.x; sy += p.y; sz += p.z;
    }
    float fc = (float)c;
    float ic = 1.0f / fmaxf(fc, 1.0f);
    vox4[v] = make_float4(sx * ic, sy * ic, sz * ic, fc);
}

// -------- feature moments: E[f] (13) + E[f f^T] upper-tri (91) -> partials --
__global__ __launch_bounds__(256) void k_mom(
    const float4* __restrict__ pts, const float* __restrict__ nor,
    const int* __restrict__ gind, const int* __restrict__ cinv,
    const float4* __restrict__ vox4, float* __restrict__ MOMP)
{
    const int T = MOMB * 256;
    int tid = blockIdx.x * 256 + threadIdx.x;
    float s[13], q[91];
#pragma unroll
    for (int j = 0; j < 13; j++) s[j] = 0.f;
#pragma unroll
    for (int j = 0; j < 91; j++) q[j] = 0.f;
    for (int i = tid; i < NPTS; i += T) {
        float4 p = pts[i];
        int g0 = gind[3*i], g1 = gind[3*i+1], g2 = gind[3*i+2];
        float n0 = nor[3*i], n1 = nor[3*i+1], n2 = nor[3*i+2];
        float4 vs = vox4[cinv[i]];
        float f[13];
        f[0] = p.x; f[1] = p.y; f[2] = p.z; f[3] = p.w;
        f[4] = p.x - vs.x; f[5] = p.y - vs.y; f[6] = p.z - vs.z;
        f[7] = p.x - ((float)g0 * 0.2f - 51.2f);
        f[8] = p.y - ((float)g1 * 0.2f - 51.2f);
        f[9] = p.z - ((float)g2 * 0.2f - 4.0f);
        f[10] = n0; f[11] = n1; f[12] = n2;
#pragma unroll
        for (int j = 0; j < 13; j++) s[j] += f[j];
#pragma unroll
        for (int j = 0; j < 13; j++)
#pragma unroll
            for (int k = j; k < 13; k++) q[TRI(j,k)] += f[j] * f[k];
    }
#pragma unroll
    for (int j = 0; j < 13; j++) s[j] = wave_red(s[j]);
#pragma unroll
    for (int j = 0; j < 91; j++) q[j] = wave_red(q[j]);
    __shared__ float red[4][104];
    int w = threadIdx.x >> 6, lane = threadIdx.x & 63;
    if (lane == 0) {
#pragma unroll
        for (int j = 0; j < 13; j++) red[w][j] = s[j];
#pragma unroll
        for (int j = 0; j < 91; j++) red[w][13 + j] = q[j];
    }
    __syncthreads();
    int t = threadIdx.x;
    if (t < 104)
        MOMP[blockIdx.x * 104 + t] = red[0][t] + red[1][t] + red[2][t] + red[3][t];
}

// ---- reduce moments; fold BN0 AND BN1 analytically -> Wf2, bf2 -------------
__global__ void k_fold_all(
    const float* __restrict__ MOMP,
    const float* __restrict__ bn0g, const float* __restrict__ bn0b,
    const float* __restrict__ w1, const float* __restrict__ b1,
    const float* __restrict__ bn1g, const float* __restrict__ bn1b,
    float* __restrict__ Wf2, float* __restrict__ bf2)
{
    __shared__ float mom[104];
    __shared__ float mu[13];
    __shared__ float C[13][13];
    int t = threadIdx.x;  // 128 threads
    for (int j = t; j < 104; j += 128) {
        float s = 0.f;
        for (int b = 0; b < MOMB; b++) s += MOMP[b * 104 + j];
        mom[j] = s;
    }
    __syncthreads();
    const float invN = 1.0f / (float)NPTS;
    if (t < 13) mu[t] = mom[t] * invN;
    __syncthreads();
    for (int e = t; e < 91; e += 128) {
        int j = 0, r = e;
        while (r >= 13 - j) { r -= 13 - j; j++; }
        int k = j + r;
        float v = mom[13 + e] * invN - mu[j] * mu[k];
        C[j][k] = v; C[k][j] = v;
    }
    __syncthreads();
    if (t < 64) {
        float s0[13], t0[13];
#pragma unroll
        for (int j = 0; j < 13; j++) {
            float sc = bn0g[j] * rsqrtf(C[j][j] + EPSV);
            s0[j] = sc; t0[j] = bn0b[j] - mu[j] * sc;
        }
        float wt[13];
        float bt = b1[t];
#pragma unroll
        for (int j = 0; j < 13; j++) {
            float w = w1[j*64 + t];
            wt[j] = s0[j] * w;
            bt += t0[j] * w;
        }
        float mean1 = bt;
#pragma unroll
        for (int j = 0; j < 13; j++) mean1 += wt[j] * mu[j];
        float var1 = 0.f;
#pragma unroll
        for (int j = 0; j < 13; j++) {
            float acc = 0.f;
#pragma unroll
            for (int k = 0; k < 13; k++) acc += wt[k] * C[j][k];
            var1 += wt[j] * acc;
        }
        float s1 = bn1g[t] * rsqrtf(var1 + EPSV);
        float t1 = bn1b[t] - mean1 * s1;
#pragma unroll
        for (int j = 0; j < 13; j++) Wf2[j*64 + t] = s1 * wt[j];
        bf2[t] = s1 * bt + t1;
    }
}

// ---------------- k4: L1 fp32 (exact, LDS-fed) + L2 via MFMA fp16 -----------
// Per batch of 16 points: lanes 0..47 stage ALL batch inputs into LDS with
// ~7 coalesced/parallel VMEM ops; the 16-iteration L1 loop reads only LDS.
// b2 is NOT added (h' = h - b2): BN2 stats+apply on h' are identical.
// A-frag m92 layout; D readout m89: row=(l>>4)*4+r, col=t*16+(l&15).
template <typename HT>
__global__ __launch_bounds__(512) void k4_stats2(
    const float4* __restrict__ pts, const float* __restrict__ nor,
    const int* __restrict__ gind, const int* __restrict__ cinv,
    const float4* __restrict__ vox4,
    const float* __restrict__ Wfp, const float* __restrict__ bfv,
    const float* __restrict__ w2, const float* __restrict__ b2,
    const int* __restrict__ sidx, HT* __restrict__ hout,
    float* __restrict__ PH, float* __restrict__ PQ)
{
    int lane = threadIdx.x & 63;
    int w = threadIdx.x >> 6;      // 0..7
    int wid = blockIdx.x * 8 + w;
    int p0 = wid * W2CH;
    int p1 = min(p0 + W2CH, NPTS);
    int cl = lane & 15;            // col within 16
    int kg = lane >> 4;            // k-group / row-group

    __shared__ __align__(16) _Float16 RS[8][16 * 80];  // r staging, 2560B/wave
    __shared__ int SLT[8][16];
    __shared__ __align__(16) float4 PTSL[8][16];
    __shared__ __align__(16) float4 VOXL[8][16];
    __shared__ float CENL[8][48];
    __shared__ float NORL[8][48];
    __shared__ float LH[8][64], LQ[8][64];

    REP13(DECL_W1)
    float bc = bfv[lane];

    // w2 fragments in fp16: wf[t*2+h]
    f16x8 wf[8];
#pragma unroll
    for (int t = 0; t < 4; t++)
#pragma unroll
        for (int h = 0; h < 2; h++) {
            f16x8 v;
#pragma unroll
            for (int j = 0; j < 8; j++) {
                int k = h * 32 + kg * 8 + j;
                v[j] = (_Float16)w2[k * 64 + t * 16 + cl];
            }
            wf[t * 2 + h] = v;
        }

    float sh0 = 0.f, sh1 = 0.f, sh2 = 0.f, sh3 = 0.f;
    float sq0 = 0.f, sq1 = 0.f, sq2 = 0.f, sq3 = 0.f;

    _Float16* rs = RS[w];
    int* slt = SLT[w];
    float4* ptl = PTSL[w];
    float4* vxl = VOXL[w];
    float* cel = CENL[w];
    float* nol = NORL[w];

    for (int pb = p0; pb < p1; pb += 16) {
        // ---- batch input staging: coalesced / 16-parallel loads ----
        if (lane < 16) {
            int p = pb + lane;
            ptl[lane] = pts[p];
            int cv = cinv[p];
            vxl[lane] = vox4[cv];        // 16 parallel gathers
            if (sidx) slt[lane] = sidx[p];
        }
        if (lane < 48) {
            int gv = gind[3 * pb + lane];        // coalesced 48 dwords
            int comp = lane % 3;
            cel[lane] = (float)gv * 0.2f - ((comp == 2) ? 4.0f : 51.2f);
            nol[lane] = nor[3 * pb + lane];      // coalesced
        }
        // ---- L1 for 16 points (fp32 exact), all inputs from LDS ----
        for (int m = 0; m < 16; m++) {
            float4 pt = ptl[m];
            float4 vs = vxl[m];
            float c0 = cel[3*m], c1 = cel[3*m+1], c2 = cel[3*m+2];
            float f0 = pt.x, f1 = pt.y, f2 = pt.z, f3 = pt.w;
            float f4 = pt.x - vs.x, f5 = pt.y - vs.y, f6 = pt.z - vs.z;
            float f7 = pt.x - c0, f8 = pt.y - c1, f9 = pt.z - c2;
            float f10 = nol[3*m], f11 = nol[3*m+1], f12 = nol[3*m+2];
            float r = fmaxf(L1EXPR, 0.f);
            rs[m * 80 + lane] = (_Float16)r;
        }
        const _Float16* arow = rs + cl * 80 + kg * 8;
        f16x8 a0 = *(const f16x8*)(arow);        // k 0..31 slice
        f16x8 a1 = *(const f16x8*)(arow + 32);   // k 32..63 slice
        f32x4 acc0 = {0.f, 0.f, 0.f, 0.f};
        f32x4 acc1 = {0.f, 0.f, 0.f, 0.f};
        f32x4 acc2 = {0.f, 0.f, 0.f, 0.f};
        f32x4 acc3 = {0.f, 0.f, 0.f, 0.f};
        acc0 = __builtin_amdgcn_mfma_f32_16x16x32_f16(a0, wf[0], acc0, 0, 0, 0);
        acc0 = __builtin_amdgcn_mfma_f32_16x16x32_f16(a1, wf[1], acc0, 0, 0, 0);
        acc1 = __builtin_amdgcn_mfma_f32_16x16x32_f16(a0, wf[2], acc1, 0, 0, 0);
        acc1 = __builtin_amdgcn_mfma_f32_16x16x32_f16(a1, wf[3], acc1, 0, 0, 0);
        acc2 = __builtin_amdgcn_mfma_f32_16x16x32_f16(a0, wf[4], acc2, 0, 0, 0);
        acc2 = __builtin_amdgcn_mfma_f32_16x16x32_f16(a1, wf[5], acc2, 0, 0, 0);
        acc3 = __builtin_amdgcn_mfma_f32_16x16x32_f16(a0, wf[6], acc3, 0, 0, 0);
        acc3 = __builtin_amdgcn_mfma_f32_16x16x32_f16(a1, wf[7], acc3, 0, 0, 0);
        int s0v = 0, s1v = 0, s2v = 0, s3v = 0;
        if (sidx) {
            s0v = slt[kg * 4 + 0]; s1v = slt[kg * 4 + 1];
            s2v = slt[kg * 4 + 2]; s3v = slt[kg * 4 + 3];
        }
#define TILE_OUT(T, ACC) { \
        float d0 = ACC[0], d1 = ACC[1], d2 = ACC[2], d3 = ACC[3]; \
        sh##T += (d0 + d1) + (d2 + d3); \
        sq##T += (d0*d0 + d1*d1) + (d2*d2 + d3*d3); \
        if (hout) { \
            hout[(size_t)s0v * 64 + (T)*16 + cl] = (HT)d0; \
            hout[(size_t)s1v * 64 + (T)*16 + cl] = (HT)d1; \
            hout[(size_t)s2v * 64 + (T)*16 + cl] = (HT)d2; \
            hout[(size_t)s3v * 64 + (T)*16 + cl] = (HT)d3; \
        } }
        TILE_OUT(0, acc0)
        TILE_OUT(1, acc1)
        TILE_OUT(2, acc2)
        TILE_OUT(3, acc3)
#undef TILE_OUT
    }
    // column totals: combine lanes {l, l^16, l^32, l^48}
#define COLRED(V) { V += __shfl_xor(V, 16); V += __shfl_xor(V, 32); }
    COLRED(sh0) COLRED(sh1) COLRED(sh2) COLRED(sh3)
    COLRED(sq0) COLRED(sq1) COLRED(sq2) COLRED(sq3)
#undef COLRED
    if (lane < 16) {
        LH[w][cl]      = sh0; LH[w][16 + cl] = sh1;
        LH[w][32 + cl] = sh2; LH[w][48 + cl] = sh3;
        LQ[w][cl]      = sq0; LQ[w][16 + cl] = sq1;
        LQ[w][32 + cl] = sq2; LQ[w][48 + cl] = sq3;
    }
    __syncthreads();
    if (w == 0) {
        float a = 0.f, b = 0.f;
#pragma unroll
        for (int x = 0; x < 8; x++) { a += LH[x][lane]; b += LQ[x][lane]; }
        PH[blockIdx.x * 64 + lane] = a;
        PQ[blockIdx.x * 64 + lane] = b;
    }
}

// ---------------- reduce + finalize BN2 (stats are of h' = h - b2) ----------
__global__ __launch_bounds__(256) void k5_bn2(
    const float* __restrict__ PH, const float* __restrict__ PQ,
    const float* __restrict__ bn2g, const float* __restrict__ bn2b,
    float* __restrict__ s2, float* __restrict__ t2)
{
    __shared__ float LH[4][64], LQ[4][64];
    int c = threadIdx.x & 63, g = threadIdx.x >> 6;
    float sH = 0.f, sQ = 0.f;
    for (int b = g; b < KB2; b += 4) { sH += PH[b*64 + c]; sQ += PQ[b*64 + c]; }
    LH[g][c] = sH; LQ[g][c] = sQ;
    __syncthreads();
    if (g == 0) {
        const float invN = 1.0f / (float)NPTS;
        float mn = (LH[0][c] + LH[1][c] + LH[2][c] + LH[3][c]) * invN;
        float vr = (LQ[0][c] + LQ[1][c] + LQ[2][c] + LQ[3][c]) * invN - mn * mn;
        float s = bn2g[c] * rsqrtf(vr + EPSV);
        s2[c] = s; t2[c] = bn2b[c] - mn * s;
    }
}

// -------- FAST PATH k6: stream stored h' (CSR order), BN2+relu+segsum,
//          fuse mean + w3 matmul + bias. unroll-8 for MLP -------------------
template <typename HT>
__global__ __launch_bounds__(512) void k6_stream(
    const int* __restrict__ base, const HT* __restrict__ h,
    const float* __restrict__ s2, const float* __restrict__ t2,
    const float* __restrict__ w3, const float* __restrict__ b3,
    float* __restrict__ out)
{
    int lane = threadIdx.x & 63;
    int wid = blockIdx.x * 8 + (threadIdx.x >> 6);
    int v0 = wid * V6SCH;
    if (v0 >= NVOX) return;
    int v1 = min(v0 + V6SCH, NVOX);
    REP64(DECL_W3)
    float b3c = b3[lane];
    float s2c = s2[lane], t2c = t2[lane];
    int st = (v0 == 0) ? 0 : base[v0 - 1];
    for (int v = v0; v < v1; v++) {
        int en = base[v];
        int c = en - st;
        const HT* hp = h + (size_t)st * 64 + lane;
        float accz = 0.f;
        int ii = 0;
        for (; ii + 7 < c; ii += 8) {
            float h0 = (float)hp[(size_t)(ii + 0) * 64];
            float h1 = (float)hp[(size_t)(ii + 1) * 64];
            float h2v = (float)hp[(size_t)(ii + 2) * 64];
            float h3v = (float)hp[(size_t)(ii + 3) * 64];
            float h4 = (float)hp[(size_t)(ii + 4) * 64];
            float h5 = (float)hp[(size_t)(ii + 5) * 64];
            float h6 = (float)hp[(size_t)(ii + 6) * 64];
            float h7 = (float)hp[(size_t)(ii + 7) * 64];
            accz += fmaxf(s2c * h0 + t2c, 0.f);
            accz += fmaxf(s2c * h1 + t2c, 0.f);
            accz += fmaxf(s2c * h2v + t2c, 0.f);
            accz += fmaxf(s2c * h3v + t2c, 0.f);
            accz += fmaxf(s2c * h4 + t2c, 0.f);
            accz += fmaxf(s2c * h5 + t2c, 0.f);
            accz += fmaxf(s2c * h6 + t2c, 0.f);
            accz += fmaxf(s2c * h7 + t2c, 0.f);
        }
        for (; ii < c; ii++)
            accz += fmaxf(s2c * (float)hp[(size_t)ii * 64] + t2c, 0.f);
        float* row = out + (size_t)v * 64;
        if (c > 0) {
            float m = accz / (float)c;
            float ya = b3c, yb = 0.f, yc = 0.f, yd = 0.f;
            L3ALL
            row[lane] = (ya + yb) + (yc + yd);
        } else {
            row[lane] = 0.f;
        }
        st = en;
    }
}

// ---- FALLBACK PATH: recompute h' (no b2; consistent with k5 stats) ---------
__global__ __launch_bounds__(256, 3) void k6_gather(
    const float4* __restrict__ pts, const float* __restrict__ nor,
    const int* __restrict__ gind,
    const int* __restrict__ base, const int* __restrict__ pidx,
    const float4* __restrict__ vox4,
    const float* __restrict__ Wfp, const float* __restrict__ bfv,
    const float* __restrict__ w2, const float* __restrict__ b2,
    const float* __restrict__ s2, const float* __restrict__ t2,
    float* __restrict__ out)
{
    int lane = threadIdx.x & 63;
    int wid = blockIdx.x * 4 + (threadIdx.x >> 6);
    int v0 = wid * V6CH, v1 = min(v0 + V6CH, NVOX);
    REP13(DECL_W1)
    float bc = bfv[lane];
    REP64(DECL_W2)
    float s2c = s2[lane], t2c = t2[lane];

    for (int v = v0; v < v1; v++) {
        int st = (v == 0) ? 0 : base[v - 1];
        int en = base[v];
        float4 vs = vox4[v];
        float accz = 0.f;
        for (int ii = st; ii < en; ii++) {
            int p = pidx[ii];
            FEAT_BODY
            float r = fmaxf(L1EXPR, 0.f);
            float ha = 0.f, hb = 0.f, hc = 0.f, hd = 0.f;
            L2ALL
            float h = (ha + hb) + (hc + hd);
            accz += fmaxf(s2c * h + t2c, 0.f);
        }
        out[(size_t)v * 64 + lane] = accz;
    }
}

// ---------- mean + w3 matmul + bias (in-place on d_out) — fallback only -----
__global__ __launch_bounds__(256, 3) void k7_final(
    const float4* __restrict__ vox4, const float* __restrict__ w3,
    const float* __restrict__ b3, float* __restrict__ out)
{
    int lane = threadIdx.x & 63;
    int wid = blockIdx.x * 4 + (threadIdx.x >> 6);
    int v0 = wid * V7CH, v1 = min(v0 + V7CH, NVOX);
    REP64(DECL_W3)
    float b3c = b3[lane];
    for (int v = v0; v < v1; v++) {
        float cnt = vox4[v].w;
        float* row = out + (size_t)v * 64;
        if (cnt > 0.5f) {
            float m = row[lane] / cnt;
            float ya = b3c, yb = 0.f, yc = 0.f, yd = 0.f;
            L3ALL
            row[lane] = (ya + yb) + (yc + yd);
        } else {
            row[lane] = 0.f;
        }
    }
}

extern "C" void kernel_launch(void* const* d_in, const int* in_sizes, int n_in,
                              void* d_out, int out_size, void* d_ws, size_t ws_size,
                              hipStream_t stream) {
    const float4* pts  = (const float4*)d_in[0];
    const float*  nor  = (const float*)d_in[1];
    const int*    gind = (const int*)d_in[2];
    const int*    cinv = (const int*)d_in[3];
    const float*  bn0g = (const float*)d_in[4];
    const float*  bn0b = (const float*)d_in[5];
    const float*  w1   = (const float*)d_in[6];
    const float*  b1   = (const float*)d_in[7];
    const float*  bn1g = (const float*)d_in[8];
    const float*  bn1b = (const float*)d_in[9];
    const float*  w2   = (const float*)d_in[10];
    const float*  b2   = (const float*)d_in[11];
    const float*  bn2g = (const float*)d_in[12];
    const float*  bn2b = (const float*)d_in[13];
    const float*  w3   = (const float*)d_in[14];
    const float*  b3   = (const float*)d_in[15];

    float* ws  = (float*)d_ws;
    float* out = (float*)d_out;

    // tier select: PREFER fp16 h (halves the k4-write + k6-read HBM traffic;
    // 128 MB h also L3-resident). 1 = fp16-h fast, 0 = recompute fallback.
    int tier = 0;
    if (ws_size >= NEED_F16_BYTES) tier = 1;

    const bool fast = tier > 0;

    int*   cnt  = (int*)(ws + (fast ? F_CNT  : OFF_CNT));
    int*   base = (int*)(ws + (fast ? F_BASE : OFF_BASE));
    int*   bsum = (int*)(ws + (fast ? F_BSUM : OFF_BSUM));
    int*   boff = (int*)(ws + (fast ? F_BOFF : OFF_BOFF));
    int*   pidx = (int*)(ws + (fast ? F_PIDX : OFF_PIDX));
    float4* vox4 = (float4*)(ws + (fast ? F_VOX : OFF_VOX));
    float* MOMP = ws + (fast ? F_MOM : OFF_MOM);
    float* PH2  = ws + (fast ? F_PH2 : OFF_PH2);
    float* PQ2  = ws + (fast ? F_PQ2 : OFF_PQ2);
    float* Wf2  = ws + (fast ? F_WF2 : OFF_WF2);
    float* bf2  = ws + (fast ? F_BF2 : OFF_BF2);
    float* s2   = ws + (fast ? F_S2  : OFF_S2);
    float* t2   = ws + (fast ? F_T2  : OFF_T2);
    int*   sidx = fast ? (int*)(ws + F_SIDX) : (int*)nullptr;
    void*  hbuf = fast ? (void*)(ws + F_H)   : nullptr;

    hipMemsetAsync(cnt, 0, (size_t)ZERO_WORDS * 4, stream);

    k_count<<<(NPTS + 255) / 256, 256, 0, stream>>>(cinv, cnt);
    k_scan1<<<NSCAN, SCAN_B, 0, stream>>>(cnt, base, bsum);
    k_scan2<<<1, SCAN_B, 0, stream>>>(bsum, boff);
    k_base<<<(NVOX + 255) / 256, 256, 0, stream>>>(boff, base);
    k_fill<<<(NPTS + 255) / 256, 256, 0, stream>>>(cinv, base, pidx, sidx);
    k_mean<<<NMB, 256, 0, stream>>>(pts, base, pidx, vox4);
    k_mom<<<MOMB, 256, 0, stream>>>(pts, nor, gind, cinv, vox4, MOMP);
    k_fold_all<<<1, 128, 0, stream>>>(MOMP, bn0g, bn0b, w1, b1, bn1g, bn1b, Wf2, bf2);

    if (tier == 1) {
        k4_stats2<_Float16><<<KB2, 512, 0, stream>>>(pts, nor, gind, cinv, vox4, Wf2, bf2,
                                                     w2, b2, sidx, (_Float16*)hbuf, PH2, PQ2);
    } else {
        k4_stats2<float><<<KB2, 512, 0, stream>>>(pts, nor, gind, cinv, vox4, Wf2, bf2,
                                                  w2, b2, (const int*)nullptr,
                                                  (float*)nullptr, PH2, PQ2);
    }
    k5_bn2<<<1, 256, 0, stream>>>(PH2, PQ2, bn2g, bn2b, s2, t2);
    if (tier == 1) {
        k6_stream<_Float16><<<KB6S, 512, 0, stream>>>(base, (const _Float16*)hbuf, s2, t2, w3, b3, out);
    } else {
        k6_gather<<<KB6, 256, 0, stream>>>(pts, nor, gind, base, pidx, vox4,
                                           Wf2, bf2, w2, b2, s2, t2, out);
        k7_final<<<KB7, 256, 0, stream>>>(vox4, w3, b3, out);
    }
}

// Round 17
// 486.810 us; speedup vs baseline: 2.7959x; 1.1082x over previous
//
#include <hip/hip_runtime.h>

#define NPTS 1000000
#define NVOX 200000
#define EPSV 1e-5f

#define KB2 768     // k4 blocks (512 thr = 8 waves) -> 6144 waves, exactly 3 blocks/CU
#define KB6 768     // k6_gather blocks (fallback)
#define KB7 768     // k7 blocks (fallback)
#define KB6S 782    // k6_stream blocks (512 thr = 8 waves): 6256 waves, 6250 active
#define MOMB 512    // k_mom blocks
#define NMB ((NVOX + 255) / 256)   // 782 (k_mean blocks)

#define W2CH 176    // pts/wave (k4): 176%16==0
#define V6CH ((NVOX + KB6*4 - 1) / (KB6*4))     // 66 vox/wave (k6_gather)
#define V7CH ((NVOX + KB7*4 - 1) / (KB7*4))     // 66 vox/wave (k7)
#define V6SCH 32    // vox/wave (k6_stream): 2 MFMA batches of 16; 200000 = 6250*32

// ================= ws layouts (4-byte word offsets) =================
// --- compact layout (fallback; ~9.5 MB) ---
#define OFF_CNT    0
#define ZERO_WORDS 200000
#define OFF_BASE   200000
#define OFF_BSUM   400000
#define OFF_BOFF   400512
#define OFF_PIDX   401024
#define OFF_VOX    1401024     // 800000 (16B aligned)
#define OFF_MOM    2201024     // MOMB*104 = 53248
#define OFF_PH2    2254272     // KB2*64 = 49152
#define OFF_PQ2    2303424
#define OFF_WF2    2352576     // 832
#define OFF_BF2    2353408     // 64
#define OFF_S2     2353472
#define OFF_T2     2353536

// --- fast layout: live-through-k6 state first, then h; early-dead blocks
//     (cnt/scan/pidx/mom) overlap the h region (dead before k4 writes h). ---
#define F_BASE   0             // 200000   live: scan .. k6_stream
#define F_VOX    200000        // 800000   live: k_mean .. k4 (16B aligned)
#define F_PH2    1000000       // 49152    live: k4 .. k5
#define F_PQ2    1049152       // 49152
#define F_WF2    1098304       // 832
#define F_BF2    1099136       // 64
#define F_S2     1099200       // 64
#define F_T2     1099264       // 64
#define F_SIDX   1099328       // 1000000  live: k_fill .. k4
#define F_H      2099328       // h: fp16 32e6 words
// early-dead overlay inside h region:
#define F_CNT    2099328       // 200000   k_count..k_scan1
#define F_BSUM   2299328       // 512
#define F_BOFF   2299840       // 512
#define F_PIDX   2300352       // 1000000  k_fill..k_mean
#define F_MOM    3300352       // 53248    k_mom..k_fold_all

#define NEED_F16_BYTES ((size_t)F_H * 4 + (size_t)NPTS * 64 * 2)  // 136,397,312

#define SCAN_B 512
#define NSCAN ((NVOX + SCAN_B - 1) / SCAN_B)   // 391

#define TRI(j,k) ((j)*13 - (j)*((j)-1)/2 + ((k)-(j)))

typedef _Float16 f16x8 __attribute__((ext_vector_type(8)));
typedef float f32x4 __attribute__((ext_vector_type(4)));

__device__ __forceinline__ float bcast(float x, int k) {
    return __int_as_float(__builtin_amdgcn_readlane(__float_as_int(x), k));
}
__device__ __forceinline__ float wave_red(float x) {
#pragma unroll
    for (int o = 32; o > 0; o >>= 1) x += __shfl_down(x, o);
    return x;
}

// ---- macro-generated straight-line register code ----
#define REP13(M) M(0) M(1) M(2) M(3) M(4) M(5) M(6) M(7) M(8) M(9) M(10) M(11) M(12)
#define REP64(M) M(0) M(1) M(2) M(3) M(4) M(5) M(6) M(7) M(8) M(9) \
 M(10) M(11) M(12) M(13) M(14) M(15) M(16) M(17) M(18) M(19) \
 M(20) M(21) M(22) M(23) M(24) M(25) M(26) M(27) M(28) M(29) \
 M(30) M(31) M(32) M(33) M(34) M(35) M(36) M(37) M(38) M(39) \
 M(40) M(41) M(42) M(43) M(44) M(45) M(46) M(47) M(48) M(49) \
 M(50) M(51) M(52) M(53) M(54) M(55) M(56) M(57) M(58) M(59) \
 M(60) M(61) M(62) M(63)

#define DECL_W1(J)  float w1c_##J = Wfp[(J)*64 + lane]; asm("" : "+v"(w1c_##J));
#define DECL_W2(K)  float w2c_##K = w2[(K)*64 + lane];  asm("" : "+v"(w2c_##K));
#define DECL_W3(K)  float w3c_##K = w3[(K)*64 + lane];  asm("" : "+v"(w3c_##K));

#define FEAT_BODY \
    float4 pt = pts[p]; \
    int g0 = gind[3*p], g1 = gind[3*p+1], g2 = gind[3*p+2]; \
    float f0 = pt.x, f1 = pt.y, f2 = pt.z, f3 = pt.w; \
    float f4 = pt.x - vs.x, f5 = pt.y - vs.y, f6 = pt.z - vs.z; \
    float f7 = pt.x - ((float)g0 * 0.2f - 51.2f); \
    float f8 = pt.y - ((float)g1 * 0.2f - 51.2f); \
    float f9 = pt.z - ((float)g2 * 0.2f - 4.0f); \
    float f10 = nor[3*p], f11 = nor[3*p+1], f12 = nor[3*p+2];

#define FEAT_GATHER float4 vs = vox4[cinv[p]]; FEAT_BODY

#define L1EXPR (bc + ((((f0*w1c_0 + f1*w1c_1) + (f2*w1c_2 + f3*w1c_3)) \
              + ((f4*w1c_4 + f5*w1c_5) + (f6*w1c_6 + f7*w1c_7))) \
              + (((f8*w1c_8 + f9*w1c_9) + (f10*w1c_10 + f11*w1c_11)) \
              + f12*w1c_12)))

#define L2G(A,B,C,D) ha += bcast(r,A)*w2c_##A; hb += bcast(r,B)*w2c_##B; \
                     hc += bcast(r,C)*w2c_##C; hd += bcast(r,D)*w2c_##D;
#define L2ALL L2G(0,1,2,3) L2G(4,5,6,7) L2G(8,9,10,11) L2G(12,13,14,15) \
  L2G(16,17,18,19) L2G(20,21,22,23) L2G(24,25,26,27) L2G(28,29,30,31) \
  L2G(32,33,34,35) L2G(36,37,38,39) L2G(40,41,42,43) L2G(44,45,46,47) \
  L2G(48,49,50,51) L2G(52,53,54,55) L2G(56,57,58,59) L2G(60,61,62,63)

#define L3G(A,B,C,D) ya += bcast(m,A)*w3c_##A; yb += bcast(m,B)*w3c_##B; \
                     yc += bcast(m,C)*w3c_##C; yd += bcast(m,D)*w3c_##D;
#define L3ALL L3G(0,1,2,3) L3G(4,5,6,7) L3G(8,9,10,11) L3G(12,13,14,15) \
  L3G(16,17,18,19) L3G(20,21,22,23) L3G(24,25,26,27) L3G(28,29,30,31) \
  L3G(32,33,34,35) L3G(36,37,38,39) L3G(40,41,42,43) L3G(44,45,46,47) \
  L3G(48,49,50,51) L3G(52,53,54,55) L3G(56,57,58,59) L3G(60,61,62,63)

// ---------------- counts ----------------
__global__ __launch_bounds__(256) void k_count(
    const int* __restrict__ cinv, int* __restrict__ cnt)
{
    int i = blockIdx.x * 256 + threadIdx.x;
    if (i < NPTS) atomicAdd(&cnt[cinv[i]], 1);
}

// ---------------- scan ----------------
__global__ __launch_bounds__(SCAN_B) void k_scan1(
    const int* __restrict__ cnt, int* __restrict__ base, int* __restrict__ bsum)
{
    __shared__ int sd[SCAN_B];
    int t = threadIdx.x;
    int v = blockIdx.x * SCAN_B + t;
    int x = (v < NVOX) ? cnt[v] : 0;
    sd[t] = x;
    __syncthreads();
    for (int o = 1; o < SCAN_B; o <<= 1) {
        int y = (t >= o) ? sd[t - o] : 0;
        __syncthreads();
        sd[t] += y;
        __syncthreads();
    }
    if (v < NVOX) base[v] = sd[t] - x;
    if (t == SCAN_B - 1) bsum[blockIdx.x] = sd[t];
}

__global__ __launch_bounds__(SCAN_B) void k_scan2(
    const int* __restrict__ bsum, int* __restrict__ boff)
{
    __shared__ int sd[SCAN_B];
    int t = threadIdx.x;
    int x = (t < NSCAN) ? bsum[t] : 0;
    sd[t] = x;
    __syncthreads();
    for (int o = 1; o < SCAN_B; o <<= 1) {
        int y = (t >= o) ? sd[t - o] : 0;
        __syncthreads();
        sd[t] += y;
        __syncthreads();
    }
    if (t < NSCAN) boff[t] = sd[t] - x;
}

__global__ __launch_bounds__(256) void k_base(
    const int* __restrict__ boff, int* __restrict__ base)
{
    int v = blockIdx.x * 256 + threadIdx.x;
    if (v < NVOX) base[v] += boff[v >> 9];
}

__global__ __launch_bounds__(256) void k_fill(
    const int* __restrict__ cinv, int* __restrict__ base,
    int* __restrict__ pidx, int* __restrict__ sidx)
{
    int i = blockIdx.x * 256 + threadIdx.x;
    if (i >= NPTS) return;
    int slot = atomicAdd(&base[cinv[i]], 1);
    pidx[slot] = i;
    if (sidx) sidx[i] = slot;
}

// ---------------- per-voxel means ----------------
__global__ __launch_bounds__(256, 2) void k_mean(
    const float4* __restrict__ pts, const int* __restrict__ base,
    const int* __restrict__ pidx, float4* __restrict__ vox4)
{
    int v = blockIdx.x * 256 + threadIdx.x;
    if (v >= NVOX) return;
    int st = (v == 0) ? 0 : base[v - 1];
    int en = base[v];
    int c = en - st;
    float sx = 0.f, sy = 0.f, sz = 0.f;
    for (int i = st; i < en; i++) {
        float4 p = pts[pidx[i]];
        sx += p.x; sy += p.y; sz += p.z;
    }
    float fc = (float)c;
    float ic = 1.0f / fmaxf(fc, 1.0f);
    vox4[v] = make_float4(sx * ic, sy * ic, sz * ic, fc);
}

// -------- feature moments: E[f] (13) + E[f f^T] upper-tri (91) -> partials --
__global__ __launch_bounds__(256) void k_mom(
    const float4* __restrict__ pts, const float* __restrict__ nor,
    const int* __restrict__ gind, const int* __restrict__ cinv,
    const float4* __restrict__ vox4, float* __restrict__ MOMP)
{
    const int T = MOMB * 256;
    int tid = blockIdx.x * 256 + threadIdx.x;
    float s[13], q[91];
#pragma unroll
    for (int j = 0; j < 13; j++) s[j] = 0.f;
#pragma unroll
    for (int j = 0; j < 91; j++) q[j] = 0.f;
    for (int i = tid; i < NPTS; i += T) {
        float4 p = pts[i];
        int g0 = gind[3*i], g1 = gind[3*i+1], g2 = gind[3*i+2];
        float n0 = nor[3*i], n1 = nor[3*i+1], n2 = nor[3*i+2];
        float4 vs = vox4[cinv[i]];
        float f[13];
        f[0] = p.x; f[1] = p.y; f[2] = p.z; f[3] = p.w;
        f[4] = p.x - vs.x; f[5] = p.y - vs.y; f[6] = p.z - vs.z;
        f[7] = p.x - ((float)g0 * 0.2f - 51.2f);
        f[8] = p.y - ((float)g1 * 0.2f - 51.2f);
        f[9] = p.z - ((float)g2 * 0.2f - 4.0f);
        f[10] = n0; f[11] = n1; f[12] = n2;
#pragma unroll
        for (int j = 0; j < 13; j++) s[j] += f[j];
#pragma unroll
        for (int j = 0; j < 13; j++)
#pragma unroll
            for (int k = j; k < 13; k++) q[TRI(j,k)] += f[j] * f[k];
    }
#pragma unroll
    for (int j = 0; j < 13; j++) s[j] = wave_red(s[j]);
#pragma unroll
    for (int j = 0; j < 91; j++) q[j] = wave_red(q[j]);
    __shared__ float red[4][104];
    int w = threadIdx.x >> 6, lane = threadIdx.x & 63;
    if (lane == 0) {
#pragma unroll
        for (int j = 0; j < 13; j++) red[w][j] = s[j];
#pragma unroll
        for (int j = 0; j < 91; j++) red[w][13 + j] = q[j];
    }
    __syncthreads();
    int t = threadIdx.x;
    if (t < 104)
        MOMP[blockIdx.x * 104 + t] = red[0][t] + red[1][t] + red[2][t] + red[3][t];
}

// ---- reduce moments; fold BN0 AND BN1 analytically -> Wf2, bf2 -------------
__global__ void k_fold_all(
    const float* __restrict__ MOMP,
    const float* __restrict__ bn0g, const float* __restrict__ bn0b,
    const float* __restrict__ w1, const float* __restrict__ b1,
    const float* __restrict__ bn1g, const float* __restrict__ bn1b,
    float* __restrict__ Wf2, float* __restrict__ bf2)
{
    __shared__ float mom[104];
    __shared__ float mu[13];
    __shared__ float C[13][13];
    int t = threadIdx.x;  // 128 threads
    for (int j = t; j < 104; j += 128) {
        float s = 0.f;
        for (int b = 0; b < MOMB; b++) s += MOMP[b * 104 + j];
        mom[j] = s;
    }
    __syncthreads();
    const float invN = 1.0f / (float)NPTS;
    if (t < 13) mu[t] = mom[t] * invN;
    __syncthreads();
    for (int e = t; e < 91; e += 128) {
        int j = 0, r = e;
        while (r >= 13 - j) { r -= 13 - j; j++; }
        int k = j + r;
        float v = mom[13 + e] * invN - mu[j] * mu[k];
        C[j][k] = v; C[k][j] = v;
    }
    __syncthreads();
    if (t < 64) {
        float s0[13], t0[13];
#pragma unroll
        for (int j = 0; j < 13; j++) {
            float sc = bn0g[j] * rsqrtf(C[j][j] + EPSV);
            s0[j] = sc; t0[j] = bn0b[j] - mu[j] * sc;
        }
        float wt[13];
        float bt = b1[t];
#pragma unroll
        for (int j = 0; j < 13; j++) {
            float w = w1[j*64 + t];
            wt[j] = s0[j] * w;
            bt += t0[j] * w;
        }
        float mean1 = bt;
#pragma unroll
        for (int j = 0; j < 13; j++) mean1 += wt[j] * mu[j];
        float var1 = 0.f;
#pragma unroll
        for (int j = 0; j < 13; j++) {
            float acc = 0.f;
#pragma unroll
            for (int k = 0; k < 13; k++) acc += wt[k] * C[j][k];
            var1 += wt[j] * acc;
        }
        float s1 = bn1g[t] * rsqrtf(var1 + EPSV);
        float t1 = bn1b[t] - mean1 * s1;
#pragma unroll
        for (int j = 0; j < 13; j++) Wf2[j*64 + t] = s1 * wt[j];
        bf2[t] = s1 * bt + t1;
    }
}

// ---------------- k4: L1 fp32 (exact, LDS-fed) + L2 via MFMA fp16 -----------
template <typename HT>
__global__ __launch_bounds__(512) void k4_stats2(
    const float4* __restrict__ pts, const float* __restrict__ nor,
    const int* __restrict__ gind, const int* __restrict__ cinv,
    const float4* __restrict__ vox4,
    const float* __restrict__ Wfp, const float* __restrict__ bfv,
    const float* __restrict__ w2, const float* __restrict__ b2,
    const int* __restrict__ sidx, HT* __restrict__ hout,
    float* __restrict__ PH, float* __restrict__ PQ)
{
    int lane = threadIdx.x & 63;
    int w = threadIdx.x >> 6;      // 0..7
    int wid = blockIdx.x * 8 + w;
    int p0 = wid * W2CH;
    int p1 = min(p0 + W2CH, NPTS);
    int cl = lane & 15;            // col within 16
    int kg = lane >> 4;            // k-group / row-group

    __shared__ __align__(16) _Float16 RS[8][16 * 80];  // r staging, 2560B/wave
    __shared__ int SLT[8][16];
    __shared__ __align__(16) float4 PTSL[8][16];
    __shared__ __align__(16) float4 VOXL[8][16];
    __shared__ float CENL[8][48];
    __shared__ float NORL[8][48];
    __shared__ float LH[8][64], LQ[8][64];

    REP13(DECL_W1)
    float bc = bfv[lane];

    // w2 fragments in fp16: wf[t*2+h]
    f16x8 wf[8];
#pragma unroll
    for (int t = 0; t < 4; t++)
#pragma unroll
        for (int h = 0; h < 2; h++) {
            f16x8 v;
#pragma unroll
            for (int j = 0; j < 8; j++) {
                int k = h * 32 + kg * 8 + j;
                v[j] = (_Float16)w2[k * 64 + t * 16 + cl];
            }
            wf[t * 2 + h] = v;
        }

    float sh0 = 0.f, sh1 = 0.f, sh2 = 0.f, sh3 = 0.f;
    float sq0 = 0.f, sq1 = 0.f, sq2 = 0.f, sq3 = 0.f;

    _Float16* rs = RS[w];
    int* slt = SLT[w];
    float4* ptl = PTSL[w];
    float4* vxl = VOXL[w];
    float* cel = CENL[w];
    float* nol = NORL[w];

    for (int pb = p0; pb < p1; pb += 16) {
        // ---- batch input staging: coalesced / 16-parallel loads ----
        if (lane < 16) {
            int p = pb + lane;
            ptl[lane] = pts[p];
            int cv = cinv[p];
            vxl[lane] = vox4[cv];        // 16 parallel gathers
            if (sidx) slt[lane] = sidx[p];
        }
        if (lane < 48) {
            int gv = gind[3 * pb + lane];        // coalesced 48 dwords
            int comp = lane % 3;
            cel[lane] = (float)gv * 0.2f - ((comp == 2) ? 4.0f : 51.2f);
            nol[lane] = nor[3 * pb + lane];      // coalesced
        }
        // ---- L1 for 16 points (fp32 exact), all inputs from LDS ----
        for (int m = 0; m < 16; m++) {
            float4 pt = ptl[m];
            float4 vs = vxl[m];
            float c0 = cel[3*m], c1 = cel[3*m+1], c2 = cel[3*m+2];
            float f0 = pt.x, f1 = pt.y, f2 = pt.z, f3 = pt.w;
            float f4 = pt.x - vs.x, f5 = pt.y - vs.y, f6 = pt.z - vs.z;
            float f7 = pt.x - c0, f8 = pt.y - c1, f9 = pt.z - c2;
            float f10 = nol[3*m], f11 = nol[3*m+1], f12 = nol[3*m+2];
            float r = fmaxf(L1EXPR, 0.f);
            rs[m * 80 + lane] = (_Float16)r;
        }
        const _Float16* arow = rs + cl * 80 + kg * 8;
        f16x8 a0 = *(const f16x8*)(arow);        // k 0..31 slice
        f16x8 a1 = *(const f16x8*)(arow + 32);   // k 32..63 slice
        f32x4 acc0 = {0.f, 0.f, 0.f, 0.f};
        f32x4 acc1 = {0.f, 0.f, 0.f, 0.f};
        f32x4 acc2 = {0.f, 0.f, 0.f, 0.f};
        f32x4 acc3 = {0.f, 0.f, 0.f, 0.f};
        acc0 = __builtin_amdgcn_mfma_f32_16x16x32_f16(a0, wf[0], acc0, 0, 0, 0);
        acc0 = __builtin_amdgcn_mfma_f32_16x16x32_f16(a1, wf[1], acc0, 0, 0, 0);
        acc1 = __builtin_amdgcn_mfma_f32_16x16x32_f16(a0, wf[2], acc1, 0, 0, 0);
        acc1 = __builtin_amdgcn_mfma_f32_16x16x32_f16(a1, wf[3], acc1, 0, 0, 0);
        acc2 = __builtin_amdgcn_mfma_f32_16x16x32_f16(a0, wf[4], acc2, 0, 0, 0);
        acc2 = __builtin_amdgcn_mfma_f32_16x16x32_f16(a1, wf[5], acc2, 0, 0, 0);
        acc3 = __builtin_amdgcn_mfma_f32_16x16x32_f16(a0, wf[6], acc3, 0, 0, 0);
        acc3 = __builtin_amdgcn_mfma_f32_16x16x32_f16(a1, wf[7], acc3, 0, 0, 0);
        int s0v = 0, s1v = 0, s2v = 0, s3v = 0;
        if (sidx) {
            s0v = slt[kg * 4 + 0]; s1v = slt[kg * 4 + 1];
            s2v = slt[kg * 4 + 2]; s3v = slt[kg * 4 + 3];
        }
#define TILE_OUT(T, ACC) { \
        float d0 = ACC[0], d1 = ACC[1], d2 = ACC[2], d3 = ACC[3]; \
        sh##T += (d0 + d1) + (d2 + d3); \
        sq##T += (d0*d0 + d1*d1) + (d2*d2 + d3*d3); \
        if (hout) { \
            hout[(size_t)s0v * 64 + (T)*16 + cl] = (HT)d0; \
            hout[(size_t)s1v * 64 + (T)*16 + cl] = (HT)d1; \
            hout[(size_t)s2v * 64 + (T)*16 + cl] = (HT)d2; \
            hout[(size_t)s3v * 64 + (T)*16 + cl] = (HT)d3; \
        } }
        TILE_OUT(0, acc0)
        TILE_OUT(1, acc1)
        TILE_OUT(2, acc2)
        TILE_OUT(3, acc3)
#undef TILE_OUT
    }
    // column totals: combine lanes {l, l^16, l^32, l^48}
#define COLRED(V) { V += __shfl_xor(V, 16); V += __shfl_xor(V, 32); }
    COLRED(sh0) COLRED(sh1) COLRED(sh2) COLRED(sh3)
    COLRED(sq0) COLRED(sq1) COLRED(sq2) COLRED(sq3)
#undef COLRED
    if (lane < 16) {
        LH[w][cl]      = sh0; LH[w][16 + cl] = sh1;
        LH[w][32 + cl] = sh2; LH[w][48 + cl] = sh3;
        LQ[w][cl]      = sq0; LQ[w][16 + cl] = sq1;
        LQ[w][32 + cl] = sq2; LQ[w][48 + cl] = sq3;
    }
    __syncthreads();
    if (w == 0) {
        float a = 0.f, b = 0.f;
#pragma unroll
        for (int x = 0; x < 8; x++) { a += LH[x][lane]; b += LQ[x][lane]; }
        PH[blockIdx.x * 64 + lane] = a;
        PQ[blockIdx.x * 64 + lane] = b;
    }
}

// ---------------- reduce + finalize BN2 (stats are of h' = h - b2) ----------
__global__ __launch_bounds__(256) void k5_bn2(
    const float* __restrict__ PH, const float* __restrict__ PQ,
    const float* __restrict__ bn2g, const float* __restrict__ bn2b,
    float* __restrict__ s2, float* __restrict__ t2)
{
    __shared__ float LH[4][64], LQ[4][64];
    int c = threadIdx.x & 63, g = threadIdx.x >> 6;
    float sH = 0.f, sQ = 0.f;
    for (int b = g; b < KB2; b += 4) { sH += PH[b*64 + c]; sQ += PQ[b*64 + c]; }
    LH[g][c] = sH; LQ[g][c] = sQ;
    __syncthreads();
    if (g == 0) {
        const float invN = 1.0f / (float)NPTS;
        float mn = (LH[0][c] + LH[1][c] + LH[2][c] + LH[3][c]) * invN;
        float vr = (LQ[0][c] + LQ[1][c] + LQ[2][c] + LQ[3][c]) * invN - mn * mn;
        float s = bn2g[c] * rsqrtf(vr + EPSV);
        s2[c] = s; t2[c] = bn2b[c] - mn * s;
    }
}

// -------- FAST PATH k6: per voxel segmean of BN2(h')+relu (scalar, c~5),
//          then w3 matmul via MFMA over 16-voxel batches (replaces the
//          128-VALU/voxel readlane matmul). base[] prefetched per wave. -----
template <typename HT>
__global__ __launch_bounds__(512) void k6_stream(
    const int* __restrict__ base, const HT* __restrict__ h,
    const float* __restrict__ s2, const float* __restrict__ t2,
    const float* __restrict__ w3, const float* __restrict__ b3,
    float* __restrict__ out)
{
    int lane = threadIdx.x & 63;
    int w = threadIdx.x >> 6;
    int wid = blockIdx.x * 8 + w;
    int v0 = wid * V6SCH;            // 32 voxels/wave, exact (200000 = 6250*32)
    if (v0 >= NVOX) return;
    int cl = lane & 15, kg = lane >> 4;

    __shared__ __align__(16) _Float16 RS[8][16 * 80];  // mean staging
    __shared__ int BL[8][33];                          // base prefetch
    __shared__ int CNTL[8][16];                        // per-voxel counts

    float s2c = s2[lane], t2c = t2[lane];

    // w3 fragments in fp16 (same mapping as k4's w2)
    f16x8 wf[8];
#pragma unroll
    for (int t = 0; t < 4; t++)
#pragma unroll
        for (int hh = 0; hh < 2; hh++) {
            f16x8 v;
#pragma unroll
            for (int j = 0; j < 8; j++) {
                int k = hh * 32 + kg * 8 + j;
                v[j] = (_Float16)w3[k * 64 + t * 16 + cl];
            }
            wf[t * 2 + hh] = v;
        }
    float b3v0 = b3[cl], b3v1 = b3[16 + cl], b3v2 = b3[32 + cl], b3v3 = b3[48 + cl];

    _Float16* rs = RS[w];
    int* bl = BL[w];
    int* cntl = CNTL[w];

    // prefetch base[v0-1 .. v0+31] (33 values; removes per-voxel uniform-load chain)
    if (lane < 33) {
        int idx = v0 - 1 + lane;
        bl[lane] = (idx < 0) ? 0 : base[idx];
    }

    for (int vb = 0; vb < V6SCH; vb += 16) {
        // ---- 16 voxel means (lane = channel) ----
        for (int m = 0; m < 16; m++) {
            int st = bl[vb + m];
            int en = bl[vb + m + 1];
            int c = en - st;
            const HT* hp = h + (size_t)st * 64 + lane;
            float accz = 0.f;
            int ii = 0;
            for (; ii + 3 < c; ii += 4) {
                float h0 = (float)hp[(size_t)(ii + 0) * 64];
                float h1 = (float)hp[(size_t)(ii + 1) * 64];
                float h2v = (float)hp[(size_t)(ii + 2) * 64];
                float h3v = (float)hp[(size_t)(ii + 3) * 64];
                accz += fmaxf(s2c * h0 + t2c, 0.f);
                accz += fmaxf(s2c * h1 + t2c, 0.f);
                accz += fmaxf(s2c * h2v + t2c, 0.f);
                accz += fmaxf(s2c * h3v + t2c, 0.f);
            }
            for (; ii < c; ii++)
                accz += fmaxf(s2c * (float)hp[(size_t)ii * 64] + t2c, 0.f);
            float inv = 1.0f / fmaxf((float)c, 1.0f);
            rs[m * 80 + lane] = (_Float16)(accz * inv);
            if (lane == 0) cntl[m] = c;
        }
        // ---- w3 matmul via MFMA (A = means, m92 layout; D per m89) ----
        const _Float16* arow = rs + cl * 80 + kg * 8;
        f16x8 a0 = *(const f16x8*)(arow);
        f16x8 a1 = *(const f16x8*)(arow + 32);
        f32x4 acc0 = {0.f, 0.f, 0.f, 0.f};
        f32x4 acc1 = {0.f, 0.f, 0.f, 0.f};
        f32x4 acc2 = {0.f, 0.f, 0.f, 0.f};
        f32x4 acc3 = {0.f, 0.f, 0.f, 0.f};
        acc0 = __builtin_amdgcn_mfma_f32_16x16x32_f16(a0, wf[0], acc0, 0, 0, 0);
        acc0 = __builtin_amdgcn_mfma_f32_16x16x32_f16(a1, wf[1], acc0, 0, 0, 0);
        acc1 = __builtin_amdgcn_mfma_f32_16x16x32_f16(a0, wf[2], acc1, 0, 0, 0);
        acc1 = __builtin_amdgcn_mfma_f32_16x16x32_f16(a1, wf[3], acc1, 0, 0, 0);
        acc2 = __builtin_amdgcn_mfma_f32_16x16x32_f16(a0, wf[4], acc2, 0, 0, 0);
        acc2 = __builtin_amdgcn_mfma_f32_16x16x32_f16(a1, wf[5], acc2, 0, 0, 0);
        acc3 = __builtin_amdgcn_mfma_f32_16x16x32_f16(a0, wf[6], acc3, 0, 0, 0);
        acc3 = __builtin_amdgcn_mfma_f32_16x16x32_f16(a1, wf[7], acc3, 0, 0, 0);
        int vbase = v0 + vb;
#define OUT_TILE(T, ACC, B3) { \
        _Pragma("unroll") \
        for (int r = 0; r < 4; r++) { \
            int m = kg * 4 + r; \
            float d = ACC[r] + B3; \
            out[(size_t)(vbase + m) * 64 + (T)*16 + cl] = (cntl[m] > 0) ? d : 0.f; \
        } }
        OUT_TILE(0, acc0, b3v0)
        OUT_TILE(1, acc1, b3v1)
        OUT_TILE(2, acc2, b3v2)
        OUT_TILE(3, acc3, b3v3)
#undef OUT_TILE
    }
}

// ---- FALLBACK PATH: recompute h' (no b2; consistent with k5 stats) ---------
__global__ __launch_bounds__(256, 3) void k6_gather(
    const float4* __restrict__ pts, const float* __restrict__ nor,
    const int* __restrict__ gind,
    const int* __restrict__ base, const int* __restrict__ pidx,
    const float4* __restrict__ vox4,
    const float* __restrict__ Wfp, const float* __restrict__ bfv,
    const float* __restrict__ w2, const float* __restrict__ b2,
    const float* __restrict__ s2, const float* __restrict__ t2,
    float* __restrict__ out)
{
    int lane = threadIdx.x & 63;
    int wid = blockIdx.x * 4 + (threadIdx.x >> 6);
    int v0 = wid * V6CH, v1 = min(v0 + V6CH, NVOX);
    REP13(DECL_W1)
    float bc = bfv[lane];
    REP64(DECL_W2)
    float s2c = s2[lane], t2c = t2[lane];

    for (int v = v0; v < v1; v++) {
        int st = (v == 0) ? 0 : base[v - 1];
        int en = base[v];
        float4 vs = vox4[v];
        float accz = 0.f;
        for (int ii = st; ii < en; ii++) {
            int p = pidx[ii];
            FEAT_BODY
            float r = fmaxf(L1EXPR, 0.f);
            float ha = 0.f, hb = 0.f, hc = 0.f, hd = 0.f;
            L2ALL
            float h = (ha + hb) + (hc + hd);
            accz += fmaxf(s2c * h + t2c, 0.f);
        }
        out[(size_t)v * 64 + lane] = accz;
    }
}

// ---------- mean + w3 matmul + bias (in-place on d_out) — fallback only -----
__global__ __launch_bounds__(256, 3) void k7_final(
    const float4* __restrict__ vox4, const float* __restrict__ w3,
    const float* __restrict__ b3, float* __restrict__ out)
{
    int lane = threadIdx.x & 63;
    int wid = blockIdx.x * 4 + (threadIdx.x >> 6);
    int v0 = wid * V7CH, v1 = min(v0 + V7CH, NVOX);
    REP64(DECL_W3)
    float b3c = b3[lane];
    for (int v = v0; v < v1; v++) {
        float cnt = vox4[v].w;
        float* row = out + (size_t)v * 64;
        if (cnt > 0.5f) {
            float m = row[lane] / cnt;
            float ya = b3c, yb = 0.f, yc = 0.f, yd = 0.f;
            L3ALL
            row[lane] = (ya + yb) + (yc + yd);
        } else {
            row[lane] = 0.f;
        }
    }
}

extern "C" void kernel_launch(void* const* d_in, const int* in_sizes, int n_in,
                              void* d_out, int out_size, void* d_ws, size_t ws_size,
                              hipStream_t stream) {
    const float4* pts  = (const float4*)d_in[0];
    const float*  nor  = (const float*)d_in[1];
    const int*    gind = (const int*)d_in[2];
    const int*    cinv = (const int*)d_in[3];
    const float*  bn0g = (const float*)d_in[4];
    const float*  bn0b = (const float*)d_in[5];
    const float*  w1   = (const float*)d_in[6];
    const float*  b1   = (const float*)d_in[7];
    const float*  bn1g = (const float*)d_in[8];
    const float*  bn1b = (const float*)d_in[9];
    const float*  w2   = (const float*)d_in[10];
    const float*  b2   = (const float*)d_in[11];
    const float*  bn2g = (const float*)d_in[12];
    const float*  bn2b = (const float*)d_in[13];
    const float*  w3   = (const float*)d_in[14];
    const float*  b3   = (const float*)d_in[15];

    float* ws  = (float*)d_ws;
    float* out = (float*)d_out;

    // tier select: 1 = fp16-h fast path, 0 = recompute fallback
    int tier = 0;
    if (ws_size >= NEED_F16_BYTES) tier = 1;

    const bool fast = tier > 0;

    int*   cnt  = (int*)(ws + (fast ? F_CNT  : OFF_CNT));
    int*   base = (int*)(ws + (fast ? F_BASE : OFF_BASE));
    int*   bsum = (int*)(ws + (fast ? F_BSUM : OFF_BSUM));
    int*   boff = (int*)(ws + (fast ? F_BOFF : OFF_BOFF));
    int*   pidx = (int*)(ws + (fast ? F_PIDX : OFF_PIDX));
    float4* vox4 = (float4*)(ws + (fast ? F_VOX : OFF_VOX));
    float* MOMP = ws + (fast ? F_MOM : OFF_MOM);
    float* PH2  = ws + (fast ? F_PH2 : OFF_PH2);
    float* PQ2  = ws + (fast ? F_PQ2 : OFF_PQ2);
    float* Wf2  = ws + (fast ? F_WF2 : OFF_WF2);
    float* bf2  = ws + (fast ? F_BF2 : OFF_BF2);
    float* s2   = ws + (fast ? F_S2  : OFF_S2);
    float* t2   = ws + (fast ? F_T2  : OFF_T2);
    int*   sidx = fast ? (int*)(ws + F_SIDX) : (int*)nullptr;
    void*  hbuf = fast ? (void*)(ws + F_H)   : nullptr;

    hipMemsetAsync(cnt, 0, (size_t)ZERO_WORDS * 4, stream);

    k_count<<<(NPTS + 255) / 256, 256, 0, stream>>>(cinv, cnt);
    k_scan1<<<NSCAN, SCAN_B, 0, stream>>>(cnt, base, bsum);
    k_scan2<<<1, SCAN_B, 0, stream>>>(bsum, boff);
    k_base<<<(NVOX + 255) / 256, 256, 0, stream>>>(boff, base);
    k_fill<<<(NPTS + 255) / 256, 256, 0, stream>>>(cinv, base, pidx, sidx);
    k_mean<<<NMB, 256, 0, stream>>>(pts, base, pidx, vox4);
    k_mom<<<MOMB, 256, 0, stream>>>(pts, nor, gind, cinv, vox4, MOMP);
    k_fold_all<<<1, 128, 0, stream>>>(MOMP, bn0g, bn0b, w1, b1, bn1g, bn1b, Wf2, bf2);

    if (tier == 1) {
        k4_stats2<_Float16><<<KB2, 512, 0, stream>>>(pts, nor, gind, cinv, vox4, Wf2, bf2,
                                                     w2, b2, sidx, (_Float16*)hbuf, PH2, PQ2);
    } else {
        k4_stats2<float><<<KB2, 512, 0, stream>>>(pts, nor, gind, cinv, vox4, Wf2, bf2,
                                                  w2, b2, (const int*)nullptr,
                                                  (float*)nullptr, PH2, PQ2);
    }
    k5_bn2<<<1, 256, 0, stream>>>(PH2, PQ2, bn2g, bn2b, s2, t2);
    if (tier == 1) {
        k6_stream<_Float16><<<KB6S, 512, 0, stream>>>(base, (const _Float16*)hbuf, s2, t2, w3, b3, out);
    } else {
        k6_gather<<<KB6, 256, 0, stream>>>(pts, nor, gind, base, pidx, vox4,
                                           Wf2, bf2, w2, b2, s2, t2, out);
        k7_final<<<KB7, 256, 0, stream>>>(vox4, w3, b3, out);
    }
}